// Round 1
// baseline (3735.732 us; speedup 1.0000x reference)
//
#include <hip/hip_runtime.h>
#include <cstddef>

#define DINL static __device__ __forceinline__

// rot90 applied r times (counter-clockwise, numpy convention):
// rotated_r[i][j] = w[si][sj]
DINL void rot_src(int r, int K, int i, int j, int& si, int& sj) {
  switch (r & 3) {
    case 0:  si = i;       sj = j;       break;
    case 1:  si = j;       sj = K-1-i;   break;
    case 2:  si = K-1-i;   sj = K-1-j;   break;
    default: si = K-1-j;   sj = i;       break;
  }
}

DINL float sigmoidf(float s) { return 1.f / (1.f + __expf(-s)); }

// ---------------- layer 1 (lifting) ----------------

// att1[b][r][y][x] over 48x48, 'same' 7x7; input has 1 channel so mean==max==x
__global__ void k_att_lift(const float* __restrict__ x, const float* __restrict__ aw,
                           float* __restrict__ att) {
  const int H = 48, HW = H * H;
  int idx = blockIdx.x * blockDim.x + threadIdx.x;
  if (idx >= 32 * 4 * HW) return;
  int xw = idx % H; int t = idx / H;
  int yh = t % H;  t /= H;
  int r  = t & 3;  int b = t >> 2;
  const float* xb = x + b * HW;
  float s = 0.f;
  for (int ky = 0; ky < 7; ++ky) {
    int y = yh + ky - 3;
    if ((unsigned)y >= (unsigned)H) continue;
    for (int kx = 0; kx < 7; ++kx) {
      int xx = xw + kx - 3;
      if ((unsigned)xx >= (unsigned)H) continue;
      int si, sj; rot_src(r, 7, ky, kx, si, sj);
      s += xb[y * H + xx] * (aw[si * 7 + sj] + aw[49 + si * 7 + sj]);
    }
  }
  att[idx] = sigmoidf(s);
}

// y1[b][o][r][yo][xo] = b1[o] + sum_taps att1[b,r,p] * x[b,p] * rot_r(w1)[o,tap]
__global__ void __launch_bounds__(256)
k_conv_lift(const float* __restrict__ x, const float* __restrict__ att,
            const float* __restrict__ w, const float* __restrict__ bias,
            float* __restrict__ y) {
  const int HI = 48, HO = 46;
  int idx = blockIdx.x * blockDim.x + threadIdx.x;
  if (idx >= 32 * 32 * 4 * HO * HO) return;
  int xo = idx % HO; int t = idx / HO;
  int yo = t % HO;  t /= HO;
  int r  = t & 3;   t >>= 2;
  int o  = t & 31;  int b = t >> 5;
  const float* xb = x + b * HI * HI;
  const float* ab = att + (b * 4 + r) * HI * HI;
  float acc = bias[o];
  #pragma unroll
  for (int ky = 0; ky < 3; ++ky)
    #pragma unroll
    for (int kx = 0; kx < 3; ++kx) {
      int si, sj; rot_src(r, 3, ky, kx, si, sj);
      int p = (yo + ky) * HI + xo + kx;
      acc = fmaf(ab[p] * xb[p], w[o * 9 + si * 3 + sj], acc);
    }
  y[idx] = acc;
}

// ---------------- GG layers ----------------

// a[b][ci(2)][g][sp]: ci=0 mean over 32 channels, ci=1 max. input [B,32,4,hw]
__global__ void k_reduce_meanmax(const float* __restrict__ xin, float* __restrict__ a,
                                 int hw) {
  int idx = blockIdx.x * blockDim.x + threadIdx.x;
  if (idx >= 32 * 4 * hw) return;
  int sp = idx % hw; int t = idx / hw;
  int g = t & 3; int b = t >> 2;
  const float* p = xin + (size_t)(b * 32 * 4 + g) * hw + sp;
  float s = 0.f, m = -INFINITY;
  for (int c = 0; c < 32; ++c) {
    float v = p[(size_t)c * 4 * hw];
    s += v; m = fmaxf(m, v);
  }
  a[((b * 2 + 0) * 4 + g) * hw + sp] = s * (1.f / 32.f);
  a[((b * 2 + 1) * 4 + g) * hw + sp] = m;
}

// att[b][r][sp] = sigmoid( gg_conv7x7(a, aw)[b,0,r,sp] ), 'same' padding
// aw: [1,2,4,7,7]; gg_rot: spatial rot + roll along g-axis
__global__ void k_att_gg(const float* __restrict__ a, const float* __restrict__ aw,
                         float* __restrict__ att, int h) {
  int hw = h * h;
  int idx = blockIdx.x * blockDim.x + threadIdx.x;
  if (idx >= 32 * 4 * hw) return;
  int xw = idx % h; int t = idx / h;
  int yh = t % h;  t /= h;
  int r = t & 3;  int b = t >> 2;
  float s = 0.f;
  for (int ky = 0; ky < 7; ++ky) {
    int y = yh + ky - 3;
    if ((unsigned)y >= (unsigned)h) continue;
    for (int kx = 0; kx < 7; ++kx) {
      int xx = xw + kx - 3;
      if ((unsigned)xx >= (unsigned)h) continue;
      int si, sj; rot_src(r, 7, ky, kx, si, sj);
      int sp = y * h + xx;
      #pragma unroll
      for (int ci = 0; ci < 2; ++ci)
        #pragma unroll
        for (int g = 0; g < 4; ++g) {
          int gs = (g - r) & 3;
          s += a[((b * 2 + ci) * 4 + g) * hw + sp] * aw[(ci * 4 + gs) * 49 + si * 7 + sj];
        }
    }
  }
  att[idx] = sigmoidf(s);
}

// wrot[((r*O+o)*9 + ky*3+kx)*128 + ci*4+g] = w[o][ci][(g-r)&3][rot_r(ky,kx)]
__global__ void k_prep_w(const float* __restrict__ w, float* __restrict__ wrot, int O) {
  int idx = blockIdx.x * blockDim.x + threadIdx.x;
  int total = 4 * O * 9 * 128;
  if (idx >= total) return;
  int cg = idx % 128; int t = idx / 128;
  int tap = t % 9; t /= 9;
  int o = t % O; int r = t / O;
  int g = cg & 3, ci = cg >> 2;
  int ky = tap / 3, kx = tap % 3;
  int si, sj; rot_src(r, 3, ky, kx, si, sj);
  int gs = (g - r) & 3;
  wrot[idx] = w[((o * 32 + ci) * 4 + gs) * 9 + si * 3 + sj];
}

// y[b][o][r][yo][xo] = bias[o] + sum_taps att[b,r,p] * sum_{ci,g} x[b,ci,g,p]*wrot
// grid: (ceil(howo/256), 32*O*4); block uniform in (b,o,r) -> weights in LDS
__global__ void __launch_bounds__(256)
k_conv_gg(const float* __restrict__ xin, const float* __restrict__ att,
          const float* __restrict__ wrot, const float* __restrict__ bias,
          float* __restrict__ y, int O, int h) {
  __shared__ float ws_w[1152];
  int ho = h - 2, hw = h * h, howo = ho * ho;
  int bor = blockIdx.y;
  int r = bor & 3; int bo = bor >> 2;
  int o = bo % O;  int b = bo / O;
  const float* wsrc = wrot + (size_t)(r * O + o) * 1152;
  for (int i = threadIdx.x; i < 1152; i += 256) ws_w[i] = wsrc[i];
  __syncthreads();
  int sp = blockIdx.x * 256 + threadIdx.x;
  if (sp >= howo) return;
  int yo = sp / ho, xo = sp % ho;
  const float* xb = xin + (size_t)b * 128 * hw;
  const float* ab = att + (size_t)(b * 4 + r) * hw;
  float acc = bias[o];
  #pragma unroll
  for (int ky = 0; ky < 3; ++ky)
    #pragma unroll
    for (int kx = 0; kx < 3; ++kx) {
      int p = (yo + ky) * h + xo + kx;
      const float* xp = xb + p;
      const float* wp = ws_w + (ky * 3 + kx) * 128;
      float tap = 0.f;
      #pragma unroll 8
      for (int cg = 0; cg < 128; ++cg)
        tap = fmaf(xp[(size_t)cg * hw], wp[cg], tap);
      acc = fmaf(ab[p], tap, acc);
    }
  y[(size_t)bor * howo + sp] = acc;
}

// ---------------- BatchNorm3d (training-mode batch stats) ----------------

// partials: grid = 32 channels * 64 splits; part[0..2047]=sum, part[2048..]=sumsq
__global__ void k_bn_partial(const float* __restrict__ y, float* __restrict__ part,
                             int hw) {
  __shared__ float s1s[256], s2s[256];
  int c = blockIdx.x >> 6;
  int s = blockIdx.x & 63;
  int N = 32 * 4 * hw;
  float s1 = 0.f, s2 = 0.f;
  for (int j = s * 256 + threadIdx.x; j < N; j += 64 * 256) {
    int sp = j % hw; int bg = j / hw;
    int g = bg & 3; int b = bg >> 2;
    float v = y[(size_t)((b * 32 + c) * 4 + g) * hw + sp];
    s1 += v; s2 += v * v;
  }
  s1s[threadIdx.x] = s1; s2s[threadIdx.x] = s2;
  __syncthreads();
  for (int off = 128; off > 0; off >>= 1) {
    if (threadIdx.x < off) {
      s1s[threadIdx.x] += s1s[threadIdx.x + off];
      s2s[threadIdx.x] += s2s[threadIdx.x + off];
    }
    __syncthreads();
  }
  if (threadIdx.x == 0) {
    part[blockIdx.x] = s1s[0];
    part[2048 + blockIdx.x] = s2s[0];
  }
}

// stats[c]=scale, stats[32+c]=shift
__global__ void k_bn_finalize(const float* __restrict__ part,
                              const float* __restrict__ gamma,
                              const float* __restrict__ beta,
                              float* __restrict__ stats, int hw) {
  int c = threadIdx.x;
  if (c >= 32) return;
  float s1 = 0.f, s2 = 0.f;
  for (int s = 0; s < 64; ++s) { s1 += part[c * 64 + s]; s2 += part[2048 + c * 64 + s]; }
  float N = 32.f * 4.f * (float)hw;
  float m = s1 / N;
  float v = s2 / N - m * m;
  float inv = rsqrtf(v + 2e-5f);
  float sc = gamma[c] * inv;
  stats[c] = sc;
  stats[32 + c] = beta[c] - m * sc;
}

__global__ void k_bn_apply_relu(float* __restrict__ y, const float* __restrict__ stats,
                                int hw) {
  int idx = blockIdx.x * blockDim.x + threadIdx.x;
  if (idx >= 32 * 32 * 4 * hw) return;
  int c = (idx / (4 * hw)) & 31;
  y[idx] = fmaxf(fmaf(y[idx], stats[c], stats[32 + c]), 0.f);
}

// ---------------- pool + final ----------------

// [32,32,4,44,44] -> [32,32,4,22,22]
__global__ void k_pool(const float* __restrict__ yin, float* __restrict__ yout) {
  const int HI = 44, HO = 22;
  int idx = blockIdx.x * blockDim.x + threadIdx.x;
  if (idx >= 32 * 32 * 4 * HO * HO) return;
  int xo = idx % HO; int t = idx / HO;
  int yo = t % HO; int bcg = t / HO;
  const float* p = yin + ((size_t)bcg * HI + yo * 2) * HI + xo * 2;
  yout[idx] = fmaxf(fmaxf(p[0], p[1]), fmaxf(p[HI], p[HI + 1]));
}

// y7 [32,10,4,12,12] -> out[b*10+o] = mean_sp max_r
__global__ void k_final(const float* __restrict__ y7, float* __restrict__ out) {
  int idx = blockIdx.x * blockDim.x + threadIdx.x;
  if (idx >= 320) return;
  int o = idx % 10; int b = idx / 10;
  const float* p = y7 + (size_t)((b * 10 + o) * 4) * 144;
  float s = 0.f;
  for (int sp = 0; sp < 144; ++sp) {
    float m = fmaxf(fmaxf(p[sp], p[144 + sp]), fmaxf(p[288 + sp], p[432 + sp]));
    s += m;
  }
  out[idx] = s * (1.f / 144.f);
}

// ---------------- host ----------------

extern "C" void kernel_launch(void* const* d_in, const int* in_sizes, int n_in,
                              void* d_out, int out_size, void* d_ws, size_t ws_size,
                              hipStream_t stream) {
  (void)in_sizes; (void)n_in; (void)out_size; (void)ws_size;
  const float* x   = (const float*)d_in[0];
  const float* w1  = (const float*)d_in[1];
  const float* b1  = (const float*)d_in[2];
  const float* aw1 = (const float*)d_in[3];
  // w2..w7 / b2..b7 / aw2..aw7 at indices 4..21 (stride 3)
  const float* W[6];  const float* BI[6]; const float* AW[6];
  for (int i = 0; i < 6; ++i) {
    W[i]  = (const float*)d_in[4 + 3 * i];
    BI[i] = (const float*)d_in[5 + 3 * i];
    AW[i] = (const float*)d_in[6 + 3 * i];
  }
  // g1,be1,...,g6,be6 at 22..33
  const float* G[6]; const float* BE[6];
  for (int i = 0; i < 6; ++i) {
    G[i]  = (const float*)d_in[22 + 2 * i];
    BE[i] = (const float*)d_in[23 + 2 * i];
  }
  float* out = (float*)d_out;

  // workspace layout (floats); total 18,404,160 floats = 73.6 MB
  float* ws    = (float*)d_ws;
  float* A     = ws;                 // 8,700,000  (max 8,667,136 = y1)
  float* Bb    = ws + 8700000;       // 8,700,000  (max 7,929,856 = y2)
  float* AMAP  = ws + 17400000;      //   550,000  (max 541,696)
  float* ATT   = ws + 17950000;      //   300,000  (max 294,912)
  float* WROT  = ws + 18250000;      //   150,000  (max 147,456)
  float* PART  = ws + 18400000;      //     4,096
  float* STATS = ws + 18404096;      //        64

  auto cdiv = [](int a, int b) { return (a + b - 1) / b; };

  auto bn_relu = [&](float* buf, int hw, const float* gamma, const float* beta) {
    k_bn_partial<<<dim3(2048), dim3(256), 0, stream>>>(buf, PART, hw);
    k_bn_finalize<<<dim3(1), dim3(64), 0, stream>>>(PART, gamma, beta, STATS, hw);
    int total = 32 * 32 * 4 * hw;
    k_bn_apply_relu<<<dim3(cdiv(total, 256)), dim3(256), 0, stream>>>(buf, STATS, hw);
  };

  auto gg_layer = [&](const float* in, float* outb, int hin, int O,
                      const float* w, const float* bias, const float* aw) {
    int hw = hin * hin;
    int nred = 32 * 4 * hw;
    k_reduce_meanmax<<<dim3(cdiv(nred, 256)), dim3(256), 0, stream>>>(in, AMAP, hw);
    k_att_gg<<<dim3(cdiv(nred, 256)), dim3(256), 0, stream>>>(AMAP, aw, ATT, hin);
    int nw = 4 * O * 9 * 128;
    k_prep_w<<<dim3(cdiv(nw, 256)), dim3(256), 0, stream>>>(w, WROT, O);
    int ho = hin - 2, howo = ho * ho;
    dim3 grid(cdiv(howo, 256), 32 * O * 4);
    k_conv_gg<<<grid, dim3(256), 0, stream>>>(in, ATT, WROT, bias, outb, O, hin);
  };

  // ---- layer 1: attentive lifting conv + bn + relu ----
  {
    int natt = 32 * 4 * 48 * 48;
    k_att_lift<<<dim3(cdiv(natt, 256)), dim3(256), 0, stream>>>(x, aw1, ATT);
    int n1 = 32 * 32 * 4 * 46 * 46;
    k_conv_lift<<<dim3(cdiv(n1, 256)), dim3(256), 0, stream>>>(x, ATT, w1, b1, A);
    bn_relu(A, 46 * 46, G[0], BE[0]);
  }
  // ---- layer 2 + pool ----
  gg_layer(A, Bb, 46, 32, W[0], BI[0], AW[0]);
  bn_relu(Bb, 44 * 44, G[1], BE[1]);
  {
    int np = 32 * 32 * 4 * 22 * 22;
    k_pool<<<dim3(cdiv(np, 256)), dim3(256), 0, stream>>>(Bb, A);
  }
  // ---- layers 3..6 ----
  gg_layer(A, Bb, 22, 32, W[1], BI[1], AW[1]);  bn_relu(Bb, 20 * 20, G[2], BE[2]);
  gg_layer(Bb, A, 20, 32, W[2], BI[2], AW[2]);  bn_relu(A, 18 * 18, G[3], BE[3]);
  gg_layer(A, Bb, 18, 32, W[3], BI[3], AW[3]);  bn_relu(Bb, 16 * 16, G[4], BE[4]);
  gg_layer(Bb, A, 16, 32, W[4], BI[4], AW[4]);  bn_relu(A, 14 * 14, G[5], BE[5]);
  // ---- layer 7 (classifier, no bn/relu) ----
  gg_layer(A, Bb, 14, 10, W[5], BI[5], AW[5]);
  // ---- rotation max + spatial mean ----
  k_final<<<dim3(5), dim3(64), 0, stream>>>(Bb, out);
}

// Round 2
// 1272.209 us; speedup vs baseline: 2.9364x; 2.9364x over previous
//
#include <hip/hip_runtime.h>
#include <cstddef>

#define DINL static __device__ __forceinline__

// rot90 applied r times (counter-clockwise, numpy convention):
// rotated_r[i][j] = w[si][sj]
DINL void rot_src(int r, int K, int i, int j, int& si, int& sj) {
  switch (r & 3) {
    case 0:  si = i;       sj = j;       break;
    case 1:  si = j;       sj = K-1-i;   break;
    case 2:  si = K-1-i;   sj = K-1-j;   break;
    default: si = K-1-j;   sj = i;       break;
  }
}

DINL float sigmoidf(float s) { return 1.f / (1.f + __expf(-s)); }

// ---------------- layer 1 (lifting) ----------------

__global__ void k_att_lift(const float* __restrict__ x, const float* __restrict__ aw,
                           float* __restrict__ att) {
  const int H = 48, HW = H * H;
  int idx = blockIdx.x * blockDim.x + threadIdx.x;
  if (idx >= 32 * 4 * HW) return;
  int xw = idx % H; int t = idx / H;
  int yh = t % H;  t /= H;
  int r  = t & 3;  int b = t >> 2;
  const float* xb = x + b * HW;
  float s = 0.f;
  for (int ky = 0; ky < 7; ++ky) {
    int y = yh + ky - 3;
    if ((unsigned)y >= (unsigned)H) continue;
    for (int kx = 0; kx < 7; ++kx) {
      int xx = xw + kx - 3;
      if ((unsigned)xx >= (unsigned)H) continue;
      int si, sj; rot_src(r, 7, ky, kx, si, sj);
      s += xb[y * H + xx] * (aw[si * 7 + sj] + aw[49 + si * 7 + sj]);
    }
  }
  att[idx] = sigmoidf(s);
}

__global__ void __launch_bounds__(256)
k_conv_lift(const float* __restrict__ x, const float* __restrict__ att,
            const float* __restrict__ w, const float* __restrict__ bias,
            float* __restrict__ y) {
  const int HI = 48, HO = 46;
  int idx = blockIdx.x * blockDim.x + threadIdx.x;
  if (idx >= 32 * 32 * 4 * HO * HO) return;
  int xo = idx % HO; int t = idx / HO;
  int yo = t % HO;  t /= HO;
  int r  = t & 3;   t >>= 2;
  int o  = t & 31;  int b = t >> 5;
  const float* xb = x + b * HI * HI;
  const float* ab = att + (b * 4 + r) * HI * HI;
  float acc = bias[o];
  #pragma unroll
  for (int ky = 0; ky < 3; ++ky)
    #pragma unroll
    for (int kx = 0; kx < 3; ++kx) {
      int si, sj; rot_src(r, 3, ky, kx, si, sj);
      int p = (yo + ky) * HI + xo + kx;
      acc = fmaf(ab[p] * xb[p], w[o * 9 + si * 3 + sj], acc);
    }
  y[idx] = acc;
}

// ---------------- GG layers ----------------

// a[b][ci(2)][g][sp]: ci=0 mean over 32 channels, ci=1 max. input [B,32,4,hw]
__global__ void k_reduce_meanmax(const float* __restrict__ xin, float* __restrict__ a,
                                 int hw) {
  int idx = blockIdx.x * blockDim.x + threadIdx.x;
  if (idx >= 32 * 4 * hw) return;
  int sp = idx % hw; int t = idx / hw;
  int g = t & 3; int b = t >> 2;
  const float* p = xin + (size_t)(b * 32 * 4 + g) * hw + sp;
  float s = 0.f, m = -INFINITY;
  for (int c = 0; c < 32; ++c) {
    float v = p[(size_t)c * 4 * hw];
    s += v; m = fmaxf(m, v);
  }
  a[((b * 2 + 0) * 4 + g) * hw + sp] = s * (1.f / 32.f);
  a[((b * 2 + 1) * 4 + g) * hw + sp] = m;
}

// att[b][r][sp] = sigmoid( gg_conv7x7(a, aw)[b,0,r,sp] ), 'same' padding
__global__ void k_att_gg(const float* __restrict__ a, const float* __restrict__ aw,
                         float* __restrict__ att, int h) {
  int hw = h * h;
  int idx = blockIdx.x * blockDim.x + threadIdx.x;
  if (idx >= 32 * 4 * hw) return;
  int xw = idx % h; int t = idx / h;
  int yh = t % h;  t /= h;
  int r = t & 3;  int b = t >> 2;
  float s = 0.f;
  for (int ky = 0; ky < 7; ++ky) {
    int y = yh + ky - 3;
    if ((unsigned)y >= (unsigned)h) continue;
    for (int kx = 0; kx < 7; ++kx) {
      int xx = xw + kx - 3;
      if ((unsigned)xx >= (unsigned)h) continue;
      int si, sj; rot_src(r, 7, ky, kx, si, sj);
      int sp = y * h + xx;
      #pragma unroll
      for (int ci = 0; ci < 2; ++ci)
        #pragma unroll
        for (int g = 0; g < 4; ++g) {
          int gs = (g - r) & 3;
          s += a[((b * 2 + ci) * 4 + g) * hw + sp] * aw[(ci * 4 + gs) * 49 + si * 7 + sj];
        }
    }
  }
  att[idx] = sigmoidf(s);
}

// weight prep into [r][og][tap][cg][o8] layout (o8 = o within group of 8):
// wrot[(((r*OG+og)*9+tap)*128+cg)*8+oi] = w[o][ci][(g-r)&3][rot_r(tap)], o=og*8+oi
__global__ void k_prep_w(const float* __restrict__ w, float* __restrict__ wrot,
                         int O, int OG) {
  int idx = blockIdx.x * blockDim.x + threadIdx.x;
  int total = 4 * OG * 9 * 128 * 8;
  if (idx >= total) return;
  int oi = idx & 7; int t = idx >> 3;
  int cg = t & 127; t >>= 7;
  int tap = t % 9; t /= 9;
  int og = t % OG; int r = t / OG;
  int o = og * 8 + oi;
  int g = cg & 3, ci = cg >> 2;
  int ky = tap / 3, kx = tap % 3;
  int si, sj; rot_src(r, 3, ky, kx, si, sj);
  int gs = (g - r) & 3;
  wrot[idx] = (o < O) ? w[((o * 32 + ci) * 4 + gs) * 9 + si * 3 + sj] : 0.f;
}

// Register-tiled attentive GG conv: each thread computes 8 output channels x
// 4 consecutive output columns for fixed (b, r, og). Weights wave-uniform in
// LDS (broadcast reads, conflict-free); each x load feeds 16 FMAs.
// grid: (ceil(ho*ceil(ho/4)/256), 32*4*OG)
__global__ void __launch_bounds__(256)
k_conv_gg(const float* __restrict__ xin, const float* __restrict__ att,
          const float* __restrict__ wrot, const float* __restrict__ bias,
          float* __restrict__ y, int O, int OG, int h) {
  __shared__ float ws_w[9 * 128 * 8];  // 36864 B
  const int ho = h - 2, hw = h * h;
  const int CG = (ho + 3) >> 2;
  int t = blockIdx.y;
  int og = t % OG; t /= OG;
  int r = t & 3; int b = t >> 2;
  const float* wsrc = wrot + (size_t)(r * OG + og) * 9216;
  for (int i = threadIdx.x; i < 9216; i += 256) ws_w[i] = wsrc[i];
  __syncthreads();
  int item = blockIdx.x * 256 + threadIdx.x;
  int items = ho * CG;
  if (item >= items) return;
  int yrow = item / CG;
  int c0 = (item % CG) * 4;
  const float* xb = xin + (size_t)b * 128 * hw;
  const float* ab = att + (size_t)(b * 4 + r) * hw;

  float acc[8][4];
  #pragma unroll
  for (int oi = 0; oi < 8; ++oi) {
    int o = og * 8 + oi;
    float bv = (o < O) ? bias[o] : 0.f;
    #pragma unroll
    for (int j = 0; j < 4; ++j) acc[oi][j] = bv;
  }

  #pragma unroll
  for (int ky = 0; ky < 3; ++ky) {
    const int rowoff = (yrow + ky) * h + c0;
    float av[6];
    #pragma unroll
    for (int j = 0; j < 6; ++j) av[j] = ab[rowoff + j];
    const float* wk = ws_w + ky * 3 * 128 * 8;
    const float* xr = xb + rowoff;
    #pragma unroll 2
    for (int cg = 0; cg < 128; ++cg) {
      float xa[6];
      #pragma unroll
      for (int j = 0; j < 6; ++j) xa[j] = xr[(size_t)cg * hw + j] * av[j];
      #pragma unroll
      for (int kx = 0; kx < 3; ++kx) {
        const float* wp = wk + (kx * 128 + cg) * 8;
        #pragma unroll
        for (int oi = 0; oi < 8; ++oi) {
          float wv = wp[oi];
          #pragma unroll
          for (int j = 0; j < 4; ++j)
            acc[oi][j] = fmaf(xa[kx + j], wv, acc[oi][j]);
        }
      }
    }
  }

  #pragma unroll
  for (int oi = 0; oi < 8; ++oi) {
    int o = og * 8 + oi;
    if (o < O) {
      float* yp = y + ((size_t)((b * O + o) * 4 + r) * ho + yrow) * ho + c0;
      #pragma unroll
      for (int j = 0; j < 4; ++j)
        if (c0 + j < ho) yp[j] = acc[oi][j];
    }
  }
}

// ---------------- BatchNorm3d (training-mode batch stats) ----------------

__global__ void k_bn_partial(const float* __restrict__ y, float* __restrict__ part,
                             int hw) {
  __shared__ float s1s[256], s2s[256];
  int c = blockIdx.x >> 6;
  int s = blockIdx.x & 63;
  int N = 32 * 4 * hw;
  float s1 = 0.f, s2 = 0.f;
  for (int j = s * 256 + threadIdx.x; j < N; j += 64 * 256) {
    int sp = j % hw; int bg = j / hw;
    int g = bg & 3; int b = bg >> 2;
    float v = y[(size_t)((b * 32 + c) * 4 + g) * hw + sp];
    s1 += v; s2 += v * v;
  }
  s1s[threadIdx.x] = s1; s2s[threadIdx.x] = s2;
  __syncthreads();
  for (int off = 128; off > 0; off >>= 1) {
    if (threadIdx.x < off) {
      s1s[threadIdx.x] += s1s[threadIdx.x + off];
      s2s[threadIdx.x] += s2s[threadIdx.x + off];
    }
    __syncthreads();
  }
  if (threadIdx.x == 0) {
    part[blockIdx.x] = s1s[0];
    part[2048 + blockIdx.x] = s2s[0];
  }
}

__global__ void k_bn_finalize(const float* __restrict__ part,
                              const float* __restrict__ gamma,
                              const float* __restrict__ beta,
                              float* __restrict__ stats, int hw) {
  int c = threadIdx.x;
  if (c >= 32) return;
  float s1 = 0.f, s2 = 0.f;
  for (int s = 0; s < 64; ++s) { s1 += part[c * 64 + s]; s2 += part[2048 + c * 64 + s]; }
  float N = 32.f * 4.f * (float)hw;
  float m = s1 / N;
  float v = s2 / N - m * m;
  float inv = rsqrtf(v + 2e-5f);
  float sc = gamma[c] * inv;
  stats[c] = sc;
  stats[32 + c] = beta[c] - m * sc;
}

__global__ void k_bn_apply_relu(float* __restrict__ y, const float* __restrict__ stats,
                                int hw) {
  int idx = blockIdx.x * blockDim.x + threadIdx.x;
  if (idx >= 32 * 32 * 4 * hw) return;
  int c = (idx / (4 * hw)) & 31;
  y[idx] = fmaxf(fmaf(y[idx], stats[c], stats[32 + c]), 0.f);
}

// ---------------- pool + final ----------------

__global__ void k_pool(const float* __restrict__ yin, float* __restrict__ yout) {
  const int HI = 44, HO = 22;
  int idx = blockIdx.x * blockDim.x + threadIdx.x;
  if (idx >= 32 * 32 * 4 * HO * HO) return;
  int xo = idx % HO; int t = idx / HO;
  int yo = t % HO; int bcg = t / HO;
  const float* p = yin + ((size_t)bcg * HI + yo * 2) * HI + xo * 2;
  yout[idx] = fmaxf(fmaxf(p[0], p[1]), fmaxf(p[HI], p[HI + 1]));
}

__global__ void k_final(const float* __restrict__ y7, float* __restrict__ out) {
  int idx = blockIdx.x * blockDim.x + threadIdx.x;
  if (idx >= 320) return;
  int o = idx % 10; int b = idx / 10;
  const float* p = y7 + (size_t)((b * 10 + o) * 4) * 144;
  float s = 0.f;
  for (int sp = 0; sp < 144; ++sp) {
    float m = fmaxf(fmaxf(p[sp], p[144 + sp]), fmaxf(p[288 + sp], p[432 + sp]));
    s += m;
  }
  out[idx] = s * (1.f / 144.f);
}

// ---------------- host ----------------

extern "C" void kernel_launch(void* const* d_in, const int* in_sizes, int n_in,
                              void* d_out, int out_size, void* d_ws, size_t ws_size,
                              hipStream_t stream) {
  (void)in_sizes; (void)n_in; (void)out_size; (void)ws_size;
  const float* x   = (const float*)d_in[0];
  const float* w1  = (const float*)d_in[1];
  const float* b1  = (const float*)d_in[2];
  const float* aw1 = (const float*)d_in[3];
  const float* W[6];  const float* BI[6]; const float* AW[6];
  for (int i = 0; i < 6; ++i) {
    W[i]  = (const float*)d_in[4 + 3 * i];
    BI[i] = (const float*)d_in[5 + 3 * i];
    AW[i] = (const float*)d_in[6 + 3 * i];
  }
  const float* G[6]; const float* BE[6];
  for (int i = 0; i < 6; ++i) {
    G[i]  = (const float*)d_in[22 + 2 * i];
    BE[i] = (const float*)d_in[23 + 2 * i];
  }
  float* out = (float*)d_out;

  // workspace layout (floats); total ~18.4M floats = 73.6 MB
  float* ws    = (float*)d_ws;
  float* A     = ws;                 // 8,700,000
  float* Bb    = ws + 8700000;       // 8,700,000
  float* AMAP  = ws + 17400000;      //   550,000
  float* ATT   = ws + 17950000;      //   300,000
  float* WROT  = ws + 18250000;      //   150,000 (max 147,456)
  float* PART  = ws + 18400000;      //     4,096
  float* STATS = ws + 18404096;      //        64

  auto cdiv = [](int a, int b) { return (a + b - 1) / b; };

  auto bn_relu = [&](float* buf, int hw, const float* gamma, const float* beta) {
    k_bn_partial<<<dim3(2048), dim3(256), 0, stream>>>(buf, PART, hw);
    k_bn_finalize<<<dim3(1), dim3(64), 0, stream>>>(PART, gamma, beta, STATS, hw);
    int total = 32 * 32 * 4 * hw;
    k_bn_apply_relu<<<dim3(cdiv(total, 256)), dim3(256), 0, stream>>>(buf, STATS, hw);
  };

  auto gg_layer = [&](const float* in, float* outb, int hin, int O,
                      const float* w, const float* bias, const float* aw) {
    int hw = hin * hin;
    int nred = 32 * 4 * hw;
    k_reduce_meanmax<<<dim3(cdiv(nred, 256)), dim3(256), 0, stream>>>(in, AMAP, hw);
    k_att_gg<<<dim3(cdiv(nred, 256)), dim3(256), 0, stream>>>(AMAP, aw, ATT, hin);
    int OG = cdiv(O, 8);
    int nw = 4 * OG * 9 * 128 * 8;
    k_prep_w<<<dim3(cdiv(nw, 256)), dim3(256), 0, stream>>>(w, WROT, O, OG);
    int ho = hin - 2;
    int CG = (ho + 3) >> 2;
    int items = ho * CG;
    dim3 grid(cdiv(items, 256), 32 * 4 * OG);
    k_conv_gg<<<grid, dim3(256), 0, stream>>>(in, ATT, WROT, bias, outb, O, OG, hin);
  };

  // ---- layer 1: attentive lifting conv + bn + relu ----
  {
    int natt = 32 * 4 * 48 * 48;
    k_att_lift<<<dim3(cdiv(natt, 256)), dim3(256), 0, stream>>>(x, aw1, ATT);
    int n1 = 32 * 32 * 4 * 46 * 46;
    k_conv_lift<<<dim3(cdiv(n1, 256)), dim3(256), 0, stream>>>(x, ATT, w1, b1, A);
    bn_relu(A, 46 * 46, G[0], BE[0]);
  }
  // ---- layer 2 + pool ----
  gg_layer(A, Bb, 46, 32, W[0], BI[0], AW[0]);
  bn_relu(Bb, 44 * 44, G[1], BE[1]);
  {
    int np = 32 * 32 * 4 * 22 * 22;
    k_pool<<<dim3(cdiv(np, 256)), dim3(256), 0, stream>>>(Bb, A);
  }
  // ---- layers 3..6 ----
  gg_layer(A, Bb, 22, 32, W[1], BI[1], AW[1]);  bn_relu(Bb, 20 * 20, G[2], BE[2]);
  gg_layer(Bb, A, 20, 32, W[2], BI[2], AW[2]);  bn_relu(A, 18 * 18, G[3], BE[3]);
  gg_layer(A, Bb, 18, 32, W[3], BI[3], AW[3]);  bn_relu(Bb, 16 * 16, G[4], BE[4]);
  gg_layer(Bb, A, 16, 32, W[4], BI[4], AW[4]);  bn_relu(A, 14 * 14, G[5], BE[5]);
  // ---- layer 7 (classifier, no bn/relu) ----
  gg_layer(A, Bb, 14, 10, W[5], BI[5], AW[5]);
  // ---- rotation max + spatial mean ----
  k_final<<<dim3(5), dim3(64), 0, stream>>>(Bb, out);
}

// Round 3
// 1155.965 us; speedup vs baseline: 3.2317x; 1.1006x over previous
//
#include <hip/hip_runtime.h>
#include <cstddef>

#define DINL static __device__ __forceinline__

// rot90 applied r times (counter-clockwise, numpy convention):
// rotated_r[i][j] = w[si][sj]
DINL void rot_src(int r, int K, int i, int j, int& si, int& sj) {
  switch (r & 3) {
    case 0:  si = i;       sj = j;       break;
    case 1:  si = j;       sj = K-1-i;   break;
    case 2:  si = K-1-i;   sj = K-1-j;   break;
    default: si = K-1-j;   sj = i;       break;
  }
}

DINL float sigmoidf(float s) { return 1.f / (1.f + __expf(-s)); }

// ---------------- layer 1 (lifting) ----------------

__global__ void k_att_lift(const float* __restrict__ x, const float* __restrict__ aw,
                           float* __restrict__ att) {
  const int H = 48, HW = H * H;
  int idx = blockIdx.x * blockDim.x + threadIdx.x;
  if (idx >= 32 * 4 * HW) return;
  int xw = idx % H; int t = idx / H;
  int yh = t % H;  t /= H;
  int r  = t & 3;  int b = t >> 2;
  const float* xb = x + b * HW;
  float s = 0.f;
  for (int ky = 0; ky < 7; ++ky) {
    int y = yh + ky - 3;
    if ((unsigned)y >= (unsigned)H) continue;
    for (int kx = 0; kx < 7; ++kx) {
      int xx = xw + kx - 3;
      if ((unsigned)xx >= (unsigned)H) continue;
      int si, sj; rot_src(r, 7, ky, kx, si, sj);
      s += xb[y * H + xx] * (aw[si * 7 + sj] + aw[49 + si * 7 + sj]);
    }
  }
  att[idx] = sigmoidf(s);
}

__global__ void __launch_bounds__(256)
k_conv_lift(const float* __restrict__ x, const float* __restrict__ att,
            const float* __restrict__ w, const float* __restrict__ bias,
            float* __restrict__ y) {
  const int HI = 48, HO = 46;
  int idx = blockIdx.x * blockDim.x + threadIdx.x;
  if (idx >= 32 * 32 * 4 * HO * HO) return;
  int xo = idx % HO; int t = idx / HO;
  int yo = t % HO;  t /= HO;
  int r  = t & 3;   t >>= 2;
  int o  = t & 31;  int b = t >> 5;
  const float* xb = x + b * HI * HI;
  const float* ab = att + (b * 4 + r) * HI * HI;
  float acc = bias[o];
  #pragma unroll
  for (int ky = 0; ky < 3; ++ky)
    #pragma unroll
    for (int kx = 0; kx < 3; ++kx) {
      int si, sj; rot_src(r, 3, ky, kx, si, sj);
      int p = (yo + ky) * HI + xo + kx;
      acc = fmaf(ab[p] * xb[p], w[o * 9 + si * 3 + sj], acc);
    }
  y[idx] = acc;
}

// ---------------- attention (GG) ----------------

// att[b][r][sp] = sigmoid( gg_conv7x7(amap, aw)[b,0,r,sp] ), 'same' padding
__global__ void k_att_gg(const float* __restrict__ a, const float* __restrict__ aw,
                         float* __restrict__ att, int h) {
  int hw = h * h;
  int idx = blockIdx.x * blockDim.x + threadIdx.x;
  if (idx >= 32 * 4 * hw) return;
  int xw = idx % h; int t = idx / h;
  int yh = t % h;  t /= h;
  int r = t & 3;  int b = t >> 2;
  float s = 0.f;
  for (int ky = 0; ky < 7; ++ky) {
    int y = yh + ky - 3;
    if ((unsigned)y >= (unsigned)h) continue;
    for (int kx = 0; kx < 7; ++kx) {
      int xx = xw + kx - 3;
      if ((unsigned)xx >= (unsigned)h) continue;
      int si, sj; rot_src(r, 7, ky, kx, si, sj);
      int sp = y * h + xx;
      #pragma unroll
      for (int ci = 0; ci < 2; ++ci)
        #pragma unroll
        for (int g = 0; g < 4; ++g) {
          int gs = (g - r) & 3;
          s += a[((b * 2 + ci) * 4 + g) * hw + sp] * aw[(ci * 4 + gs) * 49 + si * 7 + sj];
        }
    }
  }
  att[idx] = sigmoidf(s);
}

// ---------------- attentive GG conv (templated, register-tiled) ----------------
//
// Each thread: OT output channels x NT consecutive columns for fixed (b,r,og).
// Weights gathered+rotated into LDS at block start (wave-uniform broadcast reads).
// XS=true (layer-2 only): 1D grid swizzled so blockIdx%8 == b%8 -> all blocks
// sharing a batch slice land on one XCD (round-robin model) for L2 reuse.
template<int H, int OT, int NT, int O, bool XS>
__global__ void __launch_bounds__(256)
k_conv_gg(const float* __restrict__ xin, const float* __restrict__ att,
          const float* __restrict__ w, const float* __restrict__ bias,
          float* __restrict__ y) {
  constexpr int HO = H - 2, HW = H * H;
  constexpr int CG = (HO + NT - 1) / NT;
  constexpr int OG = (O + OT - 1) / OT;
  constexpr int IPB = HO * CG;  // spatial items per batch image
  __shared__ float ws_w[9 * 128 * OT];

  int r, og, item;
  if constexpr (XS) {
    // id = slot + 8*k ; k = chunk(1b) | og(2b) | r(2b) | bhi(2b); b = bhi*8+slot
    int id = blockIdx.x;
    int slot = id & 7, k = id >> 3;
    int chunk = k & 1; int t2 = k >> 1;
    og = t2 & 3; t2 >>= 2;
    r = t2 & 3; int bhi = t2 >> 2;
    int within = chunk * 256 + threadIdx.x;
    item = (within < IPB) ? ((bhi * 8 + slot) * IPB + within) : -1;
  } else {
    int t2 = blockIdx.y;
    og = t2 % OG; r = t2 / OG;
    item = blockIdx.x * 256 + threadIdx.x;
    if (item >= 32 * IPB) item = -1;
  }

  // stage weights with on-the-fly p4 rotation: layout [tap][cg][oi]
  for (int i = threadIdx.x; i < 9 * 128 * OT; i += 256) {
    int oi = i % OT; int t3 = i / OT;
    int cg = t3 & 127; int tap = t3 >> 7;
    int o = og * OT + oi;
    int g = cg & 3, ci = cg >> 2;
    int ky = tap / 3, kx = tap % 3;
    int si, sj; rot_src(r, 3, ky, kx, si, sj);
    int gs = (g - r) & 3;
    ws_w[i] = (o < O) ? w[((o * 32 + ci) * 4 + gs) * 9 + si * 3 + sj] : 0.f;
  }
  __syncthreads();
  if (item < 0) return;

  int b = item / IPB; int rem = item % IPB;
  int yrow = rem / CG, c0 = (rem % CG) * NT;
  const float* xb = xin + (size_t)b * 128 * HW;
  const float* ab = att + (size_t)(b * 4 + r) * HW;

  float acc[OT][NT];
  #pragma unroll
  for (int oi = 0; oi < OT; ++oi) {
    int o = og * OT + oi;
    float bv = (o < O) ? bias[o] : 0.f;
    #pragma unroll
    for (int j = 0; j < NT; ++j) acc[oi][j] = bv;
  }

  #pragma unroll
  for (int ky = 0; ky < 3; ++ky) {
    const int rowoff = (yrow + ky) * H + c0;
    float av[NT + 2];
    #pragma unroll
    for (int j = 0; j < NT + 2; ++j) av[j] = ab[rowoff + j];
    const float* wk = ws_w + ky * 3 * 128 * OT;
    const float* xr = xb + rowoff;
    #pragma unroll 2
    for (int cg = 0; cg < 128; ++cg) {
      float xa[NT + 2];
      #pragma unroll
      for (int j = 0; j < NT + 2; ++j) xa[j] = xr[j] * av[j];
      #pragma unroll
      for (int kx = 0; kx < 3; ++kx) {
        const float* wp = wk + (kx * 128 + cg) * OT;
        #pragma unroll
        for (int oi = 0; oi < OT; ++oi) {
          float wv = wp[oi];
          #pragma unroll
          for (int j = 0; j < NT; ++j)
            acc[oi][j] = fmaf(xa[kx + j], wv, acc[oi][j]);
        }
      }
      xr += HW;
    }
  }

  #pragma unroll
  for (int oi = 0; oi < OT; ++oi) {
    int o = og * OT + oi;
    if (o < O) {
      float* yp = y + (((size_t)(b * O + o) * 4 + r) * HO + yrow) * HO + c0;
      #pragma unroll
      for (int j = 0; j < NT; ++j)
        if (c0 + j < HO) yp[j] = acc[oi][j];
    }
  }
}

// ---------------- BatchNorm3d stats (training-mode batch stats) ----------------

__global__ void k_bn_partial(const float* __restrict__ y, float* __restrict__ part,
                             int hw, int S) {
  __shared__ float s1s[256], s2s[256];
  int c = blockIdx.x / S;
  int s = blockIdx.x % S;
  int N = 32 * 4 * hw;
  float s1 = 0.f, s2 = 0.f;
  for (int j = s * 256 + threadIdx.x; j < N; j += S * 256) {
    int sp = j % hw; int bg = j / hw;
    int g = bg & 3; int b = bg >> 2;
    float v = y[(size_t)((b * 32 + c) * 4 + g) * hw + sp];
    s1 += v; s2 += v * v;
  }
  s1s[threadIdx.x] = s1; s2s[threadIdx.x] = s2;
  __syncthreads();
  for (int off = 128; off > 0; off >>= 1) {
    if (threadIdx.x < off) {
      s1s[threadIdx.x] += s1s[threadIdx.x + off];
      s2s[threadIdx.x] += s2s[threadIdx.x + off];
    }
    __syncthreads();
  }
  if (threadIdx.x == 0) {
    part[c * 64 + s] = s1s[0];
    part[2048 + c * 64 + s] = s2s[0];
  }
}

__global__ void k_bn_finalize(const float* __restrict__ part,
                              const float* __restrict__ gamma,
                              const float* __restrict__ beta,
                              float* __restrict__ stats, int hw, int S) {
  int c = threadIdx.x;
  if (c >= 32) return;
  float s1 = 0.f, s2 = 0.f;
  for (int s = 0; s < S; ++s) { s1 += part[c * 64 + s]; s2 += part[2048 + c * 64 + s]; }
  float N = 32.f * 4.f * (float)hw;
  float m = s1 / N;
  float v = s2 / N - m * m;
  float inv = rsqrtf(v + 2e-5f);
  float sc = gamma[c] * inv;
  stats[c] = sc;
  stats[32 + c] = beta[c] - m * sc;
}

// ---------------- fused BN-apply + ReLU + channel mean/max (+pool) ----------------

// reads raw y [B,32,4,hw]; writes normalized xn (same layout) and
// amap [B,2,4,hw] (ci=0 mean, ci=1 max over the 32 channels)
__global__ void k_meanmax_bn(const float* __restrict__ y, const float* __restrict__ stats,
                             float* __restrict__ xn, float* __restrict__ amap, int hw) {
  int idx = blockIdx.x * blockDim.x + threadIdx.x;
  if (idx >= 32 * 4 * hw) return;
  int sp = idx % hw; int t = idx / hw;
  int g = t & 3; int b = t >> 2;
  size_t base = ((size_t)(b * 32) * 4 + g) * hw + sp;
  float s = 0.f, m = -INFINITY;
  for (int c = 0; c < 32; ++c) {
    size_t off = base + (size_t)c * 4 * hw;
    float v = fmaxf(fmaf(y[off], stats[c], stats[32 + c]), 0.f);
    xn[off] = v;
    s += v; m = fmaxf(m, v);
  }
  amap[((b * 2 + 0) * 4 + g) * hw + sp] = s * (1.f / 32.f);
  amap[((b * 2 + 1) * 4 + g) * hw + sp] = m;
}

// layer-2 variant: BN+ReLU on 44x44, then 2x2 maxpool -> xn/amap at 22x22
__global__ void k_meanmax_bn_pool(const float* __restrict__ y, const float* __restrict__ stats,
                                  float* __restrict__ xn, float* __restrict__ amap) {
  const int HI = 44, HWI = HI * HI, HOq = 22, HWO = HOq * HOq;
  int idx = blockIdx.x * blockDim.x + threadIdx.x;
  if (idx >= 32 * 4 * HWO) return;
  int sp = idx % HWO; int t = idx / HWO;
  int g = t & 3; int b = t >> 2;
  int x22 = sp % HOq, y22 = sp / HOq;
  int in0 = (y22 * 2) * HI + x22 * 2;
  float s = 0.f, m = -INFINITY;
  for (int c = 0; c < 32; ++c) {
    const float* yp = y + ((size_t)((b * 32 + c) * 4) + g) * HWI + in0;
    float sc = stats[c], sh = stats[32 + c];
    float v0 = fmaxf(fmaf(yp[0],      sc, sh), 0.f);
    float v1 = fmaxf(fmaf(yp[1],      sc, sh), 0.f);
    float v2 = fmaxf(fmaf(yp[HI],     sc, sh), 0.f);
    float v3 = fmaxf(fmaf(yp[HI + 1], sc, sh), 0.f);
    float v = fmaxf(fmaxf(v0, v1), fmaxf(v2, v3));
    xn[((size_t)((b * 32 + c) * 4) + g) * HWO + sp] = v;
    s += v; m = fmaxf(m, v);
  }
  amap[((b * 2 + 0) * 4 + g) * HWO + sp] = s * (1.f / 32.f);
  amap[((b * 2 + 1) * 4 + g) * HWO + sp] = m;
}

// ---------------- final: rotation max + spatial mean ----------------

__global__ void k_final(const float* __restrict__ y7, float* __restrict__ out) {
  int idx = blockIdx.x * blockDim.x + threadIdx.x;
  if (idx >= 320) return;
  int o = idx % 10; int b = idx / 10;
  const float* p = y7 + (size_t)((b * 10 + o) * 4) * 144;
  float s = 0.f;
  for (int sp = 0; sp < 144; ++sp) {
    float m = fmaxf(fmaxf(p[sp], p[144 + sp]), fmaxf(p[288 + sp], p[432 + sp]));
    s += m;
  }
  out[idx] = s * (1.f / 144.f);
}

// ---------------- host ----------------

extern "C" void kernel_launch(void* const* d_in, const int* in_sizes, int n_in,
                              void* d_out, int out_size, void* d_ws, size_t ws_size,
                              hipStream_t stream) {
  (void)in_sizes; (void)n_in; (void)out_size; (void)ws_size;
  const float* x   = (const float*)d_in[0];
  const float* w1  = (const float*)d_in[1];
  const float* b1  = (const float*)d_in[2];
  const float* aw1 = (const float*)d_in[3];
  const float* W[6];  const float* BI[6]; const float* AW[6];
  for (int i = 0; i < 6; ++i) {
    W[i]  = (const float*)d_in[4 + 3 * i];
    BI[i] = (const float*)d_in[5 + 3 * i];
    AW[i] = (const float*)d_in[6 + 3 * i];
  }
  const float* G[6]; const float* BE[6];
  for (int i = 0; i < 6; ++i) {
    G[i]  = (const float*)d_in[22 + 2 * i];
    BE[i] = (const float*)d_in[23 + 2 * i];
  }
  float* out = (float*)d_out;

  // workspace (floats): A raw conv out, B normalized input; ~73 MB total
  float* ws    = (float*)d_ws;
  float* A     = ws;                 // 8,700,000
  float* Bb    = ws + 8700000;       // 8,700,000
  float* AMAP  = ws + 17400000;      //   550,000 (max 541,696)
  float* ATT   = ws + 17950000;      //   300,000 (max 294,912)
  float* PART  = ws + 18250000;      //     4,096
  float* STATS = ws + 18254096;      //        64

  auto cdiv = [](int a, int b) { return (a + b - 1) / b; };
  auto Sfor = [&](int hw) {
    int N = 32 * 4 * hw;
    int S = (N + 16383) / 16384;
    return S > 64 ? 64 : (S < 1 ? 1 : S);
  };

  auto bn_stats = [&](const float* buf, int hw, const float* gamma, const float* beta) {
    int S = Sfor(hw);
    k_bn_partial<<<dim3(32 * S), dim3(256), 0, stream>>>(buf, PART, hw, S);
    k_bn_finalize<<<dim3(1), dim3(64), 0, stream>>>(PART, gamma, beta, STATS, hw, S);
  };

  // ---- layer 1: attentive lifting conv ----
  {
    int natt = 32 * 4 * 48 * 48;
    k_att_lift<<<dim3(cdiv(natt, 256)), dim3(256), 0, stream>>>(x, aw1, ATT);
    int n1 = 32 * 32 * 4 * 46 * 46;
    k_conv_lift<<<dim3(cdiv(n1, 256)), dim3(256), 0, stream>>>(x, ATT, w1, b1, A);
    bn_stats(A, 46 * 46, G[0], BE[0]);
    int nmm = 32 * 4 * 46 * 46;
    k_meanmax_bn<<<dim3(cdiv(nmm, 256)), dim3(256), 0, stream>>>(A, STATS, Bb, AMAP, 46 * 46);
    k_att_gg<<<dim3(cdiv(nmm, 256)), dim3(256), 0, stream>>>(AMAP, AW[0], ATT, 46);
  }
  // ---- layer 2 (XCD-swizzled conv) + pool ----
  {
    k_conv_gg<46, 8, 4, 32, true><<<dim3(1024), dim3(256), 0, stream>>>(Bb, ATT, W[0], BI[0], A);
    bn_stats(A, 44 * 44, G[1], BE[1]);
    int nmm = 32 * 4 * 22 * 22;
    k_meanmax_bn_pool<<<dim3(cdiv(nmm, 256)), dim3(256), 0, stream>>>(A, STATS, Bb, AMAP);
    k_att_gg<<<dim3(cdiv(nmm, 256)), dim3(256), 0, stream>>>(AMAP, AW[1], ATT, 22);
  }
  // ---- layer 3: h=22 -> 20 ----
  {
    k_conv_gg<22, 8, 2, 32, false><<<dim3(25, 16), dim3(256), 0, stream>>>(Bb, ATT, W[1], BI[1], A);
    bn_stats(A, 20 * 20, G[2], BE[2]);
    int nmm = 32 * 4 * 20 * 20;
    k_meanmax_bn<<<dim3(cdiv(nmm, 256)), dim3(256), 0, stream>>>(A, STATS, Bb, AMAP, 20 * 20);
    k_att_gg<<<dim3(cdiv(nmm, 256)), dim3(256), 0, stream>>>(AMAP, AW[2], ATT, 20);
  }
  // ---- layer 4: h=20 -> 18 ----
  {
    k_conv_gg<20, 8, 2, 32, false><<<dim3(21, 16), dim3(256), 0, stream>>>(Bb, ATT, W[2], BI[2], A);
    bn_stats(A, 18 * 18, G[3], BE[3]);
    int nmm = 32 * 4 * 18 * 18;
    k_meanmax_bn<<<dim3(cdiv(nmm, 256)), dim3(256), 0, stream>>>(A, STATS, Bb, AMAP, 18 * 18);
    k_att_gg<<<dim3(cdiv(nmm, 256)), dim3(256), 0, stream>>>(AMAP, AW[3], ATT, 18);
  }
  // ---- layer 5: h=18 -> 16 ----
  {
    k_conv_gg<18, 4, 2, 32, false><<<dim3(16, 32), dim3(256), 0, stream>>>(Bb, ATT, W[3], BI[3], A);
    bn_stats(A, 16 * 16, G[4], BE[4]);
    int nmm = 32 * 4 * 16 * 16;
    k_meanmax_bn<<<dim3(cdiv(nmm, 256)), dim3(256), 0, stream>>>(A, STATS, Bb, AMAP, 16 * 16);
    k_att_gg<<<dim3(cdiv(nmm, 256)), dim3(256), 0, stream>>>(AMAP, AW[4], ATT, 16);
  }
  // ---- layer 6: h=16 -> 14 ----
  {
    k_conv_gg<16, 4, 2, 32, false><<<dim3(13, 32), dim3(256), 0, stream>>>(Bb, ATT, W[4], BI[4], A);
    bn_stats(A, 14 * 14, G[5], BE[5]);
    int nmm = 32 * 4 * 14 * 14;
    k_meanmax_bn<<<dim3(cdiv(nmm, 256)), dim3(256), 0, stream>>>(A, STATS, Bb, AMAP, 14 * 14);
    k_att_gg<<<dim3(cdiv(nmm, 256)), dim3(256), 0, stream>>>(AMAP, AW[5], ATT, 14);
  }
  // ---- layer 7: h=14 -> 12, O=10, no BN ----
  k_conv_gg<14, 4, 2, 10, false><<<dim3(9, 12), dim3(256), 0, stream>>>(Bb, ATT, W[5], BI[5], A);
  // ---- rotation max + spatial mean ----
  k_final<<<dim3(5), dim3(64), 0, stream>>>(A, out);
}

// Round 6
// 1007.926 us; speedup vs baseline: 3.7064x; 1.1469x over previous
//
#include <hip/hip_runtime.h>
#include <cstddef>

#define DINL static __device__ __forceinline__

// collision-proof custom vector types (HIP headers own names like short8/float4)
typedef __attribute__((ext_vector_type(4))) float f4v;
typedef __attribute__((ext_vector_type(8))) short bh8;  // 8 bf16 bit patterns (4 VGPRs)

// rot90 applied r times (counter-clockwise, numpy convention): rotated_r[i][j] = w[si][sj]
DINL void rot_src(int r, int K, int i, int j, int& si, int& sj) {
  switch (r & 3) {
    case 0:  si = i;       sj = j;       break;
    case 1:  si = j;       sj = K-1-i;   break;
    case 2:  si = K-1-i;   sj = K-1-j;   break;
    default: si = K-1-j;   sj = i;       break;
  }
}

DINL float sigmoidf(float s) { return 1.f / (1.f + __expf(-s)); }

// float -> bf16 bits, round-to-nearest-even
DINL unsigned short f2bf(float f) {
  unsigned u = __builtin_bit_cast(unsigned, f);
  u += 0x7fffu + ((u >> 16) & 1u);
  return (unsigned short)(u >> 16);
}
DINL float bf2f(unsigned short h) {
  unsigned u = ((unsigned)h) << 16;
  return __builtin_bit_cast(float, u);
}

// ---------------- weight prep: all 6 GG layers -> bf16 [r][tap][o][cg] ----------------
// offsets (ushort): L2..L6 at L*147456 (OPAD=32), L7 at 737280 (OPAD=16, O=10)
__global__ void k_prep_w(const float* __restrict__ w2, const float* __restrict__ w3,
                         const float* __restrict__ w4, const float* __restrict__ w5,
                         const float* __restrict__ w6, const float* __restrict__ w7,
                         unsigned short* __restrict__ wrot) {
  int idx = blockIdx.x * 256 + threadIdx.x;
  if (idx >= 811008) return;
  const float* w; int OPAD, O, base;
  if (idx < 737280) {
    int L = idx / 147456; base = L * 147456; OPAD = 32; O = 32;
    w = (L == 0) ? w2 : (L == 1) ? w3 : (L == 2) ? w4 : (L == 3) ? w5 : w6;
  } else { base = 737280; OPAD = 16; O = 10; w = w7; }
  int local = idx - base;
  int cg = local & 127; int t = local >> 7;
  int o = t % OPAD; t /= OPAD;
  int tap = t % 9; int r = t / 9;
  float val = 0.f;
  if (o < O) {
    int g = cg & 3, ci = cg >> 2;
    int ky = tap / 3, kx = tap % 3;
    int si, sj; rot_src(r, 3, ky, kx, si, sj);
    int gs = (g - r) & 3;
    val = w[((o * 32 + ci) * 4 + gs) * 9 + si * 3 + sj];
  }
  wrot[idx] = f2bf(val);
}

// ---------------- layer 1 (lifting) ----------------

__global__ void k_att_lift(const float* __restrict__ x, const float* __restrict__ aw,
                           float* __restrict__ att) {
  const int H = 48, HW = H * H;
  int idx = blockIdx.x * blockDim.x + threadIdx.x;
  if (idx >= 32 * 4 * HW) return;
  int xw = idx % H; int t = idx / H;
  int yh = t % H;  t /= H;
  int r  = t & 3;  int b = t >> 2;
  const float* xb = x + b * HW;
  float s = 0.f;
  for (int ky = 0; ky < 7; ++ky) {
    int y = yh + ky - 3;
    if ((unsigned)y >= (unsigned)H) continue;
    for (int kx = 0; kx < 7; ++kx) {
      int xx = xw + kx - 3;
      if ((unsigned)xx >= (unsigned)H) continue;
      int si, sj; rot_src(r, 7, ky, kx, si, sj);
      s += xb[y * H + xx] * (aw[si * 7 + sj] + aw[49 + si * 7 + sj]);
    }
  }
  att[idx] = sigmoidf(s);
}

// lifting conv, channels-last out: y[(b*2116+p)*128 + o*4 + r]
__global__ void __launch_bounds__(256)
k_conv_lift(const float* __restrict__ x, const float* __restrict__ att,
            const float* __restrict__ w, const float* __restrict__ bias,
            float* __restrict__ y) {
  const int HI = 48, HO = 46, HWO = HO * HO;
  int idx = blockIdx.x * blockDim.x + threadIdx.x;
  if (idx >= 32 * HWO * 128) return;
  int co = idx & 127; int t = idx >> 7;
  int p = t % HWO; int b = t / HWO;
  int r = co & 3, o = co >> 2;
  int yo = p / HO, xo = p % HO;
  const float* xb = x + b * HI * HI;
  const float* ab = att + (b * 4 + r) * HI * HI;
  float acc = bias[o];
  #pragma unroll
  for (int ky = 0; ky < 3; ++ky)
    #pragma unroll
    for (int kx = 0; kx < 3; ++kx) {
      int si, sj; rot_src(r, 3, ky, kx, si, sj);
      int pp = (yo + ky) * HI + xo + kx;
      acc = fmaf(ab[pp] * xb[pp], w[o * 9 + si * 3 + sj], acc);
    }
  y[idx] = acc;
}

// ---------------- MFMA attentive GG conv ----------------
// Input xn [b][p][128] fp32 channels-last, att [b][4][hw], weights bf16 [r][tap][OPAD][128].
// Block: 128 threads (2 waves); tile 4 rows x 16 cols for fixed (b,r).
// B = att*x staged to LDS bf16 [winrow][wincol][cg(pad 136)]; A read from global (L1/L2).
// Fragments (guide-verified): A[m=lane&15][k=quad*8+j], B[n=lane&15][k=quad*8+j],
// C/D col=lane&15, row=quad*4+reg. Out y [b][p'][OSTR] fp32, channel o*4+r.
template<int H, int OM, int O, int OSTR>
__global__ void __launch_bounds__(128)
k_conv_mfma(const float* __restrict__ xn, const float* __restrict__ att,
            const unsigned short* __restrict__ wl, const float* __restrict__ bias,
            float* __restrict__ y) {
  constexpr int HO = H - 2, HW = H * H;
  constexpr int TR = 4, TC = 16, WR = TR + 2, WC = TC + 2, CGS = 136;
  constexpr int NRT = (HO + TR - 1) / TR, NCT = (HO + TC - 1) / TC;
  constexpr int OPAD = OM * 16;
  __shared__ __align__(16) unsigned short xa[WR * WC * CGS];

  // XCD swizzle: blockIdx.x % 8 <-> b % 8
  int id = blockIdx.x;
  int slot = id & 7; int k = id >> 3;
  int tile = k % (NRT * NCT); k /= (NRT * NCT);
  int r = k & 3; int bhi = k >> 2;
  int b = bhi * 8 + slot;
  int rt = tile / NCT, ct = tile % NCT;
  int row0 = rt * TR, c0 = ct * TC;

  const float* xb = xn + (size_t)b * HW * 128;
  const float* ab = att + (size_t)(b * 4 + r) * HW;

  // stage xa = bf16(att * x) window
  for (int u = threadIdx.x; u < WR * WC * 16; u += 128) {
    int cq = u & 15; int pix = u >> 4;
    int wr = pix / WC, wc = pix % WC;
    int row = row0 + wr; if (row > H - 1) row = H - 1;
    int col = c0 + wc;  if (col > H - 1) col = H - 1;
    int p = row * H + col;
    const float* xp = xb + (size_t)p * 128 + cq * 8;
    float av = ab[p];
    f4v x0 = *(const f4v*)xp;
    f4v x1 = *(const f4v*)(xp + 4);
    bh8 v;
    v[0] = (short)f2bf(x0[0] * av); v[1] = (short)f2bf(x0[1] * av);
    v[2] = (short)f2bf(x0[2] * av); v[3] = (short)f2bf(x0[3] * av);
    v[4] = (short)f2bf(x1[0] * av); v[5] = (short)f2bf(x1[1] * av);
    v[6] = (short)f2bf(x1[2] * av); v[7] = (short)f2bf(x1[3] * av);
    *(bh8*)&xa[pix * CGS + cq * 8] = v;
  }
  __syncthreads();

  int lane = threadIdx.x & 63;
  int wv = threadIdx.x >> 6;        // wave 0: rows 0,1; wave 1: rows 2,3
  int n = lane & 15, quad = lane >> 4;

  f4v acc[OM][2];
  #pragma unroll
  for (int mi = 0; mi < OM; ++mi)
    #pragma unroll
    for (int ri = 0; ri < 2; ++ri) {
      acc[mi][ri][0] = 0.f; acc[mi][ri][1] = 0.f;
      acc[mi][ri][2] = 0.f; acc[mi][ri][3] = 0.f;
    }

  const bh8* wl8 = (const bh8*)wl;
  for (int tap = 0; tap < 9; ++tap) {
    int ky = tap / 3, kx = tap % 3;
    const bh8* wt = wl8 + (size_t)(r * 9 + tap) * OPAD * 16;
    int pb0 = ((2 * wv + 0 + ky) * WC + n + kx) * CGS;
    int pb1 = ((2 * wv + 1 + ky) * WC + n + kx) * CGS;
    #pragma unroll
    for (int ks = 0; ks < 4; ++ks) {
      bh8 b0 = *(const bh8*)&xa[pb0 + ks * 32 + quad * 8];
      bh8 b1 = *(const bh8*)&xa[pb1 + ks * 32 + quad * 8];
      bh8 a0 = wt[n * 16 + ks * 4 + quad];
      acc[0][0] = __builtin_amdgcn_mfma_f32_16x16x32_bf16(a0, b0, acc[0][0], 0, 0, 0);
      acc[0][1] = __builtin_amdgcn_mfma_f32_16x16x32_bf16(a0, b1, acc[0][1], 0, 0, 0);
      if constexpr (OM == 2) {
        bh8 a1 = wt[(16 + n) * 16 + ks * 4 + quad];
        acc[1][0] = __builtin_amdgcn_mfma_f32_16x16x32_bf16(a1, b0, acc[1][0], 0, 0, 0);
        acc[1][1] = __builtin_amdgcn_mfma_f32_16x16x32_bf16(a1, b1, acc[1][1], 0, 0, 0);
      }
    }
  }

  // epilogue: C/D col=lane&15 (spatial), row=quad*4+reg (o); add bias
  #pragma unroll
  for (int mi = 0; mi < OM; ++mi)
    #pragma unroll
    for (int ri = 0; ri < 2; ++ri) {
      int prow = row0 + 2 * wv + ri;
      int col = c0 + n;
      if (prow < HO && col < HO) {
        float* yp = y + ((size_t)b * HO * HO + prow * HO + col) * OSTR + r;
        #pragma unroll
        for (int reg = 0; reg < 4; ++reg) {
          int o = mi * 16 + quad * 4 + reg;
          if (o < O) yp[o * 4] = acc[mi][ri][reg] + bias[o];
        }
      }
    }
}

// ---------------- BatchNorm3d stats (channels-last) ----------------
__global__ void k_bn_partial(const float* __restrict__ y, float* __restrict__ part,
                             int npix) {
  __shared__ float l1[256], l2[256];
  int s = blockIdx.x;
  int co = threadIdx.x & 127; int slot = threadIdx.x >> 7;
  float s1 = 0.f, s2 = 0.f;
  for (int j = s * 2 + slot; j < npix; j += 128) {
    float v = y[(size_t)j * 128 + co];
    s1 += v; s2 += v * v;
  }
  l1[threadIdx.x] = s1; l2[threadIdx.x] = s2;
  __syncthreads();
  if (slot == 0) { l1[co] = s1 + l1[128 + co]; l2[co] = s2 + l2[128 + co]; }
  __syncthreads();
  if (threadIdx.x < 32) {
    int o = threadIdx.x;
    float a = 0.f, q = 0.f;
    #pragma unroll
    for (int g = 0; g < 4; ++g) { a += l1[o * 4 + g]; q += l2[o * 4 + g]; }
    part[o * 64 + s] = a;
    part[4096 + o * 64 + s] = q;
  }
}

__global__ void k_bn_finalize(const float* __restrict__ part,
                              const float* __restrict__ gamma,
                              const float* __restrict__ beta,
                              float* __restrict__ stats, int npix) {
  int c = threadIdx.x;
  if (c >= 32) return;
  float s1 = 0.f, s2 = 0.f;
  for (int s = 0; s < 64; ++s) { s1 += part[c * 64 + s]; s2 += part[4096 + c * 64 + s]; }
  float N = 4.f * (float)npix;
  float m = s1 / N;
  float v = s2 / N - m * m;
  float inv = rsqrtf(v + 2e-5f);
  float sc = gamma[c] * inv;
  stats[c] = sc;
  stats[32 + c] = beta[c] - m * sc;
}

// ---------------- fused BN+ReLU+channel mean/max (channels-last, bf16 amap) ----------------

__global__ void k_meanmax_bn(const float* __restrict__ yr, const float* __restrict__ stats,
                             float* __restrict__ xn, unsigned short* __restrict__ amap,
                             int npix) {
  __shared__ float st[64];
  if (threadIdx.x < 64) st[threadIdx.x] = stats[threadIdx.x];
  __syncthreads();
  int idx = blockIdx.x * 256 + threadIdx.x;
  if (idx >= npix) return;
  const float* yp = yr + (size_t)idx * 128;
  float* xp = xn + (size_t)idx * 128;
  float sm[4] = {0.f, 0.f, 0.f, 0.f};
  float mx[4] = {-1e30f, -1e30f, -1e30f, -1e30f};
  #pragma unroll 8
  for (int o = 0; o < 32; ++o) {
    f4v v = *(const f4v*)(yp + o * 4);
    float sc = st[o], sh = st[32 + o];
    f4v w;
    #pragma unroll
    for (int g = 0; g < 4; ++g) {
      float val = fmaxf(fmaf(v[g], sc, sh), 0.f);
      w[g] = val; sm[g] += val; mx[g] = fmaxf(mx[g], val);
    }
    *(f4v*)(xp + o * 4) = w;
  }
  bh8 am;
  #pragma unroll
  for (int g = 0; g < 4; ++g) {
    am[g] = (short)f2bf(sm[g] * (1.f / 32.f));
    am[4 + g] = (short)f2bf(mx[g]);
  }
  *(bh8*)(amap + (size_t)idx * 8) = am;
}

// layer-2 variant: BN+ReLU at 44x44 then 2x2 maxpool -> 22x22
__global__ void k_meanmax_bn_pool(const float* __restrict__ yr, const float* __restrict__ stats,
                                  float* __restrict__ xn, unsigned short* __restrict__ amap) {
  const int HI = 44, HOq = 22, HWO = HOq * HOq;
  __shared__ float st[64];
  if (threadIdx.x < 64) st[threadIdx.x] = stats[threadIdx.x];
  __syncthreads();
  int idx = blockIdx.x * 256 + threadIdx.x;
  if (idx >= 32 * HWO) return;
  int p22 = idx % HWO; int b = idx / HWO;
  int y0 = (p22 / HOq) * 2, x0 = (p22 % HOq) * 2;
  const float* p00 = yr + ((size_t)b * HI * HI + y0 * HI + x0) * 128;
  float* xp = xn + (size_t)idx * 128;
  float sm[4] = {0.f, 0.f, 0.f, 0.f};
  float mx[4] = {-1e30f, -1e30f, -1e30f, -1e30f};
  #pragma unroll 4
  for (int o = 0; o < 32; ++o) {
    f4v v0 = *(const f4v*)(p00 + o * 4);
    f4v v1 = *(const f4v*)(p00 + 128 + o * 4);
    f4v v2 = *(const f4v*)(p00 + (size_t)HI * 128 + o * 4);
    f4v v3 = *(const f4v*)(p00 + (size_t)(HI + 1) * 128 + o * 4);
    float sc = st[o], sh = st[32 + o];
    f4v w;
    #pragma unroll
    for (int g = 0; g < 4; ++g) {
      float a0 = fmaxf(fmaf(v0[g], sc, sh), 0.f);
      float a1 = fmaxf(fmaf(v1[g], sc, sh), 0.f);
      float a2 = fmaxf(fmaf(v2[g], sc, sh), 0.f);
      float a3 = fmaxf(fmaf(v3[g], sc, sh), 0.f);
      float val = fmaxf(fmaxf(a0, a1), fmaxf(a2, a3));
      w[g] = val; sm[g] += val; mx[g] = fmaxf(mx[g], val);
    }
    *(f4v*)(xp + o * 4) = w;
  }
  bh8 am;
  #pragma unroll
  for (int g = 0; g < 4; ++g) {
    am[g] = (short)f2bf(sm[g] * (1.f / 32.f));
    am[4 + g] = (short)f2bf(mx[g]);
  }
  *(bh8*)(amap + (size_t)idx * 8) = am;
}

// ---------------- attention GG conv (bf16 channels-last amap) ----------------

__global__ void k_att_gg(const unsigned short* __restrict__ amap,
                         const float* __restrict__ aw,
                         float* __restrict__ att, int h) {
  int hw = h * h;
  int idx = blockIdx.x * blockDim.x + threadIdx.x;
  if (idx >= 32 * 4 * hw) return;
  int p = idx % hw; int t = idx / hw;
  int r = t & 3; int b = t >> 2;
  int yh = p / h, xw = p % h;
  float s = 0.f;
  for (int ky = 0; ky < 7; ++ky) {
    int y = yh + ky - 3;
    if ((unsigned)y >= (unsigned)h) continue;
    for (int kx = 0; kx < 7; ++kx) {
      int xx = xw + kx - 3;
      if ((unsigned)xx >= (unsigned)h) continue;
      int si, sj; rot_src(r, 7, ky, kx, si, sj);
      bh8 av = *(const bh8*)(amap + ((size_t)b * hw + y * h + xx) * 8);
      const float* awp = aw + si * 7 + sj;
      #pragma unroll
      for (int g = 0; g < 4; ++g) {
        int gs = (g - r) & 3;
        s += bf2f((unsigned short)av[g]) * awp[gs * 49]
           + bf2f((unsigned short)av[4 + g]) * awp[(4 + gs) * 49];
      }
    }
  }
  att[idx] = sigmoidf(s);
}

// ---------------- final: rotation max + spatial mean ----------------
// y7 [b][p(144)][40], out[b*10+o]
__global__ void k_final(const float* __restrict__ y7, float* __restrict__ out) {
  int idx = blockIdx.x * blockDim.x + threadIdx.x;
  if (idx >= 320) return;
  int o = idx % 10; int b = idx / 10;
  const float* p = y7 + (size_t)b * 144 * 40;
  float s = 0.f;
  for (int sp = 0; sp < 144; ++sp) {
    f4v v = *(const f4v*)(p + sp * 40 + o * 4);
    s += fmaxf(fmaxf(v[0], v[1]), fmaxf(v[2], v[3]));
  }
  out[idx] = s * (1.f / 144.f);
}

// ---------------- host ----------------

extern "C" void kernel_launch(void* const* d_in, const int* in_sizes, int n_in,
                              void* d_out, int out_size, void* d_ws, size_t ws_size,
                              hipStream_t stream) {
  (void)in_sizes; (void)n_in; (void)out_size; (void)ws_size;
  const float* x   = (const float*)d_in[0];
  const float* w1  = (const float*)d_in[1];
  const float* b1  = (const float*)d_in[2];
  const float* aw1 = (const float*)d_in[3];
  const float* W[6];  const float* BI[6]; const float* AW[6];
  for (int i = 0; i < 6; ++i) {
    W[i]  = (const float*)d_in[4 + 3 * i];
    BI[i] = (const float*)d_in[5 + 3 * i];
    AW[i] = (const float*)d_in[6 + 3 * i];
  }
  const float* G[6]; const float* BE[6];
  for (int i = 0; i < 6; ++i) {
    G[i]  = (const float*)d_in[22 + 2 * i];
    BE[i] = (const float*)d_in[23 + 2 * i];
  }
  float* out = (float*)d_out;

  // workspace (floats): total 18,313,792 floats = 73.26 MB (< proven 73.62 MB)
  float* ws = (float*)d_ws;
  float* A     = ws;                  // raw conv out  [0, 8667136)
  float* Bb    = ws + 8667136;        // normalized xn [8667136, 17334272)
  unsigned short* AMAP = (unsigned short*)(ws + 17334272);  // 541,696 ushort
  float* ATT   = ws + 17605120;       // 294,912 (48x48 lifting att is the max)
  unsigned short* WROT = (unsigned short*)(ws + 17900032);  // 811,008 ushort
  float* PART  = ws + 18305536;       // 8,192
  float* STATS = ws + 18313728;       // 64

  auto cdiv = [](int a, int b) { return (a + b - 1) / b; };

  // weight prep (all 6 GG layers, one launch)
  k_prep_w<<<dim3(cdiv(811008, 256)), dim3(256), 0, stream>>>(
      W[0], W[1], W[2], W[3], W[4], W[5], WROT);
  const unsigned short* WL[6];
  for (int i = 0; i < 5; ++i) WL[i] = WROT + i * 147456;
  WL[5] = WROT + 737280;

  auto bn_stats = [&](const float* buf, int npix, const float* gamma, const float* beta) {
    k_bn_partial<<<dim3(64), dim3(256), 0, stream>>>(buf, PART, npix);
    k_bn_finalize<<<dim3(1), dim3(64), 0, stream>>>(PART, gamma, beta, STATS, npix);
  };

  // ---- layer 1: attentive lifting conv ----
  {
    int natt = 32 * 4 * 48 * 48;
    k_att_lift<<<dim3(cdiv(natt, 256)), dim3(256), 0, stream>>>(x, aw1, ATT);
    int n1 = 32 * 2116 * 128;
    k_conv_lift<<<dim3(cdiv(n1, 256)), dim3(256), 0, stream>>>(x, ATT, w1, b1, A);
    int npix = 32 * 2116;
    bn_stats(A, npix, G[0], BE[0]);
    k_meanmax_bn<<<dim3(cdiv(npix, 256)), dim3(256), 0, stream>>>(A, STATS, Bb, AMAP, npix);
    k_att_gg<<<dim3(cdiv(npix * 4, 256)), dim3(256), 0, stream>>>(AMAP, AW[0], ATT, 46);
  }
  // ---- layer 2 (H=46 -> 44) + pool ----
  {
    k_conv_mfma<46, 2, 32, 128><<<dim3(128 * 11 * 3), dim3(128), 0, stream>>>(Bb, ATT, WL[0], BI[0], A);
    int npix = 32 * 1936;
    bn_stats(A, npix, G[1], BE[1]);
    int np22 = 32 * 484;
    k_meanmax_bn_pool<<<dim3(cdiv(np22, 256)), dim3(256), 0, stream>>>(A, STATS, Bb, AMAP);
    k_att_gg<<<dim3(cdiv(np22 * 4, 256)), dim3(256), 0, stream>>>(AMAP, AW[1], ATT, 22);
  }
  // ---- layer 3 (22 -> 20) ----
  {
    k_conv_mfma<22, 2, 32, 128><<<dim3(128 * 5 * 2), dim3(128), 0, stream>>>(Bb, ATT, WL[1], BI[1], A);
    int npix = 32 * 400;
    bn_stats(A, npix, G[2], BE[2]);
    k_meanmax_bn<<<dim3(cdiv(npix, 256)), dim3(256), 0, stream>>>(A, STATS, Bb, AMAP, npix);
    k_att_gg<<<dim3(cdiv(npix * 4, 256)), dim3(256), 0, stream>>>(AMAP, AW[2], ATT, 20);
  }
  // ---- layer 4 (20 -> 18) ----
  {
    k_conv_mfma<20, 2, 32, 128><<<dim3(128 * 5 * 2), dim3(128), 0, stream>>>(Bb, ATT, WL[2], BI[2], A);
    int npix = 32 * 324;
    bn_stats(A, npix, G[3], BE[3]);
    k_meanmax_bn<<<dim3(cdiv(npix, 256)), dim3(256), 0, stream>>>(A, STATS, Bb, AMAP, npix);
    k_att_gg<<<dim3(cdiv(npix * 4, 256)), dim3(256), 0, stream>>>(AMAP, AW[3], ATT, 18);
  }
  // ---- layer 5 (18 -> 16) ----
  {
    k_conv_mfma<18, 2, 32, 128><<<dim3(128 * 4 * 1), dim3(128), 0, stream>>>(Bb, ATT, WL[3], BI[3], A);
    int npix = 32 * 256;
    bn_stats(A, npix, G[4], BE[4]);
    k_meanmax_bn<<<dim3(cdiv(npix, 256)), dim3(256), 0, stream>>>(A, STATS, Bb, AMAP, npix);
    k_att_gg<<<dim3(cdiv(npix * 4, 256)), dim3(256), 0, stream>>>(AMAP, AW[4], ATT, 16);
  }
  // ---- layer 6 (16 -> 14) ----
  {
    k_conv_mfma<16, 2, 32, 128><<<dim3(128 * 4 * 1), dim3(128), 0, stream>>>(Bb, ATT, WL[4], BI[4], A);
    int npix = 32 * 196;
    bn_stats(A, npix, G[5], BE[5]);
    k_meanmax_bn<<<dim3(cdiv(npix, 256)), dim3(256), 0, stream>>>(A, STATS, Bb, AMAP, npix);
    k_att_gg<<<dim3(cdiv(npix * 4, 256)), dim3(256), 0, stream>>>(AMAP, AW[5], ATT, 14);
  }
  // ---- layer 7 (14 -> 12, O=10, no BN) ----
  k_conv_mfma<14, 1, 10, 40><<<dim3(128 * 3 * 1), dim3(128), 0, stream>>>(Bb, ATT, WL[5], BI[5], A);
  // ---- rotation max + spatial mean ----
  k_final<<<dim3(5), dim3(64), 0, stream>>>(A, out);
}

// Round 7
// 800.718 us; speedup vs baseline: 4.6655x; 1.2588x over previous
//
#include <hip/hip_runtime.h>
#include <cstddef>

#define DINL static __device__ __forceinline__

// collision-proof custom vector types (HIP headers own names like short8/float4)
typedef __attribute__((ext_vector_type(4))) float f4v;
typedef __attribute__((ext_vector_type(8))) short bh8;  // 8 bf16 bit patterns (4 VGPRs)

// rot90 applied r times (counter-clockwise, numpy convention): rotated_r[i][j] = w[si][sj]
DINL void rot_src(int r, int K, int i, int j, int& si, int& sj) {
  switch (r & 3) {
    case 0:  si = i;       sj = j;       break;
    case 1:  si = j;       sj = K-1-i;   break;
    case 2:  si = K-1-i;   sj = K-1-j;   break;
    default: si = K-1-j;   sj = i;       break;
  }
}

DINL float sigmoidf(float s) { return 1.f / (1.f + __expf(-s)); }

// float -> bf16 bits, round-to-nearest-even
DINL unsigned short f2bf(float f) {
  unsigned u = __builtin_bit_cast(unsigned, f);
  u += 0x7fffu + ((u >> 16) & 1u);
  return (unsigned short)(u >> 16);
}
DINL float bf2f(unsigned short h) {
  unsigned u = ((unsigned)h) << 16;
  return __builtin_bit_cast(float, u);
}

// ---------------- weight prep: all 6 GG layers -> bf16 [r][tap][o][cg] ----------------
// offsets (ushort): L2..L6 at L*147456 (OPAD=32), L7 at 737280 (OPAD=16, O=10)
__global__ void k_prep_w(const float* __restrict__ w2, const float* __restrict__ w3,
                         const float* __restrict__ w4, const float* __restrict__ w5,
                         const float* __restrict__ w6, const float* __restrict__ w7,
                         unsigned short* __restrict__ wrot) {
  int idx = blockIdx.x * 256 + threadIdx.x;
  if (idx >= 811008) return;
  const float* w; int OPAD, O, base;
  if (idx < 737280) {
    int L = idx / 147456; base = L * 147456; OPAD = 32; O = 32;
    w = (L == 0) ? w2 : (L == 1) ? w3 : (L == 2) ? w4 : (L == 3) ? w5 : w6;
  } else { base = 737280; OPAD = 16; O = 10; w = w7; }
  int local = idx - base;
  int cg = local & 127; int t = local >> 7;
  int o = t % OPAD; t /= OPAD;
  int tap = t % 9; int r = t / 9;
  float val = 0.f;
  if (o < O) {
    int g = cg & 3, ci = cg >> 2;
    int ky = tap / 3, kx = tap % 3;
    int si, sj; rot_src(r, 3, ky, kx, si, sj);
    int gs = (g - r) & 3;
    val = w[((o * 32 + ci) * 4 + gs) * 9 + si * 3 + sj];
  }
  wrot[idx] = f2bf(val);
}

// ---------------- layer 1 (lifting) ----------------

__global__ void k_att_lift(const float* __restrict__ x, const float* __restrict__ aw,
                           float* __restrict__ att) {
  const int H = 48, HW = H * H;
  int idx = blockIdx.x * blockDim.x + threadIdx.x;
  if (idx >= 32 * 4 * HW) return;
  int xw = idx % H; int t = idx / H;
  int yh = t % H;  t /= H;
  int r  = t & 3;  int b = t >> 2;
  const float* xb = x + b * HW;
  float s = 0.f;
  for (int ky = 0; ky < 7; ++ky) {
    int y = yh + ky - 3;
    if ((unsigned)y >= (unsigned)H) continue;
    for (int kx = 0; kx < 7; ++kx) {
      int xx = xw + kx - 3;
      if ((unsigned)xx >= (unsigned)H) continue;
      int si, sj; rot_src(r, 7, ky, kx, si, sj);
      s += xb[y * H + xx] * (aw[si * 7 + sj] + aw[49 + si * 7 + sj]);
    }
  }
  att[idx] = sigmoidf(s);
}

// lifting conv, channels-last out: y[(b*2116+p)*128 + o*4 + r]
__global__ void __launch_bounds__(256)
k_conv_lift(const float* __restrict__ x, const float* __restrict__ att,
            const float* __restrict__ w, const float* __restrict__ bias,
            float* __restrict__ y) {
  const int HI = 48, HO = 46, HWO = HO * HO;
  int idx = blockIdx.x * blockDim.x + threadIdx.x;
  if (idx >= 32 * HWO * 128) return;
  int co = idx & 127; int t = idx >> 7;
  int p = t % HWO; int b = t / HWO;
  int r = co & 3, o = co >> 2;
  int yo = p / HO, xo = p % HO;
  const float* xb = x + b * HI * HI;
  const float* ab = att + (b * 4 + r) * HI * HI;
  float acc = bias[o];
  #pragma unroll
  for (int ky = 0; ky < 3; ++ky)
    #pragma unroll
    for (int kx = 0; kx < 3; ++kx) {
      int si, sj; rot_src(r, 3, ky, kx, si, sj);
      int pp = (yo + ky) * HI + xo + kx;
      acc = fmaf(ab[pp] * xb[pp], w[o * 9 + si * 3 + sj], acc);
    }
  y[idx] = acc;
}

// ---------------- MFMA attentive GG conv ----------------
// Input xn [b][p][128] bf16 channels-last, att [b][4][hw] fp32, weights bf16 [r][tap][OPAD][128].
// Block: 128 threads (2 waves); tile 4 rows x 16 cols for fixed (b,r).
// B = att*x staged to LDS bf16 [winrow][wincol][cg(pad 136)]; A read from global (L1/L2).
// Fragments (guide-verified): A[m=lane&15][k=quad*8+j], B[n=lane&15][k=quad*8+j],
// C/D col=lane&15, row=quad*4+reg. Out y [b][p'][OSTR] fp32, channel o*4+r.
template<int H, int OM, int O, int OSTR>
__global__ void __launch_bounds__(128)
k_conv_mfma(const unsigned short* __restrict__ xn, const float* __restrict__ att,
            const unsigned short* __restrict__ wl, const float* __restrict__ bias,
            float* __restrict__ y) {
  constexpr int HO = H - 2, HW = H * H;
  constexpr int TR = 4, TC = 16, WR = TR + 2, WC = TC + 2, CGS = 136;
  constexpr int NRT = (HO + TR - 1) / TR, NCT = (HO + TC - 1) / TC;
  constexpr int OPAD = OM * 16;
  __shared__ __align__(16) unsigned short xa[WR * WC * CGS];

  // XCD swizzle: blockIdx.x % 8 <-> b % 8
  int id = blockIdx.x;
  int slot = id & 7; int k = id >> 3;
  int tile = k % (NRT * NCT); k /= (NRT * NCT);
  int r = k & 3; int bhi = k >> 2;
  int b = bhi * 8 + slot;
  int rt = tile / NCT, ct = tile % NCT;
  int row0 = rt * TR, c0 = ct * TC;

  const unsigned short* xb = xn + (size_t)b * HW * 128;
  const float* ab = att + (size_t)(b * 4 + r) * HW;

  // stage xa = bf16(att * x) window
  for (int u = threadIdx.x; u < WR * WC * 16; u += 128) {
    int cq = u & 15; int pix = u >> 4;
    int wr = pix / WC, wc = pix % WC;
    int row = row0 + wr; if (row > H - 1) row = H - 1;
    int col = c0 + wc;  if (col > H - 1) col = H - 1;
    int p = row * H + col;
    const unsigned short* xp = xb + (size_t)p * 128 + cq * 8;
    float av = ab[p];
    bh8 xv = *(const bh8*)xp;
    bh8 v;
    #pragma unroll
    for (int j = 0; j < 8; ++j)
      v[j] = (short)f2bf(bf2f((unsigned short)xv[j]) * av);
    *(bh8*)&xa[pix * CGS + cq * 8] = v;
  }
  __syncthreads();

  int lane = threadIdx.x & 63;
  int wv = threadIdx.x >> 6;        // wave 0: rows 0,1; wave 1: rows 2,3
  int n = lane & 15, quad = lane >> 4;

  f4v acc[OM][2];
  #pragma unroll
  for (int mi = 0; mi < OM; ++mi)
    #pragma unroll
    for (int ri = 0; ri < 2; ++ri) {
      acc[mi][ri][0] = 0.f; acc[mi][ri][1] = 0.f;
      acc[mi][ri][2] = 0.f; acc[mi][ri][3] = 0.f;
    }

  const bh8* wl8 = (const bh8*)wl;
  for (int tap = 0; tap < 9; ++tap) {
    int ky = tap / 3, kx = tap % 3;
    const bh8* wt = wl8 + (size_t)(r * 9 + tap) * OPAD * 16;
    int pb0 = ((2 * wv + 0 + ky) * WC + n + kx) * CGS;
    int pb1 = ((2 * wv + 1 + ky) * WC + n + kx) * CGS;
    #pragma unroll
    for (int ks = 0; ks < 4; ++ks) {
      bh8 b0 = *(const bh8*)&xa[pb0 + ks * 32 + quad * 8];
      bh8 b1 = *(const bh8*)&xa[pb1 + ks * 32 + quad * 8];
      bh8 a0 = wt[n * 16 + ks * 4 + quad];
      acc[0][0] = __builtin_amdgcn_mfma_f32_16x16x32_bf16(a0, b0, acc[0][0], 0, 0, 0);
      acc[0][1] = __builtin_amdgcn_mfma_f32_16x16x32_bf16(a0, b1, acc[0][1], 0, 0, 0);
      if constexpr (OM == 2) {
        bh8 a1 = wt[(16 + n) * 16 + ks * 4 + quad];
        acc[1][0] = __builtin_amdgcn_mfma_f32_16x16x32_bf16(a1, b0, acc[1][0], 0, 0, 0);
        acc[1][1] = __builtin_amdgcn_mfma_f32_16x16x32_bf16(a1, b1, acc[1][1], 0, 0, 0);
      }
    }
  }

  // epilogue: C/D col=lane&15 (spatial), row=quad*4+reg (o); add bias
  #pragma unroll
  for (int mi = 0; mi < OM; ++mi)
    #pragma unroll
    for (int ri = 0; ri < 2; ++ri) {
      int prow = row0 + 2 * wv + ri;
      int col = c0 + n;
      if (prow < HO && col < HO) {
        float* yp = y + ((size_t)b * HO * HO + prow * HO + col) * OSTR + r;
        #pragma unroll
        for (int reg = 0; reg < 4; ++reg) {
          int o = mi * 16 + quad * 4 + reg;
          if (o < O) yp[o * 4] = acc[mi][ri][reg] + bias[o];
        }
      }
    }
}

// ---------------- BatchNorm3d stats (channels-last, S-way parallel) ----------------
// part[o*1024+s] = sum, part[32768+o*1024+s] = sumsq; grid = S blocks
__global__ void k_bn_partial(const float* __restrict__ y, float* __restrict__ part,
                             int npix, int S) {
  __shared__ float l1[256], l2[256];
  int s = blockIdx.x;
  int chunk = (npix + S - 1) / S;
  int p0 = s * chunk;
  int p1 = p0 + chunk; if (p1 > npix) p1 = npix;
  int co = threadIdx.x & 127; int slot = threadIdx.x >> 7;
  float s1 = 0.f, s2 = 0.f;
  for (int p = p0 + slot; p < p1; p += 2) {
    float v = y[(size_t)p * 128 + co];
    s1 += v; s2 += v * v;
  }
  l1[threadIdx.x] = s1; l2[threadIdx.x] = s2;
  __syncthreads();
  if (slot == 0) { l1[co] = s1 + l1[128 + co]; l2[co] = s2 + l2[128 + co]; }
  __syncthreads();
  if (threadIdx.x < 32) {
    int o = threadIdx.x;
    float a = 0.f, q = 0.f;
    #pragma unroll
    for (int g = 0; g < 4; ++g) { a += l1[o * 4 + g]; q += l2[o * 4 + g]; }
    part[o * 1024 + s] = a;
    part[32768 + o * 1024 + s] = q;
  }
}

__global__ void k_bn_finalize(const float* __restrict__ part,
                              const float* __restrict__ gamma,
                              const float* __restrict__ beta,
                              float* __restrict__ stats, int npix, int S) {
  __shared__ float l1[256], l2[256];
  int c = threadIdx.x & 31, ch = threadIdx.x >> 5;  // 32 channels x 8 chunks
  float s1 = 0.f, s2 = 0.f;
  for (int s = ch; s < S; s += 8) {
    s1 += part[c * 1024 + s];
    s2 += part[32768 + c * 1024 + s];
  }
  l1[threadIdx.x] = s1; l2[threadIdx.x] = s2;
  __syncthreads();
  if (threadIdx.x < 32) {
    float a = 0.f, q = 0.f;
    #pragma unroll
    for (int k = 0; k < 8; ++k) { a += l1[k * 32 + c]; q += l2[k * 32 + c]; }
    float N = 4.f * (float)npix;
    float m = a / N;
    float v = q / N - m * m;
    float inv = rsqrtf(v + 2e-5f);
    float sc = gamma[c] * inv;
    stats[c] = sc;
    stats[32 + c] = beta[c] - m * sc;
  }
}

// ---------------- fused BN+ReLU+channel mean/max (bf16 xn + bf16 amap out) ----------------

__global__ void k_meanmax_bn(const float* __restrict__ yr, const float* __restrict__ stats,
                             unsigned short* __restrict__ xn, unsigned short* __restrict__ amap,
                             int npix) {
  __shared__ float st[64];
  if (threadIdx.x < 64) st[threadIdx.x] = stats[threadIdx.x];
  __syncthreads();
  int idx = blockIdx.x * 256 + threadIdx.x;
  if (idx >= npix) return;
  const float* yp = yr + (size_t)idx * 128;
  unsigned short* xp = xn + (size_t)idx * 128;
  float sm[4] = {0.f, 0.f, 0.f, 0.f};
  float mx[4] = {-1e30f, -1e30f, -1e30f, -1e30f};
  #pragma unroll 4
  for (int oo = 0; oo < 16; ++oo) {  // channel pairs (o=2oo, 2oo+1)
    f4v va = *(const f4v*)(yp + oo * 8);
    f4v vb = *(const f4v*)(yp + oo * 8 + 4);
    int oa = 2 * oo, ob = 2 * oo + 1;
    float sca = st[oa], sha = st[32 + oa];
    float scb = st[ob], shb = st[32 + ob];
    bh8 w;
    #pragma unroll
    for (int g = 0; g < 4; ++g) {
      float v0 = fmaxf(fmaf(va[g], sca, sha), 0.f);
      float v1 = fmaxf(fmaf(vb[g], scb, shb), 0.f);
      w[g] = (short)f2bf(v0); w[4 + g] = (short)f2bf(v1);
      sm[g] += v0 + v1;
      mx[g] = fmaxf(mx[g], fmaxf(v0, v1));
    }
    *(bh8*)(xp + oo * 8) = w;
  }
  bh8 am;
  #pragma unroll
  for (int g = 0; g < 4; ++g) {
    am[g] = (short)f2bf(sm[g] * (1.f / 32.f));
    am[4 + g] = (short)f2bf(mx[g]);
  }
  *(bh8*)(amap + (size_t)idx * 8) = am;
}

// layer-2 variant: BN+ReLU at 44x44 then 2x2 maxpool -> 22x22
__global__ void k_meanmax_bn_pool(const float* __restrict__ yr, const float* __restrict__ stats,
                                  unsigned short* __restrict__ xn, unsigned short* __restrict__ amap) {
  const int HI = 44, HOq = 22, HWO = HOq * HOq;
  __shared__ float st[64];
  if (threadIdx.x < 64) st[threadIdx.x] = stats[threadIdx.x];
  __syncthreads();
  int idx = blockIdx.x * 256 + threadIdx.x;
  if (idx >= 32 * HWO) return;
  int p22 = idx % HWO; int b = idx / HWO;
  int y0 = (p22 / HOq) * 2, x0 = (p22 % HOq) * 2;
  const float* p00 = yr + ((size_t)b * HI * HI + y0 * HI + x0) * 128;
  unsigned short* xp = xn + (size_t)idx * 128;
  float sm[4] = {0.f, 0.f, 0.f, 0.f};
  float mx[4] = {-1e30f, -1e30f, -1e30f, -1e30f};
  #pragma unroll 2
  for (int oo = 0; oo < 16; ++oo) {  // channel pairs
    bh8 w;
    #pragma unroll
    for (int half = 0; half < 2; ++half) {
      int o = 2 * oo + half;
      f4v v0 = *(const f4v*)(p00 + o * 4);
      f4v v1 = *(const f4v*)(p00 + 128 + o * 4);
      f4v v2 = *(const f4v*)(p00 + (size_t)HI * 128 + o * 4);
      f4v v3 = *(const f4v*)(p00 + (size_t)(HI + 1) * 128 + o * 4);
      float sc = st[o], sh = st[32 + o];
      #pragma unroll
      for (int g = 0; g < 4; ++g) {
        float a0 = fmaxf(fmaf(v0[g], sc, sh), 0.f);
        float a1 = fmaxf(fmaf(v1[g], sc, sh), 0.f);
        float a2 = fmaxf(fmaf(v2[g], sc, sh), 0.f);
        float a3 = fmaxf(fmaf(v3[g], sc, sh), 0.f);
        float val = fmaxf(fmaxf(a0, a1), fmaxf(a2, a3));
        w[half * 4 + g] = (short)f2bf(val);
        sm[g] += val; mx[g] = fmaxf(mx[g], val);
      }
    }
    *(bh8*)(xp + oo * 8) = w;
  }
  bh8 am;
  #pragma unroll
  for (int g = 0; g < 4; ++g) {
    am[g] = (short)f2bf(sm[g] * (1.f / 32.f));
    am[4 + g] = (short)f2bf(mx[g]);
  }
  *(bh8*)(amap + (size_t)idx * 8) = am;
}

// ---------------- attention GG conv (bf16 channels-last amap) ----------------

__global__ void k_att_gg(const unsigned short* __restrict__ amap,
                         const float* __restrict__ aw,
                         float* __restrict__ att, int h) {
  int hw = h * h;
  int idx = blockIdx.x * blockDim.x + threadIdx.x;
  if (idx >= 32 * 4 * hw) return;
  int p = idx % hw; int t = idx / hw;
  int r = t & 3; int b = t >> 2;
  int yh = p / h, xw = p % h;
  float s = 0.f;
  for (int ky = 0; ky < 7; ++ky) {
    int y = yh + ky - 3;
    if ((unsigned)y >= (unsigned)h) continue;
    for (int kx = 0; kx < 7; ++kx) {
      int xx = xw + kx - 3;
      if ((unsigned)xx >= (unsigned)h) continue;
      int si, sj; rot_src(r, 7, ky, kx, si, sj);
      bh8 av = *(const bh8*)(amap + ((size_t)b * hw + y * h + xx) * 8);
      const float* awp = aw + si * 7 + sj;
      #pragma unroll
      for (int g = 0; g < 4; ++g) {
        int gs = (g - r) & 3;
        s += bf2f((unsigned short)av[g]) * awp[gs * 49]
           + bf2f((unsigned short)av[4 + g]) * awp[(4 + gs) * 49];
      }
    }
  }
  att[idx] = sigmoidf(s);
}

// ---------------- final: rotation max + spatial mean ----------------
// y7 [b][p(144)][40], out[b*10+o]
__global__ void k_final(const float* __restrict__ y7, float* __restrict__ out) {
  int idx = blockIdx.x * blockDim.x + threadIdx.x;
  if (idx >= 320) return;
  int o = idx % 10; int b = idx / 10;
  const float* p = y7 + (size_t)b * 144 * 40;
  float s = 0.f;
  for (int sp = 0; sp < 144; ++sp) {
    f4v v = *(const f4v*)(p + sp * 40 + o * 4);
    s += fmaxf(fmaxf(v[0], v[1]), fmaxf(v[2], v[3]));
  }
  out[idx] = s * (1.f / 144.f);
}

// ---------------- host ----------------

extern "C" void kernel_launch(void* const* d_in, const int* in_sizes, int n_in,
                              void* d_out, int out_size, void* d_ws, size_t ws_size,
                              hipStream_t stream) {
  (void)in_sizes; (void)n_in; (void)out_size; (void)ws_size;
  const float* x   = (const float*)d_in[0];
  const float* w1  = (const float*)d_in[1];
  const float* b1  = (const float*)d_in[2];
  const float* aw1 = (const float*)d_in[3];
  const float* W[6];  const float* BI[6]; const float* AW[6];
  for (int i = 0; i < 6; ++i) {
    W[i]  = (const float*)d_in[4 + 3 * i];
    BI[i] = (const float*)d_in[5 + 3 * i];
    AW[i] = (const float*)d_in[6 + 3 * i];
  }
  const float* G[6]; const float* BE[6];
  for (int i = 0; i < 6; ++i) {
    G[i]  = (const float*)d_in[22 + 2 * i];
    BE[i] = (const float*)d_in[23 + 2 * i];
  }
  float* out = (float*)d_out;

  // workspace (floats): total 14,037,568 floats = 56.15 MB
  float* ws = (float*)d_ws;
  float* A  = ws;                                            // raw conv out fp32, 8,667,136
  unsigned short* XN   = (unsigned short*)(ws + 8667136);    // normalized xn bf16, 8,667,136 ush
  unsigned short* AMAP = (unsigned short*)(ws + 13000704);   // 541,696 ush
  float* ATT = ws + 13271552;                                // 294,912
  unsigned short* WROT = (unsigned short*)(ws + 13566464);   // 811,008 ush
  float* PART  = ws + 13971968;                              // 65,536
  float* STATS = ws + 14037504;                              // 64

  auto cdiv = [](int a, int b) { return (a + b - 1) / b; };

  // weight prep (all 6 GG layers, one launch)
  k_prep_w<<<dim3(cdiv(811008, 256)), dim3(256), 0, stream>>>(
      W[0], W[1], W[2], W[3], W[4], W[5], WROT);
  const unsigned short* WL[6];
  for (int i = 0; i < 5; ++i) WL[i] = WROT + i * 147456;
  WL[5] = WROT + 737280;

  auto bn_stats = [&](const float* buf, int npix, const float* gamma, const float* beta) {
    int S = npix / 64; if (S > 1024) S = 1024; if (S < 1) S = 1;
    k_bn_partial<<<dim3(S), dim3(256), 0, stream>>>(buf, PART, npix, S);
    k_bn_finalize<<<dim3(1), dim3(256), 0, stream>>>(PART, gamma, beta, STATS, npix, S);
  };

  // ---- layer 1: attentive lifting conv ----
  {
    int natt = 32 * 4 * 48 * 48;
    k_att_lift<<<dim3(cdiv(natt, 256)), dim3(256), 0, stream>>>(x, aw1, ATT);
    int n1 = 32 * 2116 * 128;
    k_conv_lift<<<dim3(cdiv(n1, 256)), dim3(256), 0, stream>>>(x, ATT, w1, b1, A);
    int npix = 32 * 2116;
    bn_stats(A, npix, G[0], BE[0]);
    k_meanmax_bn<<<dim3(cdiv(npix, 256)), dim3(256), 0, stream>>>(A, STATS, XN, AMAP, npix);
    k_att_gg<<<dim3(cdiv(npix * 4, 256)), dim3(256), 0, stream>>>(AMAP, AW[0], ATT, 46);
  }
  // ---- layer 2 (H=46 -> 44) + pool ----
  {
    k_conv_mfma<46, 2, 32, 128><<<dim3(128 * 11 * 3), dim3(128), 0, stream>>>(XN, ATT, WL[0], BI[0], A);
    int npix = 32 * 1936;
    bn_stats(A, npix, G[1], BE[1]);
    int np22 = 32 * 484;
    k_meanmax_bn_pool<<<dim3(cdiv(np22, 256)), dim3(256), 0, stream>>>(A, STATS, XN, AMAP);
    k_att_gg<<<dim3(cdiv(np22 * 4, 256)), dim3(256), 0, stream>>>(AMAP, AW[1], ATT, 22);
  }
  // ---- layer 3 (22 -> 20) ----
  {
    k_conv_mfma<22, 2, 32, 128><<<dim3(128 * 5 * 2), dim3(128), 0, stream>>>(XN, ATT, WL[1], BI[1], A);
    int npix = 32 * 400;
    bn_stats(A, npix, G[2], BE[2]);
    k_meanmax_bn<<<dim3(cdiv(npix, 256)), dim3(256), 0, stream>>>(A, STATS, XN, AMAP, npix);
    k_att_gg<<<dim3(cdiv(npix * 4, 256)), dim3(256), 0, stream>>>(AMAP, AW[2], ATT, 20);
  }
  // ---- layer 4 (20 -> 18) ----
  {
    k_conv_mfma<20, 2, 32, 128><<<dim3(128 * 5 * 2), dim3(128), 0, stream>>>(XN, ATT, WL[2], BI[2], A);
    int npix = 32 * 324;
    bn_stats(A, npix, G[3], BE[3]);
    k_meanmax_bn<<<dim3(cdiv(npix, 256)), dim3(256), 0, stream>>>(A, STATS, XN, AMAP, npix);
    k_att_gg<<<dim3(cdiv(npix * 4, 256)), dim3(256), 0, stream>>>(AMAP, AW[3], ATT, 18);
  }
  // ---- layer 5 (18 -> 16) ----
  {
    k_conv_mfma<18, 2, 32, 128><<<dim3(128 * 4 * 1), dim3(128), 0, stream>>>(XN, ATT, WL[3], BI[3], A);
    int npix = 32 * 256;
    bn_stats(A, npix, G[4], BE[4]);
    k_meanmax_bn<<<dim3(cdiv(npix, 256)), dim3(256), 0, stream>>>(A, STATS, XN, AMAP, npix);
    k_att_gg<<<dim3(cdiv(npix * 4, 256)), dim3(256), 0, stream>>>(AMAP, AW[4], ATT, 16);
  }
  // ---- layer 6 (16 -> 14) ----
  {
    k_conv_mfma<16, 2, 32, 128><<<dim3(128 * 4 * 1), dim3(128), 0, stream>>>(XN, ATT, WL[4], BI[4], A);
    int npix = 32 * 196;
    bn_stats(A, npix, G[5], BE[5]);
    k_meanmax_bn<<<dim3(cdiv(npix, 256)), dim3(256), 0, stream>>>(A, STATS, XN, AMAP, npix);
    k_att_gg<<<dim3(cdiv(npix * 4, 256)), dim3(256), 0, stream>>>(AMAP, AW[5], ATT, 14);
  }
  // ---- layer 7 (14 -> 12, O=10, no BN) ----
  k_conv_mfma<14, 1, 10, 40><<<dim3(128 * 3 * 1), dim3(128), 0, stream>>>(XN, ATT, WL[5], BI[5], A);
  // ---- rotation max + spatial mean ----
  k_final<<<dim3(5), dim3(64), 0, stream>>>(A, out);
}

// Round 8
// 709.380 us; speedup vs baseline: 5.2662x; 1.1288x over previous
//
#include <hip/hip_runtime.h>
#include <cstddef>

#define DINL static __device__ __forceinline__

// collision-proof custom vector types (HIP headers own names like short8/float4)
typedef __attribute__((ext_vector_type(4))) float f4v;
typedef __attribute__((ext_vector_type(8))) short bh8;  // 8 bf16 bit patterns (4 VGPRs)

// rot90 applied r times (counter-clockwise, numpy convention): rotated_r[i][j] = w[si][sj]
DINL void rot_src(int r, int K, int i, int j, int& si, int& sj) {
  switch (r & 3) {
    case 0:  si = i;       sj = j;       break;
    case 1:  si = j;       sj = K-1-i;   break;
    case 2:  si = K-1-i;   sj = K-1-j;   break;
    default: si = K-1-j;   sj = i;       break;
  }
}

DINL float sigmoidf(float s) { return 1.f / (1.f + __expf(-s)); }

// float -> bf16 bits, round-to-nearest-even
DINL unsigned short f2bf(float f) {
  unsigned u = __builtin_bit_cast(unsigned, f);
  u += 0x7fffu + ((u >> 16) & 1u);
  return (unsigned short)(u >> 16);
}
DINL float bf2f(unsigned short h) {
  unsigned u = ((unsigned)h) << 16;
  return __builtin_bit_cast(float, u);
}

// ---------------- weight prep ----------------
// Activation channel layout: c' = g*32 + ci  (g = producing rotation, ci = channel).
// A-fragment coalesced layout: bh8 wrot[r][tap][ks][mi][lane(=16q+n)][j8]
//   lane(n,q) holds A[m = mi*16+n][k = q*8+j]; cg = ks*32 + q*8 + j => g=ks, ci=q*8+j.
// Sizes: L2..L6 at L*147456 ushorts (OM=2), L7 at 737280 (OM=1, O=10).
__global__ void k_prep_w(const float* __restrict__ w2, const float* __restrict__ w3,
                         const float* __restrict__ w4, const float* __restrict__ w5,
                         const float* __restrict__ w6, const float* __restrict__ w7,
                         unsigned short* __restrict__ wrot) {
  int idx = blockIdx.x * 256 + threadIdx.x;
  if (idx >= 811008) return;
  const float* w; int OM, O, base;
  if (idx < 737280) {
    int L = idx / 147456; base = L * 147456; OM = 2; O = 32;
    w = (L == 0) ? w2 : (L == 1) ? w3 : (L == 2) ? w4 : (L == 3) ? w5 : w6;
  } else { base = 737280; OM = 1; O = 10; w = w7; }
  int local = idx - base;
  int j = local & 7; int t = local >> 3;
  int lanei = t & 63; t >>= 6;
  int mi = t % OM; t /= OM;
  int ks = t & 3; t >>= 2;
  int tap = t % 9; int r = t / 9;
  int n = lanei & 15, q = lanei >> 4;
  int o = mi * 16 + n;
  int ci = q * 8 + j;
  int gs = (ks - r) & 3;
  int ky = tap / 3, kx = tap % 3;
  int si, sj; rot_src(r, 3, ky, kx, si, sj);
  float val = (o < O) ? w[((o * 32 + ci) * 4 + gs) * 9 + si * 3 + sj] : 0.f;
  wrot[idx] = f2bf(val);
}

// ---------------- layer 1 (lifting) ----------------

__global__ void k_att_lift(const float* __restrict__ x, const float* __restrict__ aw,
                           float* __restrict__ att) {
  const int H = 48, HW = H * H;
  int idx = blockIdx.x * blockDim.x + threadIdx.x;
  if (idx >= 32 * 4 * HW) return;
  int xw = idx % H; int t = idx / H;
  int yh = t % H;  t /= H;
  int r  = t & 3;  int b = t >> 2;
  const float* xb = x + b * HW;
  float s = 0.f;
  for (int ky = 0; ky < 7; ++ky) {
    int y = yh + ky - 3;
    if ((unsigned)y >= (unsigned)H) continue;
    for (int kx = 0; kx < 7; ++kx) {
      int xx = xw + kx - 3;
      if ((unsigned)xx >= (unsigned)H) continue;
      int si, sj; rot_src(r, 7, ky, kx, si, sj);
      s += xb[y * H + xx] * (aw[si * 7 + sj] + aw[49 + si * 7 + sj]);
    }
  }
  att[idx] = sigmoidf(s);
}

// lifting conv, channels-last out: y[(b*2116+p)*128 + r*32 + o]
__global__ void __launch_bounds__(256)
k_conv_lift(const float* __restrict__ x, const float* __restrict__ att,
            const float* __restrict__ w, const float* __restrict__ bias,
            float* __restrict__ y) {
  const int HI = 48, HO = 46, HWO = HO * HO;
  int idx = blockIdx.x * blockDim.x + threadIdx.x;
  if (idx >= 32 * HWO * 128) return;
  int co = idx & 127; int t = idx >> 7;
  int p = t % HWO; int b = t / HWO;
  int r = co >> 5, o = co & 31;
  int yo = p / HO, xo = p % HO;
  const float* xb = x + b * HI * HI;
  const float* ab = att + (b * 4 + r) * HI * HI;
  float acc = bias[o];
  #pragma unroll
  for (int ky = 0; ky < 3; ++ky)
    #pragma unroll
    for (int kx = 0; kx < 3; ++kx) {
      int si, sj; rot_src(r, 3, ky, kx, si, sj);
      int pp = (yo + ky) * HI + xo + kx;
      acc = fmaf(ab[pp] * xb[pp], w[o * 9 + si * 3 + sj], acc);
    }
  y[idx] = acc;
}

// ---------------- MFMA attentive GG conv ----------------
// xn [b][p][128] bf16 (c' = g*32+ci), att [b][4][hw] fp32, weights coalesced (see prep).
// 256 threads = 4 waves; tile 8 rows x 16 cols per (b,r); wave wv does rows 2wv,2wv+1.
// A-loads: wave-uniform base + lane*16B (fully coalesced). B from LDS window.
// Out y [b][p'][OSTR] fp32, channel r*O + o -> f4v stores for O=32.
template<int H, int OM, int O, int OSTR>
__global__ void __launch_bounds__(256, 3)
k_conv_mfma(const unsigned short* __restrict__ xn, const float* __restrict__ att,
            const unsigned short* __restrict__ wl, const float* __restrict__ bias,
            float* __restrict__ y) {
  constexpr int HO = H - 2, HW = H * H;
  constexpr int TR = 8, TC = 16, WR = TR + 2, WC = TC + 2, CGS = 136;
  constexpr int NRT = (HO + TR - 1) / TR, NCT = (HO + TC - 1) / TC;
  __shared__ __align__(16) unsigned short xa[WR * WC * CGS];  // 48960 B

  // XCD swizzle: blockIdx.x % 8 <-> b % 8
  int id = blockIdx.x;
  int slot = id & 7; int k = id >> 3;
  int tile = k % (NRT * NCT); k /= (NRT * NCT);
  int r = k & 3; int bhi = k >> 2;
  int b = bhi * 8 + slot;
  int rt = tile / NCT, ct = tile % NCT;
  int row0 = rt * TR, c0 = ct * TC;

  const unsigned short* xb = xn + (size_t)b * HW * 128;
  const float* ab = att + (size_t)(b * 4 + r) * HW;

  // stage xa = bf16(att * x) window
  for (int u = threadIdx.x; u < WR * WC * 16; u += 256) {
    int cq = u & 15; int pix = u >> 4;
    int wr = pix / WC, wc = pix % WC;
    int row = row0 + wr; if (row > H - 1) row = H - 1;
    int col = c0 + wc;  if (col > H - 1) col = H - 1;
    int p = row * H + col;
    const unsigned short* xp = xb + (size_t)p * 128 + cq * 8;
    float av = ab[p];
    bh8 xv = *(const bh8*)xp;
    bh8 v;
    #pragma unroll
    for (int j2 = 0; j2 < 8; ++j2)
      v[j2] = (short)f2bf(bf2f((unsigned short)xv[j2]) * av);
    *(bh8*)&xa[pix * CGS + cq * 8] = v;
  }
  __syncthreads();

  int lane = threadIdx.x & 63;
  int wv = threadIdx.x >> 6;
  int n = lane & 15, quad = lane >> 4;

  f4v acc[OM][2];
  #pragma unroll
  for (int mi = 0; mi < OM; ++mi)
    #pragma unroll
    for (int ri = 0; ri < 2; ++ri) {
      acc[mi][ri][0] = 0.f; acc[mi][ri][1] = 0.f;
      acc[mi][ri][2] = 0.f; acc[mi][ri][3] = 0.f;
    }

  // coalesced A base for this (r, lane)
  const bh8* wa = (const bh8*)wl + (size_t)r * 9 * 4 * OM * 64 + lane;

  #pragma unroll
  for (int tap = 0; tap < 9; ++tap) {
    constexpr int dummy = 0; (void)dummy;
    int ky = tap / 3, kx = tap % 3;
    int pb0 = ((2 * wv + 0 + ky) * WC + n + kx) * CGS;
    int pb1 = pb0 + WC * CGS;
    #pragma unroll
    for (int ks = 0; ks < 4; ++ks) {
      bh8 b0 = *(const bh8*)&xa[pb0 + ks * 32 + quad * 8];
      bh8 b1 = *(const bh8*)&xa[pb1 + ks * 32 + quad * 8];
      bh8 a0 = wa[(size_t)((tap * 4 + ks) * OM + 0) * 64];
      acc[0][0] = __builtin_amdgcn_mfma_f32_16x16x32_bf16(a0, b0, acc[0][0], 0, 0, 0);
      acc[0][1] = __builtin_amdgcn_mfma_f32_16x16x32_bf16(a0, b1, acc[0][1], 0, 0, 0);
      if constexpr (OM == 2) {
        bh8 a1 = wa[(size_t)((tap * 4 + ks) * OM + 1) * 64];
        acc[1][0] = __builtin_amdgcn_mfma_f32_16x16x32_bf16(a1, b0, acc[1][0], 0, 0, 0);
        acc[1][1] = __builtin_amdgcn_mfma_f32_16x16x32_bf16(a1, b1, acc[1][1], 0, 0, 0);
      }
    }
  }

  // epilogue: C/D col=lane&15 (spatial), row=quad*4+reg (o); c' = r*O + o
  #pragma unroll
  for (int mi = 0; mi < OM; ++mi)
    #pragma unroll
    for (int ri = 0; ri < 2; ++ri) {
      int prow = row0 + 2 * wv + ri;
      int col = c0 + n;
      if (prow < HO && col < HO) {
        float* yp = y + ((size_t)b * HO * HO + prow * HO + col) * OSTR;
        int o0 = mi * 16 + quad * 4;
        f4v v = acc[mi][ri];
        if constexpr (O == 32) {
          f4v w4;
          #pragma unroll
          for (int reg = 0; reg < 4; ++reg) w4[reg] = v[reg] + bias[o0 + reg];
          *(f4v*)(yp + r * 32 + o0) = w4;
        } else {
          #pragma unroll
          for (int reg = 0; reg < 4; ++reg) {
            int o = o0 + reg;
            if (o < O) yp[r * O + o] = v[reg] + bias[o];
          }
        }
      }
    }
}

// ---------------- BatchNorm3d stats (channels-last, S-way parallel) ----------------
// c' = r*32 + o; per-o stats. part[o*1024+s], part[32768+o*1024+s]
__global__ void k_bn_partial(const float* __restrict__ y, float* __restrict__ part,
                             int npix, int S) {
  __shared__ float l1[256], l2[256];
  int s = blockIdx.x;
  int chunk = (npix + S - 1) / S;
  int p0 = s * chunk;
  int p1 = p0 + chunk; if (p1 > npix) p1 = npix;
  int co = threadIdx.x & 127; int slot = threadIdx.x >> 7;
  float s1 = 0.f, s2 = 0.f;
  for (int p = p0 + slot; p < p1; p += 2) {
    float v = y[(size_t)p * 128 + co];
    s1 += v; s2 += v * v;
  }
  l1[threadIdx.x] = s1; l2[threadIdx.x] = s2;
  __syncthreads();
  if (slot == 0) { l1[co] = s1 + l1[128 + co]; l2[co] = s2 + l2[128 + co]; }
  __syncthreads();
  if (threadIdx.x < 32) {
    int o = threadIdx.x;
    float a = 0.f, q = 0.f;
    #pragma unroll
    for (int g = 0; g < 4; ++g) { a += l1[g * 32 + o]; q += l2[g * 32 + o]; }
    part[o * 1024 + s] = a;
    part[32768 + o * 1024 + s] = q;
  }
}

__global__ void k_bn_finalize(const float* __restrict__ part,
                              const float* __restrict__ gamma,
                              const float* __restrict__ beta,
                              float* __restrict__ stats, int npix, int S) {
  __shared__ float l1[256], l2[256];
  int c = threadIdx.x & 31, ch = threadIdx.x >> 5;  // 32 channels x 8 chunks
  float s1 = 0.f, s2 = 0.f;
  for (int s = ch; s < S; s += 8) {
    s1 += part[c * 1024 + s];
    s2 += part[32768 + c * 1024 + s];
  }
  l1[threadIdx.x] = s1; l2[threadIdx.x] = s2;
  __syncthreads();
  if (threadIdx.x < 32) {
    float a = 0.f, q = 0.f;
    #pragma unroll
    for (int k = 0; k < 8; ++k) { a += l1[k * 32 + c]; q += l2[k * 32 + c]; }
    float N = 4.f * (float)npix;
    float m = a / N;
    float v = q / N - m * m;
    float inv = rsqrtf(v + 2e-5f);
    float sc = gamma[c] * inv;
    stats[c] = sc;
    stats[32 + c] = beta[c] - m * sc;
  }
}

// ---------------- fused BN+ReLU+channel mean/max (bf16 xn + bf16 amap out) ----------------
// c' = g*32 + o: chunk cc (4 floats) has g = cc>>3, o base = (cc&7)*4.
__global__ void k_meanmax_bn(const float* __restrict__ yr, const float* __restrict__ stats,
                             unsigned short* __restrict__ xn, unsigned short* __restrict__ amap,
                             int npix) {
  __shared__ float st[64];
  if (threadIdx.x < 64) st[threadIdx.x] = stats[threadIdx.x];
  __syncthreads();
  int idx = blockIdx.x * 256 + threadIdx.x;
  if (idx >= npix) return;
  const float* yp = yr + (size_t)idx * 128;
  unsigned short* xp = xn + (size_t)idx * 128;
  float sm[4] = {0.f, 0.f, 0.f, 0.f};
  float mx[4] = {-1e30f, -1e30f, -1e30f, -1e30f};
  #pragma unroll 4
  for (int oo = 0; oo < 16; ++oo) {  // bh8 chunks; chunk cc pair (2oo, 2oo+1), g = oo>>2
    f4v va = *(const f4v*)(yp + oo * 8);
    f4v vb = *(const f4v*)(yp + oo * 8 + 4);
    int g = oo >> 2;
    int ob0 = ((2 * oo) & 7) * 4, ob1 = ((2 * oo + 1) & 7) * 4;
    bh8 w;
    #pragma unroll
    for (int e = 0; e < 4; ++e) {
      float v0 = fmaxf(fmaf(va[e], st[ob0 + e], st[32 + ob0 + e]), 0.f);
      float v1 = fmaxf(fmaf(vb[e], st[ob1 + e], st[32 + ob1 + e]), 0.f);
      w[e] = (short)f2bf(v0); w[4 + e] = (short)f2bf(v1);
      sm[g] += v0 + v1;
      mx[g] = fmaxf(mx[g], fmaxf(v0, v1));
    }
    *(bh8*)(xp + oo * 8) = w;
  }
  bh8 am;
  #pragma unroll
  for (int g = 0; g < 4; ++g) {
    am[g] = (short)f2bf(sm[g] * (1.f / 32.f));
    am[4 + g] = (short)f2bf(mx[g]);
  }
  *(bh8*)(amap + (size_t)idx * 8) = am;
}

// layer-2 variant: BN+ReLU at 44x44 then 2x2 maxpool -> 22x22
__global__ void k_meanmax_bn_pool(const float* __restrict__ yr, const float* __restrict__ stats,
                                  unsigned short* __restrict__ xn, unsigned short* __restrict__ amap) {
  const int HI = 44, HOq = 22, HWO = HOq * HOq;
  __shared__ float st[64];
  if (threadIdx.x < 64) st[threadIdx.x] = stats[threadIdx.x];
  __syncthreads();
  int idx = blockIdx.x * 256 + threadIdx.x;
  if (idx >= 32 * HWO) return;
  int p22 = idx % HWO; int b = idx / HWO;
  int y0 = (p22 / HOq) * 2, x0 = (p22 % HOq) * 2;
  const float* p00 = yr + ((size_t)b * HI * HI + y0 * HI + x0) * 128;
  unsigned short* xp = xn + (size_t)idx * 128;
  float sm[4] = {0.f, 0.f, 0.f, 0.f};
  float mx[4] = {-1e30f, -1e30f, -1e30f, -1e30f};
  #pragma unroll 2
  for (int oo = 0; oo < 16; ++oo) {
    int g = oo >> 2;
    bh8 w;
    #pragma unroll
    for (int half = 0; half < 2; ++half) {
      int cc = 2 * oo + half;
      int ob = (cc & 7) * 4;
      f4v v0 = *(const f4v*)(p00 + cc * 4);
      f4v v1 = *(const f4v*)(p00 + 128 + cc * 4);
      f4v v2 = *(const f4v*)(p00 + (size_t)HI * 128 + cc * 4);
      f4v v3 = *(const f4v*)(p00 + (size_t)(HI + 1) * 128 + cc * 4);
      #pragma unroll
      for (int e = 0; e < 4; ++e) {
        float sc = st[ob + e], sh = st[32 + ob + e];
        float a0 = fmaxf(fmaf(v0[e], sc, sh), 0.f);
        float a1 = fmaxf(fmaf(v1[e], sc, sh), 0.f);
        float a2 = fmaxf(fmaf(v2[e], sc, sh), 0.f);
        float a3 = fmaxf(fmaf(v3[e], sc, sh), 0.f);
        float val = fmaxf(fmaxf(a0, a1), fmaxf(a2, a3));
        w[half * 4 + e] = (short)f2bf(val);
        sm[g] += val; mx[g] = fmaxf(mx[g], val);
      }
    }
    *(bh8*)(xp + oo * 8) = w;
  }
  bh8 am;
  #pragma unroll
  for (int g = 0; g < 4; ++g) {
    am[g] = (short)f2bf(sm[g] * (1.f / 32.f));
    am[4 + g] = (short)f2bf(mx[g]);
  }
  *(bh8*)(amap + (size_t)idx * 8) = am;
}

// ---------------- attention GG conv (bf16 channels-last amap) ----------------

__global__ void k_att_gg(const unsigned short* __restrict__ amap,
                         const float* __restrict__ aw,
                         float* __restrict__ att, int h) {
  int hw = h * h;
  int idx = blockIdx.x * blockDim.x + threadIdx.x;
  if (idx >= 32 * 4 * hw) return;
  int p = idx % hw; int t = idx / hw;
  int r = t & 3; int b = t >> 2;
  int yh = p / h, xw = p % h;
  float s = 0.f;
  for (int ky = 0; ky < 7; ++ky) {
    int y = yh + ky - 3;
    if ((unsigned)y >= (unsigned)h) continue;
    for (int kx = 0; kx < 7; ++kx) {
      int xx = xw + kx - 3;
      if ((unsigned)xx >= (unsigned)h) continue;
      int si, sj; rot_src(r, 7, ky, kx, si, sj);
      bh8 av = *(const bh8*)(amap + ((size_t)b * hw + y * h + xx) * 8);
      const float* awp = aw + si * 7 + sj;
      #pragma unroll
      for (int g = 0; g < 4; ++g) {
        int gs = (g - r) & 3;
        s += bf2f((unsigned short)av[g]) * awp[gs * 49]
           + bf2f((unsigned short)av[4 + g]) * awp[(4 + gs) * 49];
      }
    }
  }
  att[idx] = sigmoidf(s);
}

// ---------------- final: rotation max + spatial mean ----------------
// y7 [b][p(144)][40] with c' = r*10+o; out[b*10+o]
__global__ void k_final(const float* __restrict__ y7, float* __restrict__ out) {
  int idx = blockIdx.x * blockDim.x + threadIdx.x;
  if (idx >= 320) return;
  int o = idx % 10; int b = idx / 10;
  const float* p = y7 + (size_t)b * 144 * 40;
  float s = 0.f;
  for (int sp = 0; sp < 144; ++sp) {
    const float* q = p + sp * 40 + o;
    float m = fmaxf(fmaxf(q[0], q[10]), fmaxf(q[20], q[30]));
    s += m;
  }
  out[idx] = s * (1.f / 144.f);
}

// ---------------- host ----------------

extern "C" void kernel_launch(void* const* d_in, const int* in_sizes, int n_in,
                              void* d_out, int out_size, void* d_ws, size_t ws_size,
                              hipStream_t stream) {
  (void)in_sizes; (void)n_in; (void)out_size; (void)ws_size;
  const float* x   = (const float*)d_in[0];
  const float* w1  = (const float*)d_in[1];
  const float* b1  = (const float*)d_in[2];
  const float* aw1 = (const float*)d_in[3];
  const float* W[6];  const float* BI[6]; const float* AW[6];
  for (int i = 0; i < 6; ++i) {
    W[i]  = (const float*)d_in[4 + 3 * i];
    BI[i] = (const float*)d_in[5 + 3 * i];
    AW[i] = (const float*)d_in[6 + 3 * i];
  }
  const float* G[6]; const float* BE[6];
  for (int i = 0; i < 6; ++i) {
    G[i]  = (const float*)d_in[22 + 2 * i];
    BE[i] = (const float*)d_in[23 + 2 * i];
  }
  float* out = (float*)d_out;

  // workspace (floats): total 14,037,568 floats = 56.15 MB
  float* ws = (float*)d_ws;
  float* A  = ws;                                            // raw conv out fp32, 8,667,136
  unsigned short* XN   = (unsigned short*)(ws + 8667136);    // normalized xn bf16
  unsigned short* AMAP = (unsigned short*)(ws + 13000704);   // 541,696 ush
  float* ATT = ws + 13271552;                                // 294,912
  unsigned short* WROT = (unsigned short*)(ws + 13566464);   // 811,008 ush
  float* PART  = ws + 13971968;                              // 65,536
  float* STATS = ws + 14037504;                              // 64

  auto cdiv = [](int a, int b) { return (a + b - 1) / b; };

  // weight prep (all 6 GG layers, one launch)
  k_prep_w<<<dim3(cdiv(811008, 256)), dim3(256), 0, stream>>>(
      W[0], W[1], W[2], W[3], W[4], W[5], WROT);
  const unsigned short* WL[6];
  for (int i = 0; i < 5; ++i) WL[i] = WROT + i * 147456;
  WL[5] = WROT + 737280;

  auto bn_stats = [&](const float* buf, int npix, const float* gamma, const float* beta) {
    int S = npix / 64; if (S > 1024) S = 1024; if (S < 1) S = 1;
    k_bn_partial<<<dim3(S), dim3(256), 0, stream>>>(buf, PART, npix, S);
    k_bn_finalize<<<dim3(1), dim3(256), 0, stream>>>(PART, gamma, beta, STATS, npix, S);
  };

  // ---- layer 1: attentive lifting conv ----
  {
    int natt = 32 * 4 * 48 * 48;
    k_att_lift<<<dim3(cdiv(natt, 256)), dim3(256), 0, stream>>>(x, aw1, ATT);
    int n1 = 32 * 2116 * 128;
    k_conv_lift<<<dim3(cdiv(n1, 256)), dim3(256), 0, stream>>>(x, ATT, w1, b1, A);
    int npix = 32 * 2116;
    bn_stats(A, npix, G[0], BE[0]);
    k_meanmax_bn<<<dim3(cdiv(npix, 256)), dim3(256), 0, stream>>>(A, STATS, XN, AMAP, npix);
    k_att_gg<<<dim3(cdiv(npix * 4, 256)), dim3(256), 0, stream>>>(AMAP, AW[0], ATT, 46);
  }
  // ---- layer 2 (H=46 -> 44) + pool ----  NRT=6, NCT=3
  {
    k_conv_mfma<46, 2, 32, 128><<<dim3(128 * 6 * 3), dim3(256), 0, stream>>>(XN, ATT, WL[0], BI[0], A);
    int npix = 32 * 1936;
    bn_stats(A, npix, G[1], BE[1]);
    int np22 = 32 * 484;
    k_meanmax_bn_pool<<<dim3(cdiv(np22, 256)), dim3(256), 0, stream>>>(A, STATS, XN, AMAP);
    k_att_gg<<<dim3(cdiv(np22 * 4, 256)), dim3(256), 0, stream>>>(AMAP, AW[1], ATT, 22);
  }
  // ---- layer 3 (22 -> 20) ----  NRT=3, NCT=2
  {
    k_conv_mfma<22, 2, 32, 128><<<dim3(128 * 3 * 2), dim3(256), 0, stream>>>(XN, ATT, WL[1], BI[1], A);
    int npix = 32 * 400;
    bn_stats(A, npix, G[2], BE[2]);
    k_meanmax_bn<<<dim3(cdiv(npix, 256)), dim3(256), 0, stream>>>(A, STATS, XN, AMAP, npix);
    k_att_gg<<<dim3(cdiv(npix * 4, 256)), dim3(256), 0, stream>>>(AMAP, AW[2], ATT, 20);
  }
  // ---- layer 4 (20 -> 18) ----  NRT=3, NCT=2
  {
    k_conv_mfma<20, 2, 32, 128><<<dim3(128 * 3 * 2), dim3(256), 0, stream>>>(XN, ATT, WL[2], BI[2], A);
    int npix = 32 * 324;
    bn_stats(A, npix, G[3], BE[3]);
    k_meanmax_bn<<<dim3(cdiv(npix, 256)), dim3(256), 0, stream>>>(A, STATS, XN, AMAP, npix);
    k_att_gg<<<dim3(cdiv(npix * 4, 256)), dim3(256), 0, stream>>>(AMAP, AW[3], ATT, 18);
  }
  // ---- layer 5 (18 -> 16) ----  NRT=2, NCT=1
  {
    k_conv_mfma<18, 2, 32, 128><<<dim3(128 * 2 * 1), dim3(256), 0, stream>>>(XN, ATT, WL[3], BI[3], A);
    int npix = 32 * 256;
    bn_stats(A, npix, G[4], BE[4]);
    k_meanmax_bn<<<dim3(cdiv(npix, 256)), dim3(256), 0, stream>>>(A, STATS, XN, AMAP, npix);
    k_att_gg<<<dim3(cdiv(npix * 4, 256)), dim3(256), 0, stream>>>(AMAP, AW[4], ATT, 16);
  }
  // ---- layer 6 (16 -> 14) ----  NRT=2, NCT=1
  {
    k_conv_mfma<16, 2, 32, 128><<<dim3(128 * 2 * 1), dim3(256), 0, stream>>>(XN, ATT, WL[4], BI[4], A);
    int npix = 32 * 196;
    bn_stats(A, npix, G[5], BE[5]);
    k_meanmax_bn<<<dim3(cdiv(npix, 256)), dim3(256), 0, stream>>>(A, STATS, XN, AMAP, npix);
    k_att_gg<<<dim3(cdiv(npix * 4, 256)), dim3(256), 0, stream>>>(AMAP, AW[5], ATT, 14);
  }
  // ---- layer 7 (14 -> 12, O=10, no BN) ----  NRT=2, NCT=1
  k_conv_mfma<14, 1, 10, 40><<<dim3(128 * 2 * 1), dim3(256), 0, stream>>>(XN, ATT, WL[5], BI[5], A);
  // ---- rotation max + spatial mean ----
  k_final<<<dim3(5), dim3(64), 0, stream>>>(A, out);
}

// Round 9
// 633.232 us; speedup vs baseline: 5.8995x; 1.1203x over previous
//
#include <hip/hip_runtime.h>
#include <cstddef>

#define DINL static __device__ __forceinline__

// collision-proof custom vector types (HIP headers own names like short8/float4)
typedef __attribute__((ext_vector_type(4))) float f4v;
typedef __attribute__((ext_vector_type(8))) short bh8;  // 8 bf16 bit patterns (4 VGPRs)

// rot90 applied r times (counter-clockwise, numpy convention): rotated_r[i][j] = w[si][sj]
DINL void rot_src(int r, int K, int i, int j, int& si, int& sj) {
  switch (r & 3) {
    case 0:  si = i;       sj = j;       break;
    case 1:  si = j;       sj = K-1-i;   break;
    case 2:  si = K-1-i;   sj = K-1-j;   break;
    default: si = K-1-j;   sj = i;       break;
  }
}

DINL float sigmoidf(float s) { return 1.f / (1.f + __expf(-s)); }

// float -> bf16 bits, round-to-nearest-even
DINL unsigned short f2bf(float f) {
  unsigned u = __builtin_bit_cast(unsigned, f);
  u += 0x7fffu + ((u >> 16) & 1u);
  return (unsigned short)(u >> 16);
}
DINL float bf2f(unsigned short h) {
  unsigned u = ((unsigned)h) << 16;
  return __builtin_bit_cast(float, u);
}

// ---------------- weight prep ----------------
// Activation channel layout: c' = g*32 + ci  (g = producing rotation, ci = channel).
// A-fragment coalesced layout: bh8 wrot[r][tap][ks][mi][lane(=16q+n)][j8]
//   lane(n,q) holds A[m = mi*16+n][k = q*8+j]; cg = ks*32 + q*8 + j => g=ks, ci=q*8+j.
// Sizes: L2..L6 at L*147456 ushorts (OM=2), L7 at 737280 (OM=1, O=10).
__global__ void k_prep_w(const float* __restrict__ w2, const float* __restrict__ w3,
                         const float* __restrict__ w4, const float* __restrict__ w5,
                         const float* __restrict__ w6, const float* __restrict__ w7,
                         unsigned short* __restrict__ wrot) {
  int idx = blockIdx.x * 256 + threadIdx.x;
  if (idx >= 811008) return;
  const float* w; int OM, O, base;
  if (idx < 737280) {
    int L = idx / 147456; base = L * 147456; OM = 2; O = 32;
    w = (L == 0) ? w2 : (L == 1) ? w3 : (L == 2) ? w4 : (L == 3) ? w5 : w6;
  } else { base = 737280; OM = 1; O = 10; w = w7; }
  int local = idx - base;
  int j = local & 7; int t = local >> 3;
  int lanei = t & 63; t >>= 6;
  int mi = t % OM; t /= OM;
  int ks = t & 3; t >>= 2;
  int tap = t % 9; int r = t / 9;
  int n = lanei & 15, q = lanei >> 4;
  int o = mi * 16 + n;
  int ci = q * 8 + j;
  int gs = (ks - r) & 3;
  int ky = tap / 3, kx = tap % 3;
  int si, sj; rot_src(r, 3, ky, kx, si, sj);
  float val = (o < O) ? w[((o * 32 + ci) * 4 + gs) * 9 + si * 3 + sj] : 0.f;
  wrot[idx] = f2bf(val);
}

// ---------------- layer 1 (lifting) ----------------

__global__ void k_att_lift(const float* __restrict__ x, const float* __restrict__ aw,
                           float* __restrict__ att) {
  const int H = 48, HW = H * H;
  int idx = blockIdx.x * blockDim.x + threadIdx.x;
  if (idx >= 32 * 4 * HW) return;
  int xw = idx % H; int t = idx / H;
  int yh = t % H;  t /= H;
  int r  = t & 3;  int b = t >> 2;
  const float* xb = x + b * HW;
  float s = 0.f;
  for (int ky = 0; ky < 7; ++ky) {
    int y = yh + ky - 3;
    if ((unsigned)y >= (unsigned)H) continue;
    for (int kx = 0; kx < 7; ++kx) {
      int xx = xw + kx - 3;
      if ((unsigned)xx >= (unsigned)H) continue;
      int si, sj; rot_src(r, 7, ky, kx, si, sj);
      s += xb[y * H + xx] * (aw[si * 7 + sj] + aw[49 + si * 7 + sj]);
    }
  }
  att[idx] = sigmoidf(s);
}

// lifting conv, LDS-tiled: block = (b, output row, 8-col group), 256 thr = 8 cols x 32 o
// (lane = col8*32 + o). Each thread computes all 4 rotations for its (o, col).
// rot indices are compile-time (r unrolled); x taps + weights live in registers.
// out: y[(b*2116+p)*128 + r*32 + o]
__global__ void __launch_bounds__(256)
k_conv_lift(const float* __restrict__ x, const float* __restrict__ att,
            const float* __restrict__ w, const float* __restrict__ bias,
            float* __restrict__ y) {
  const int HI = 48, HO = 46;
  __shared__ float xs[3 * 48];
  __shared__ float as[4][3 * 48];
  __shared__ float wsm[288];
  __shared__ float bs[32];
  int id = blockIdx.x;
  int cg = id % 6; int t = id / 6;
  int yo = t % HO; int b = t / HO;

  for (int i = threadIdx.x; i < 144; i += 256)
    xs[i] = x[b * 2304 + (yo + i / 48) * 48 + (i % 48)];
  for (int i = threadIdx.x; i < 576; i += 256) {
    int r = i / 144; int rem = i % 144;
    as[r][rem] = att[(b * 4 + r) * 2304 + (yo + rem / 48) * 48 + (rem % 48)];
  }
  for (int i = threadIdx.x; i < 288; i += 256) wsm[i] = w[i];
  if (threadIdx.x < 32) bs[threadIdx.x] = bias[threadIdx.x];
  __syncthreads();

  int o = threadIdx.x & 31;
  int col = (threadIdx.x >> 5) + cg * 8;
  if (col >= HO) return;

  float wreg[9];
  #pragma unroll
  for (int i = 0; i < 9; ++i) wreg[i] = wsm[o * 9 + i];
  float xv[9];
  #pragma unroll
  for (int ky = 0; ky < 3; ++ky)
    #pragma unroll
    for (int kx = 0; kx < 3; ++kx)
      xv[ky * 3 + kx] = xs[ky * 48 + col + kx];
  float bv = bs[o];
  float* yp = y + ((size_t)b * 2116 + yo * HO + col) * 128 + o;

  #pragma unroll
  for (int r = 0; r < 4; ++r) {
    float acc = bv;
    #pragma unroll
    for (int ky = 0; ky < 3; ++ky)
      #pragma unroll
      for (int kx = 0; kx < 3; ++kx) {
        int si, sj; rot_src(r, 3, ky, kx, si, sj);  // folds: r,ky,kx constant
        acc = fmaf(as[r][ky * 48 + col + kx] * xv[ky * 3 + kx], wreg[si * 3 + sj], acc);
      }
    yp[r * 32] = acc;
  }
}

// ---------------- MFMA attentive GG conv ----------------
// xn [b][p][128] bf16 (c' = g*32+ci), att [b][4][hw] fp32, weights coalesced (see prep).
// 256 threads = 4 waves; tile 8 rows x 16 cols per (b,r); wave wv does rows 2wv,2wv+1.
// A-loads: wave-uniform base + lane*16B (fully coalesced). B from LDS window.
// Out y [b][p'][OSTR] fp32, channel r*O + o -> f4v stores for O=32.
template<int H, int OM, int O, int OSTR>
__global__ void __launch_bounds__(256, 3)
k_conv_mfma(const unsigned short* __restrict__ xn, const float* __restrict__ att,
            const unsigned short* __restrict__ wl, const float* __restrict__ bias,
            float* __restrict__ y) {
  constexpr int HO = H - 2, HW = H * H;
  constexpr int TR = 8, TC = 16, WR = TR + 2, WC = TC + 2, CGS = 136;
  constexpr int NRT = (HO + TR - 1) / TR, NCT = (HO + TC - 1) / TC;
  __shared__ __align__(16) unsigned short xa[WR * WC * CGS];  // 48960 B

  // XCD swizzle: blockIdx.x % 8 <-> b % 8
  int id = blockIdx.x;
  int slot = id & 7; int k = id >> 3;
  int tile = k % (NRT * NCT); k /= (NRT * NCT);
  int r = k & 3; int bhi = k >> 2;
  int b = bhi * 8 + slot;
  int rt = tile / NCT, ct = tile % NCT;
  int row0 = rt * TR, c0 = ct * TC;

  const unsigned short* xb = xn + (size_t)b * HW * 128;
  const float* ab = att + (size_t)(b * 4 + r) * HW;

  // stage xa = bf16(att * x) window
  for (int u = threadIdx.x; u < WR * WC * 16; u += 256) {
    int cq = u & 15; int pix = u >> 4;
    int wr = pix / WC, wc = pix % WC;
    int row = row0 + wr; if (row > H - 1) row = H - 1;
    int col = c0 + wc;  if (col > H - 1) col = H - 1;
    int p = row * H + col;
    const unsigned short* xp = xb + (size_t)p * 128 + cq * 8;
    float av = ab[p];
    bh8 xv = *(const bh8*)xp;
    bh8 v;
    #pragma unroll
    for (int j2 = 0; j2 < 8; ++j2)
      v[j2] = (short)f2bf(bf2f((unsigned short)xv[j2]) * av);
    *(bh8*)&xa[pix * CGS + cq * 8] = v;
  }
  __syncthreads();

  int lane = threadIdx.x & 63;
  int wv = threadIdx.x >> 6;
  int n = lane & 15, quad = lane >> 4;

  f4v acc[OM][2];
  #pragma unroll
  for (int mi = 0; mi < OM; ++mi)
    #pragma unroll
    for (int ri = 0; ri < 2; ++ri) {
      acc[mi][ri][0] = 0.f; acc[mi][ri][1] = 0.f;
      acc[mi][ri][2] = 0.f; acc[mi][ri][3] = 0.f;
    }

  // coalesced A base for this (r, lane)
  const bh8* wa = (const bh8*)wl + (size_t)r * 9 * 4 * OM * 64 + lane;

  #pragma unroll
  for (int tap = 0; tap < 9; ++tap) {
    int ky = tap / 3, kx = tap % 3;
    int pb0 = ((2 * wv + 0 + ky) * WC + n + kx) * CGS;
    int pb1 = pb0 + WC * CGS;
    #pragma unroll
    for (int ks = 0; ks < 4; ++ks) {
      bh8 b0 = *(const bh8*)&xa[pb0 + ks * 32 + quad * 8];
      bh8 b1 = *(const bh8*)&xa[pb1 + ks * 32 + quad * 8];
      bh8 a0 = wa[(size_t)((tap * 4 + ks) * OM + 0) * 64];
      acc[0][0] = __builtin_amdgcn_mfma_f32_16x16x32_bf16(a0, b0, acc[0][0], 0, 0, 0);
      acc[0][1] = __builtin_amdgcn_mfma_f32_16x16x32_bf16(a0, b1, acc[0][1], 0, 0, 0);
      if constexpr (OM == 2) {
        bh8 a1 = wa[(size_t)((tap * 4 + ks) * OM + 1) * 64];
        acc[1][0] = __builtin_amdgcn_mfma_f32_16x16x32_bf16(a1, b0, acc[1][0], 0, 0, 0);
        acc[1][1] = __builtin_amdgcn_mfma_f32_16x16x32_bf16(a1, b1, acc[1][1], 0, 0, 0);
      }
    }
  }

  // epilogue: C/D col=lane&15 (spatial), row=quad*4+reg (o); c' = r*O + o
  #pragma unroll
  for (int mi = 0; mi < OM; ++mi)
    #pragma unroll
    for (int ri = 0; ri < 2; ++ri) {
      int prow = row0 + 2 * wv + ri;
      int col = c0 + n;
      if (prow < HO && col < HO) {
        float* yp = y + ((size_t)b * HO * HO + prow * HO + col) * OSTR;
        int o0 = mi * 16 + quad * 4;
        f4v v = acc[mi][ri];
        if constexpr (O == 32) {
          f4v w4;
          #pragma unroll
          for (int reg = 0; reg < 4; ++reg) w4[reg] = v[reg] + bias[o0 + reg];
          *(f4v*)(yp + r * 32 + o0) = w4;
        } else {
          #pragma unroll
          for (int reg = 0; reg < 4; ++reg) {
            int o = o0 + reg;
            if (o < O) yp[r * O + o] = v[reg] + bias[o];
          }
        }
      }
    }
}

// ---------------- BatchNorm3d partial stats (channels-last, S<=256 blocks) ----------------
// c' = g*32 + o; per-o stats over g. part[o*256+s] = sum, part[8192+o*256+s] = sumsq
__global__ void k_bn_partial(const float* __restrict__ y, float* __restrict__ part,
                             int npix, int S) {
  __shared__ float l1[256], l2[256];
  int s = blockIdx.x;
  int chunk = (npix + S - 1) / S;
  int p0 = s * chunk;
  int p1 = p0 + chunk; if (p1 > npix) p1 = npix;
  int co = threadIdx.x & 127; int slot = threadIdx.x >> 7;
  float s1 = 0.f, s2 = 0.f;
  for (int p = p0 + slot; p < p1; p += 2) {
    float v = y[(size_t)p * 128 + co];
    s1 += v; s2 += v * v;
  }
  l1[threadIdx.x] = s1; l2[threadIdx.x] = s2;
  __syncthreads();
  if (slot == 0) { l1[co] = s1 + l1[128 + co]; l2[co] = s2 + l2[128 + co]; }
  __syncthreads();
  if (threadIdx.x < 32) {
    int o = threadIdx.x;
    float a = 0.f, q = 0.f;
    #pragma unroll
    for (int g = 0; g < 4; ++g) { a += l1[g * 32 + o]; q += l2[g * 32 + o]; }
    part[o * 256 + s] = a;
    part[8192 + o * 256 + s] = q;
  }
}

// in-block BN finalize: reduces part -> st[64] (scale, shift) in LDS
DINL void bn_finalize_lds(const float* __restrict__ part,
                          const float* __restrict__ gamma,
                          const float* __restrict__ beta,
                          float* st, float* l1, float* l2,
                          int npix, int S, int tid) {
  int c = tid & 31, ch = tid >> 5;  // 32 channels x 8 chunks
  float s1 = 0.f, s2 = 0.f;
  for (int s = ch; s < S; s += 8) {
    s1 += part[c * 256 + s];
    s2 += part[8192 + c * 256 + s];
  }
  l1[tid] = s1; l2[tid] = s2;
  __syncthreads();
  if (tid < 32) {
    float a = 0.f, q = 0.f;
    #pragma unroll
    for (int k = 0; k < 8; ++k) { a += l1[k * 32 + c]; q += l2[k * 32 + c]; }
    float N = 4.f * (float)npix;
    float m = a / N;
    float v = q / N - m * m;
    float inv = rsqrtf(v + 2e-5f);
    float sc = gamma[c] * inv;
    st[c] = sc;
    st[32 + c] = beta[c] - m * sc;
  }
  __syncthreads();
}

// ---------------- fused BN-finalize+BN+ReLU+channel mean/max (bf16 out) ----------------
// c' = g*32 + o: chunk cc (4 floats) has g = cc>>3, o base = (cc&7)*4.
__global__ void k_meanmax_bn(const float* __restrict__ yr, const float* __restrict__ part,
                             const float* __restrict__ gamma, const float* __restrict__ beta,
                             unsigned short* __restrict__ xn, unsigned short* __restrict__ amap,
                             int npix, int S) {
  __shared__ float st[64];
  __shared__ float l1[256], l2[256];
  bn_finalize_lds(part, gamma, beta, st, l1, l2, npix, S, threadIdx.x);
  int idx = blockIdx.x * 256 + threadIdx.x;
  if (idx >= npix) return;
  const float* yp = yr + (size_t)idx * 128;
  unsigned short* xp = xn + (size_t)idx * 128;
  float sm[4] = {0.f, 0.f, 0.f, 0.f};
  float mx[4] = {-1e30f, -1e30f, -1e30f, -1e30f};
  #pragma unroll 4
  for (int oo = 0; oo < 16; ++oo) {  // bh8 chunks; chunk cc pair (2oo, 2oo+1), g = oo>>2
    f4v va = *(const f4v*)(yp + oo * 8);
    f4v vb = *(const f4v*)(yp + oo * 8 + 4);
    int g = oo >> 2;
    int ob0 = ((2 * oo) & 7) * 4, ob1 = ((2 * oo + 1) & 7) * 4;
    bh8 w;
    #pragma unroll
    for (int e = 0; e < 4; ++e) {
      float v0 = fmaxf(fmaf(va[e], st[ob0 + e], st[32 + ob0 + e]), 0.f);
      float v1 = fmaxf(fmaf(vb[e], st[ob1 + e], st[32 + ob1 + e]), 0.f);
      w[e] = (short)f2bf(v0); w[4 + e] = (short)f2bf(v1);
      sm[g] += v0 + v1;
      mx[g] = fmaxf(mx[g], fmaxf(v0, v1));
    }
    *(bh8*)(xp + oo * 8) = w;
  }
  bh8 am;
  #pragma unroll
  for (int g = 0; g < 4; ++g) {
    am[g] = (short)f2bf(sm[g] * (1.f / 32.f));
    am[4 + g] = (short)f2bf(mx[g]);
  }
  *(bh8*)(amap + (size_t)idx * 8) = am;
}

// layer-2 variant: BN+ReLU at 44x44 then 2x2 maxpool -> 22x22
__global__ void k_meanmax_bn_pool(const float* __restrict__ yr, const float* __restrict__ part,
                                  const float* __restrict__ gamma, const float* __restrict__ beta,
                                  unsigned short* __restrict__ xn, unsigned short* __restrict__ amap,
                                  int npix, int S) {
  const int HI = 44, HOq = 22, HWO = HOq * HOq;
  __shared__ float st[64];
  __shared__ float l1[256], l2[256];
  bn_finalize_lds(part, gamma, beta, st, l1, l2, npix, S, threadIdx.x);
  int idx = blockIdx.x * 256 + threadIdx.x;
  if (idx >= 32 * HWO) return;
  int p22 = idx % HWO; int b = idx / HWO;
  int y0 = (p22 / HOq) * 2, x0 = (p22 % HOq) * 2;
  const float* p00 = yr + ((size_t)b * HI * HI + y0 * HI + x0) * 128;
  unsigned short* xp = xn + (size_t)idx * 128;
  float sm[4] = {0.f, 0.f, 0.f, 0.f};
  float mx[4] = {-1e30f, -1e30f, -1e30f, -1e30f};
  #pragma unroll 2
  for (int oo = 0; oo < 16; ++oo) {
    int g = oo >> 2;
    bh8 w;
    #pragma unroll
    for (int half = 0; half < 2; ++half) {
      int cc = 2 * oo + half;
      int ob = (cc & 7) * 4;
      f4v v0 = *(const f4v*)(p00 + cc * 4);
      f4v v1 = *(const f4v*)(p00 + 128 + cc * 4);
      f4v v2 = *(const f4v*)(p00 + (size_t)HI * 128 + cc * 4);
      f4v v3 = *(const f4v*)(p00 + (size_t)(HI + 1) * 128 + cc * 4);
      #pragma unroll
      for (int e = 0; e < 4; ++e) {
        float sc = st[ob + e], sh = st[32 + ob + e];
        float a0 = fmaxf(fmaf(v0[e], sc, sh), 0.f);
        float a1 = fmaxf(fmaf(v1[e], sc, sh), 0.f);
        float a2 = fmaxf(fmaf(v2[e], sc, sh), 0.f);
        float a3 = fmaxf(fmaf(v3[e], sc, sh), 0.f);
        float val = fmaxf(fmaxf(a0, a1), fmaxf(a2, a3));
        w[half * 4 + e] = (short)f2bf(val);
        sm[g] += val; mx[g] = fmaxf(mx[g], val);
      }
    }
    *(bh8*)(xp + oo * 8) = w;
  }
  bh8 am;
  #pragma unroll
  for (int g = 0; g < 4; ++g) {
    am[g] = (short)f2bf(sm[g] * (1.f / 32.f));
    am[4 + g] = (short)f2bf(mx[g]);
  }
  *(bh8*)(amap + (size_t)idx * 8) = am;
}

// ---------------- attention GG conv (bf16 channels-last amap) ----------------

__global__ void k_att_gg(const unsigned short* __restrict__ amap,
                         const float* __restrict__ aw,
                         float* __restrict__ att, int h) {
  int hw = h * h;
  int idx = blockIdx.x * blockDim.x + threadIdx.x;
  if (idx >= 32 * 4 * hw) return;
  int p = idx % hw; int t = idx / hw;
  int r = t & 3; int b = t >> 2;
  int yh = p / h, xw = p % h;
  float s = 0.f;
  for (int ky = 0; ky < 7; ++ky) {
    int y = yh + ky - 3;
    if ((unsigned)y >= (unsigned)h) continue;
    for (int kx = 0; kx < 7; ++kx) {
      int xx = xw + kx - 3;
      if ((unsigned)xx >= (unsigned)h) continue;
      int si, sj; rot_src(r, 7, ky, kx, si, sj);
      bh8 av = *(const bh8*)(amap + ((size_t)b * hw + y * h + xx) * 8);
      const float* awp = aw + si * 7 + sj;
      #pragma unroll
      for (int g = 0; g < 4; ++g) {
        int gs = (g - r) & 3;
        s += bf2f((unsigned short)av[g]) * awp[gs * 49]
           + bf2f((unsigned short)av[4 + g]) * awp[(4 + gs) * 49];
      }
    }
  }
  att[idx] = sigmoidf(s);
}

// ---------------- final: rotation max + spatial mean ----------------
// y7 [b][p(144)][40] with c' = r*10+o; out[b*10+o]
__global__ void k_final(const float* __restrict__ y7, float* __restrict__ out) {
  int idx = blockIdx.x * blockDim.x + threadIdx.x;
  if (idx >= 320) return;
  int o = idx % 10; int b = idx / 10;
  const float* p = y7 + (size_t)b * 144 * 40;
  float s = 0.f;
  for (int sp = 0; sp < 144; ++sp) {
    const float* q = p + sp * 40 + o;
    float m = fmaxf(fmaxf(q[0], q[10]), fmaxf(q[20], q[30]));
    s += m;
  }
  out[idx] = s * (1.f / 144.f);
}

// ---------------- host ----------------

extern "C" void kernel_launch(void* const* d_in, const int* in_sizes, int n_in,
                              void* d_out, int out_size, void* d_ws, size_t ws_size,
                              hipStream_t stream) {
  (void)in_sizes; (void)n_in; (void)out_size; (void)ws_size;
  const float* x   = (const float*)d_in[0];
  const float* w1  = (const float*)d_in[1];
  const float* b1  = (const float*)d_in[2];
  const float* aw1 = (const float*)d_in[3];
  const float* W[6];  const float* BI[6]; const float* AW[6];
  for (int i = 0; i < 6; ++i) {
    W[i]  = (const float*)d_in[4 + 3 * i];
    BI[i] = (const float*)d_in[5 + 3 * i];
    AW[i] = (const float*)d_in[6 + 3 * i];
  }
  const float* G[6]; const float* BE[6];
  for (int i = 0; i < 6; ++i) {
    G[i]  = (const float*)d_in[22 + 2 * i];
    BE[i] = (const float*)d_in[23 + 2 * i];
  }
  float* out = (float*)d_out;

  // workspace (floats): ~56 MB
  float* ws = (float*)d_ws;
  float* A  = ws;                                            // raw conv out fp32, 8,667,136
  unsigned short* XN   = (unsigned short*)(ws + 8667136);    // normalized xn bf16
  unsigned short* AMAP = (unsigned short*)(ws + 13000704);   // 541,696 ush
  float* ATT = ws + 13271552;                                // 294,912
  unsigned short* WROT = (unsigned short*)(ws + 13566464);   // 811,008 ush
  float* PART  = ws + 13971968;                              // 16,384

  auto cdiv = [](int a, int b) { return (a + b - 1) / b; };
  auto Sfor = [](int npix) {
    int S = npix / 64; if (S > 256) S = 256; if (S < 1) S = 1;
    return S;
  };

  // weight prep (all 6 GG layers, one launch)
  k_prep_w<<<dim3(cdiv(811008, 256)), dim3(256), 0, stream>>>(
      W[0], W[1], W[2], W[3], W[4], W[5], WROT);
  const unsigned short* WL[6];
  for (int i = 0; i < 5; ++i) WL[i] = WROT + i * 147456;
  WL[5] = WROT + 737280;

  // ---- layer 1: attentive lifting conv ----
  {
    int natt = 32 * 4 * 48 * 48;
    k_att_lift<<<dim3(cdiv(natt, 256)), dim3(256), 0, stream>>>(x, aw1, ATT);
    k_conv_lift<<<dim3(32 * 46 * 6), dim3(256), 0, stream>>>(x, ATT, w1, b1, A);
    int npix = 32 * 2116;
    int S = Sfor(npix);
    k_bn_partial<<<dim3(S), dim3(256), 0, stream>>>(A, PART, npix, S);
    k_meanmax_bn<<<dim3(cdiv(npix, 256)), dim3(256), 0, stream>>>(A, PART, G[0], BE[0], XN, AMAP, npix, S);
    k_att_gg<<<dim3(cdiv(npix * 4, 256)), dim3(256), 0, stream>>>(AMAP, AW[0], ATT, 46);
  }
  // ---- layer 2 (H=46 -> 44) + pool ----  NRT=6, NCT=3
  {
    k_conv_mfma<46, 2, 32, 128><<<dim3(128 * 6 * 3), dim3(256), 0, stream>>>(XN, ATT, WL[0], BI[0], A);
    int npix = 32 * 1936;
    int S = Sfor(npix);
    k_bn_partial<<<dim3(S), dim3(256), 0, stream>>>(A, PART, npix, S);
    int np22 = 32 * 484;
    k_meanmax_bn_pool<<<dim3(cdiv(np22, 256)), dim3(256), 0, stream>>>(A, PART, G[1], BE[1], XN, AMAP, npix, S);
    k_att_gg<<<dim3(cdiv(np22 * 4, 256)), dim3(256), 0, stream>>>(AMAP, AW[1], ATT, 22);
  }
  // ---- layer 3 (22 -> 20) ----  NRT=3, NCT=2
  {
    k_conv_mfma<22, 2, 32, 128><<<dim3(128 * 3 * 2), dim3(256), 0, stream>>>(XN, ATT, WL[1], BI[1], A);
    int npix = 32 * 400;
    int S = Sfor(npix);
    k_bn_partial<<<dim3(S), dim3(256), 0, stream>>>(A, PART, npix, S);
    k_meanmax_bn<<<dim3(cdiv(npix, 256)), dim3(256), 0, stream>>>(A, PART, G[2], BE[2], XN, AMAP, npix, S);
    k_att_gg<<<dim3(cdiv(npix * 4, 256)), dim3(256), 0, stream>>>(AMAP, AW[2], ATT, 20);
  }
  // ---- layer 4 (20 -> 18) ----  NRT=3, NCT=2
  {
    k_conv_mfma<20, 2, 32, 128><<<dim3(128 * 3 * 2), dim3(256), 0, stream>>>(XN, ATT, WL[2], BI[2], A);
    int npix = 32 * 324;
    int S = Sfor(npix);
    k_bn_partial<<<dim3(S), dim3(256), 0, stream>>>(A, PART, npix, S);
    k_meanmax_bn<<<dim3(cdiv(npix, 256)), dim3(256), 0, stream>>>(A, PART, G[3], BE[3], XN, AMAP, npix, S);
    k_att_gg<<<dim3(cdiv(npix * 4, 256)), dim3(256), 0, stream>>>(AMAP, AW[3], ATT, 18);
  }
  // ---- layer 5 (18 -> 16) ----  NRT=2, NCT=1
  {
    k_conv_mfma<18, 2, 32, 128><<<dim3(128 * 2 * 1), dim3(256), 0, stream>>>(XN, ATT, WL[3], BI[3], A);
    int npix = 32 * 256;
    int S = Sfor(npix);
    k_bn_partial<<<dim3(S), dim3(256), 0, stream>>>(A, PART, npix, S);
    k_meanmax_bn<<<dim3(cdiv(npix, 256)), dim3(256), 0, stream>>>(A, PART, G[4], BE[4], XN, AMAP, npix, S);
    k_att_gg<<<dim3(cdiv(npix * 4, 256)), dim3(256), 0, stream>>>(AMAP, AW[4], ATT, 16);
  }
  // ---- layer 6 (16 -> 14) ----  NRT=2, NCT=1
  {
    k_conv_mfma<16, 2, 32, 128><<<dim3(128 * 2 * 1), dim3(256), 0, stream>>>(XN, ATT, WL[4], BI[4], A);
    int npix = 32 * 196;
    int S = Sfor(npix);
    k_bn_partial<<<dim3(S), dim3(256), 0, stream>>>(A, PART, npix, S);
    k_meanmax_bn<<<dim3(cdiv(npix, 256)), dim3(256), 0, stream>>>(A, PART, G[5], BE[5], XN, AMAP, npix, S);
    k_att_gg<<<dim3(cdiv(npix * 4, 256)), dim3(256), 0, stream>>>(AMAP, AW[5], ATT, 14);
  }
  // ---- layer 7 (14 -> 12, O=10, no BN) ----  NRT=2, NCT=1
  k_conv_mfma<14, 1, 10, 40><<<dim3(128 * 2 * 1), dim3(256), 0, stream>>>(XN, ATT, WL[5], BI[5], A);
  // ---- rotation max + spatial mean ----
  k_final<<<dim3(5), dim3(64), 0, stream>>>(A, out);
}

// Round 10
// 558.106 us; speedup vs baseline: 6.6936x; 1.1346x over previous
//
#include <hip/hip_runtime.h>
#include <cstddef>

#define DINL static __device__ __forceinline__

// collision-proof custom vector types (HIP headers own names like short8/float4)
typedef __attribute__((ext_vector_type(4))) float f4v;
typedef __attribute__((ext_vector_type(8))) short bh8;  // 8 bf16 bit patterns (4 VGPRs)

// rot90 applied r times (counter-clockwise, numpy convention): rotated_r[i][j] = w[si][sj]
DINL void rot_src(int r, int K, int i, int j, int& si, int& sj) {
  switch (r & 3) {
    case 0:  si = i;       sj = j;       break;
    case 1:  si = j;       sj = K-1-i;   break;
    case 2:  si = K-1-i;   sj = K-1-j;   break;
    default: si = K-1-j;   sj = i;       break;
  }
}

DINL float sigmoidf(float s) { return 1.f / (1.f + __expf(-s)); }

// float -> bf16 bits, round-to-nearest-even
DINL unsigned short f2bf(float f) {
  unsigned u = __builtin_bit_cast(unsigned, f);
  u += 0x7fffu + ((u >> 16) & 1u);
  return (unsigned short)(u >> 16);
}
DINL float bf2f(unsigned short h) {
  unsigned u = ((unsigned)h) << 16;
  return __builtin_bit_cast(float, u);
}

// ---------------- weight prep ----------------
// Activation channel layout: c' = g*32 + ci  (g = producing rotation, ci = channel).
// A-fragment coalesced layout: bh8 wrot[r][tap][ks][mi][lane(=16q+n)][j8]
//   lane(n,q) holds A[m = mi*16+n][k = q*8+j]; cg = ks*32 + q*8 + j => g=ks, ci=q*8+j.
// Sizes: L2..L6 at L*147456 ushorts (OM=2), L7 at 737280 (OM=1, O=10).
__global__ void k_prep_w(const float* __restrict__ w2, const float* __restrict__ w3,
                         const float* __restrict__ w4, const float* __restrict__ w5,
                         const float* __restrict__ w6, const float* __restrict__ w7,
                         unsigned short* __restrict__ wrot) {
  int idx = blockIdx.x * 256 + threadIdx.x;
  if (idx >= 811008) return;
  const float* w; int OM, O, base;
  if (idx < 737280) {
    int L = idx / 147456; base = L * 147456; OM = 2; O = 32;
    w = (L == 0) ? w2 : (L == 1) ? w3 : (L == 2) ? w4 : (L == 3) ? w5 : w6;
  } else { base = 737280; OM = 1; O = 10; w = w7; }
  int local = idx - base;
  int j = local & 7; int t = local >> 3;
  int lanei = t & 63; t >>= 6;
  int mi = t % OM; t /= OM;
  int ks = t & 3; t >>= 2;
  int tap = t % 9; int r = t / 9;
  int n = lanei & 15, q = lanei >> 4;
  int o = mi * 16 + n;
  int ci = q * 8 + j;
  int gs = (ks - r) & 3;
  int ky = tap / 3, kx = tap % 3;
  int si, sj; rot_src(r, 3, ky, kx, si, sj);
  float val = (o < O) ? w[((o * 32 + ci) * 4 + gs) * 9 + si * 3 + sj] : 0.f;
  wrot[idx] = f2bf(val);
}

// ---------------- layer 1: fused att-lift + lifting conv + BN partial stats ----------------
// block = (b, output row yo, 8-col group cg); 256 thr = 8 cols x 32 o.
// Stages x rows [yo-3, yo+5] (zero-padded), computes the 4r x 3x10 attention patch
// inline (CBAM lift: single channel -> mean==max==x), then the conv.
// Stats: per-o sum/sumsq -> LDS atomics -> bucketed global atomicAdd into partl.
__global__ void __launch_bounds__(256)
k_conv_lift(const float* __restrict__ x, const float* __restrict__ aw,
            const float* __restrict__ w, const float* __restrict__ bias,
            float* __restrict__ y, float* __restrict__ partl) {
  const int HO = 46;
  __shared__ float xs2[9 * 48];
  __shared__ float as2[4][32];
  __shared__ float wsm[288];
  __shared__ float bs[32];
  __shared__ float bnred[64];
  int id = blockIdx.x;
  int cg = id % 6; int t = id / 6;
  int yo = t % HO; int b = t / HO;

  for (int i = threadIdx.x; i < 9 * 48; i += 256) {
    int rr = yo - 3 + i / 48;
    xs2[i] = ((unsigned)rr < 48u) ? x[b * 2304 + rr * 48 + (i % 48)] : 0.f;
  }
  for (int i = threadIdx.x; i < 288; i += 256) wsm[i] = w[i];
  if (threadIdx.x < 32) bs[threadIdx.x] = bias[threadIdx.x];
  if (threadIdx.x < 64) bnred[threadIdx.x] = 0.f;
  __syncthreads();

  // attention patch: r in 0..3, rows yo..yo+2 (ar 0..2), cols cg*8..cg*8+9 (ac 0..9)
  if (threadIdx.x < 120) {
    int r = threadIdx.x / 30; int rem = threadIdx.x % 30;
    int ar = rem / 10, ac = rem % 10;
    int ax = cg * 8 + ac;
    float s = 0.f;
    if (ax < 48) {
      for (int i = 0; i < 7; ++i)
        for (int j = 0; j < 7; ++j) {
          int xx = ax + j - 3;
          if ((unsigned)xx >= 48u) continue;
          int si, sj; rot_src(r, 7, i, j, si, sj);
          s += xs2[(ar + i) * 48 + xx] * (aw[si * 7 + sj] + aw[49 + si * 7 + sj]);
        }
    }
    as2[r][ar * 10 + ac] = sigmoidf(s);
  }
  __syncthreads();

  int o = threadIdx.x & 31;
  int cl = threadIdx.x >> 5;
  int col = cl + cg * 8;
  bool active = (col < HO);
  float sacc = 0.f, qacc = 0.f;
  if (active) {
    float wreg[9];
    #pragma unroll
    for (int i = 0; i < 9; ++i) wreg[i] = wsm[o * 9 + i];
    float xv[9];
    #pragma unroll
    for (int ky = 0; ky < 3; ++ky)
      #pragma unroll
      for (int kx = 0; kx < 3; ++kx)
        xv[ky * 3 + kx] = xs2[(3 + ky) * 48 + col + kx];
    float bv = bs[o];
    float* yp = y + ((size_t)b * 2116 + yo * HO + col) * 128 + o;
    #pragma unroll
    for (int r = 0; r < 4; ++r) {
      float acc = bv;
      #pragma unroll
      for (int ky = 0; ky < 3; ++ky)
        #pragma unroll
        for (int kx = 0; kx < 3; ++kx) {
          int si, sj; rot_src(r, 3, ky, kx, si, sj);  // folds: r,ky,kx constant
          acc = fmaf(as2[r][ky * 10 + cl + kx] * xv[ky * 3 + kx], wreg[si * 3 + sj], acc);
        }
      yp[r * 32] = acc;
      sacc += acc; qacc += acc * acc;
    }
  }
  atomicAdd(&bnred[o], sacc);
  atomicAdd(&bnred[32 + o], qacc);
  __syncthreads();
  if (threadIdx.x < 64) {
    int bucket = blockIdx.x & 63;
    int c = threadIdx.x & 31;
    int off = (threadIdx.x < 32) ? c : (64 + c);
    atomicAdd(&partl[bucket * 128 + off], bnred[threadIdx.x]);
  }
}

// ---------------- MFMA attentive GG conv (split-K staging + fused BN stats) ----------------
// xn [b][p][128] bf16 (c' = g*32+ci), att [b][4][hw] fp32, weights coalesced (see prep).
// 256 threads = 4 waves; tile 8 rows x 16 cols per (b,r); wave wv does rows 2wv,2wv+1.
// Split-K: stage 64 channels (half) at a time -> LDS 25 KB -> 6 blocks/CU.
// A-loads wave-coalesced from global; B from LDS window (2-way bank alias = free).
// Out y [b][p'][OSTR] fp32 (c' = r*O+o). BNS: per-o sum/sumsq via shfl + bucketed atomics.
template<int H, int OM, int O, int OSTR, bool BNS>
__global__ void __launch_bounds__(256)
k_conv_mfma(const unsigned short* __restrict__ xn, const float* __restrict__ att,
            const unsigned short* __restrict__ wl, const float* __restrict__ bias,
            float* __restrict__ y, float* __restrict__ partl) {
  constexpr int HO = H - 2, HW = H * H;
  constexpr int TR = 8, TC = 16, WR = TR + 2, WC = TC + 2, CGH = 68;
  constexpr int NRT = (HO + TR - 1) / TR, NCT = (HO + TC - 1) / TC;
  __shared__ __align__(16) unsigned short xa[WR * WC * CGH];  // 24,480 B
  __shared__ float bnred[128];

  // XCD swizzle: blockIdx.x % 8 <-> b % 8
  int id = blockIdx.x;
  int slot = id & 7; int k = id >> 3;
  int tile = k % (NRT * NCT); k /= (NRT * NCT);
  int r = k & 3; int bhi = k >> 2;
  int b = bhi * 8 + slot;
  int rt = tile / NCT, ct = tile % NCT;
  int row0 = rt * TR, c0 = ct * TC;

  const unsigned short* xb = xn + (size_t)b * HW * 128;
  const float* ab = att + (size_t)(b * 4 + r) * HW;

  int lane = threadIdx.x & 63;
  int wv = threadIdx.x >> 6;
  int n = lane & 15, quad = lane >> 4;

  f4v acc[OM][2];
  #pragma unroll
  for (int mi = 0; mi < OM; ++mi)
    #pragma unroll
    for (int ri = 0; ri < 2; ++ri) {
      acc[mi][ri][0] = 0.f; acc[mi][ri][1] = 0.f;
      acc[mi][ri][2] = 0.f; acc[mi][ri][3] = 0.f;
    }

  const bh8* wa = (const bh8*)wl + (size_t)r * 9 * 4 * OM * 64 + lane;

  for (int half = 0; half < 2; ++half) {
    if (half) __syncthreads();  // all reads of previous half done
    // stage 64 channels: xa[pix][ch(8 chunks of 8 ushorts)]
    for (int u = threadIdx.x; u < WR * WC * 8; u += 256) {
      int ch = u & 7; int pix = u >> 3;
      int wr = pix / WC, wc = pix % WC;
      int row = row0 + wr; if (row > H - 1) row = H - 1;
      int col = c0 + wc;  if (col > H - 1) col = H - 1;
      int p = row * H + col;
      const unsigned short* xp = xb + (size_t)p * 128 + half * 64 + ch * 8;
      float av = ab[p];
      bh8 xv = *(const bh8*)xp;
      bh8 v;
      #pragma unroll
      for (int j2 = 0; j2 < 8; ++j2)
        v[j2] = (short)f2bf(bf2f((unsigned short)xv[j2]) * av);
      *(bh8*)&xa[pix * CGH + ch * 8] = v;
    }
    __syncthreads();

    #pragma unroll
    for (int tap = 0; tap < 9; ++tap) {
      int ky = tap / 3, kx = tap % 3;
      int pb0 = ((2 * wv + ky) * WC + n + kx) * CGH;
      int pb1 = pb0 + WC * CGH;
      #pragma unroll
      for (int kl = 0; kl < 2; ++kl) {
        int ks = half * 2 + kl;
        bh8 b0 = *(const bh8*)&xa[pb0 + kl * 32 + quad * 8];
        bh8 b1 = *(const bh8*)&xa[pb1 + kl * 32 + quad * 8];
        bh8 a0 = wa[(size_t)((tap * 4 + ks) * OM + 0) * 64];
        acc[0][0] = __builtin_amdgcn_mfma_f32_16x16x32_bf16(a0, b0, acc[0][0], 0, 0, 0);
        acc[0][1] = __builtin_amdgcn_mfma_f32_16x16x32_bf16(a0, b1, acc[0][1], 0, 0, 0);
        if constexpr (OM == 2) {
          bh8 a1 = wa[(size_t)((tap * 4 + ks) * OM + 1) * 64];
          acc[1][0] = __builtin_amdgcn_mfma_f32_16x16x32_bf16(a1, b0, acc[1][0], 0, 0, 0);
          acc[1][1] = __builtin_amdgcn_mfma_f32_16x16x32_bf16(a1, b1, acc[1][1], 0, 0, 0);
        }
      }
    }
  }

  // epilogue: C/D col=lane&15 (spatial), row=quad*4+reg (o); c' = r*O + o
  float sv[OM * 4], qv[OM * 4];
  #pragma unroll
  for (int e = 0; e < OM * 4; ++e) { sv[e] = 0.f; qv[e] = 0.f; }
  #pragma unroll
  for (int mi = 0; mi < OM; ++mi)
    #pragma unroll
    for (int ri = 0; ri < 2; ++ri) {
      int prow = row0 + 2 * wv + ri;
      int col = c0 + n;
      if (prow < HO && col < HO) {
        float* yp = y + ((size_t)b * HO * HO + prow * HO + col) * OSTR;
        int o0 = mi * 16 + quad * 4;
        f4v v = acc[mi][ri];
        if constexpr (O == 32) {
          f4v w4;
          #pragma unroll
          for (int reg = 0; reg < 4; ++reg) {
            float val = v[reg] + bias[o0 + reg];
            w4[reg] = val;
            if constexpr (BNS) { sv[mi * 4 + reg] += val; qv[mi * 4 + reg] += val * val; }
          }
          *(f4v*)(yp + r * 32 + o0) = w4;
        } else {
          #pragma unroll
          for (int reg = 0; reg < 4; ++reg) {
            int o = o0 + reg;
            if (o < O) yp[r * O + o] = v[reg] + bias[o];
          }
        }
      }
    }

  if constexpr (BNS) {
    #pragma unroll
    for (int e = 0; e < OM * 4; ++e) {
      #pragma unroll
      for (int off = 1; off < 16; off <<= 1) {
        sv[e] += __shfl_xor(sv[e], off);
        qv[e] += __shfl_xor(qv[e], off);
      }
    }
    if (threadIdx.x < 128) bnred[threadIdx.x] = 0.f;
    __syncthreads();
    if (n == 0) {
      #pragma unroll
      for (int e = 0; e < OM * 4; ++e) {
        int o = (e >> 2) * 16 + quad * 4 + (e & 3);
        atomicAdd(&bnred[o], sv[e]);
        atomicAdd(&bnred[64 + o], qv[e]);
      }
    }
    __syncthreads();
    if (threadIdx.x < 128)
      atomicAdd(&partl[(blockIdx.x & 63) * 128 + threadIdx.x], bnred[threadIdx.x]);
  }
}

// ---------------- BN finalize from bucketed partials (in-block) ----------------
// partl: 64 buckets x [sum[32] at 0..63? no: sums at [b*128+c], sq at [b*128+64+c]]
DINL void bn_finalize2(const float* __restrict__ partl,
                       const float* __restrict__ gamma, const float* __restrict__ beta,
                       float* st, int npix, int tid) {
  if (tid < 32) {
    float s1 = 0.f, s2 = 0.f;
    for (int bk = 0; bk < 64; ++bk) {
      s1 += partl[bk * 128 + tid];
      s2 += partl[bk * 128 + 64 + tid];
    }
    float N = 4.f * (float)npix;
    float m = s1 / N;
    float v = s2 / N - m * m;
    float inv = rsqrtf(v + 2e-5f);
    float sc = gamma[tid] * inv;
    st[tid] = sc;
    st[32 + tid] = beta[tid] - m * sc;
  }
  __syncthreads();
}

// ---------------- fused BN-finalize+BN+ReLU+channel mean/max (bf16 out) ----------------
// c' = g*32 + o: chunk cc (4 floats) has g = cc>>3, o base = (cc&7)*4.
__global__ void k_meanmax_bn(const float* __restrict__ yr, const float* __restrict__ partl,
                             const float* __restrict__ gamma, const float* __restrict__ beta,
                             unsigned short* __restrict__ xn, unsigned short* __restrict__ amap,
                             int npix) {
  __shared__ float st[64];
  bn_finalize2(partl, gamma, beta, st, npix, threadIdx.x);
  int idx = blockIdx.x * 256 + threadIdx.x;
  if (idx >= npix) return;
  const float* yp = yr + (size_t)idx * 128;
  unsigned short* xp = xn + (size_t)idx * 128;
  float sm[4] = {0.f, 0.f, 0.f, 0.f};
  float mx[4] = {-1e30f, -1e30f, -1e30f, -1e30f};
  #pragma unroll 4
  for (int oo = 0; oo < 16; ++oo) {  // bh8 chunks; chunk cc pair (2oo, 2oo+1), g = oo>>2
    f4v va = *(const f4v*)(yp + oo * 8);
    f4v vb = *(const f4v*)(yp + oo * 8 + 4);
    int g = oo >> 2;
    int ob0 = ((2 * oo) & 7) * 4, ob1 = ((2 * oo + 1) & 7) * 4;
    bh8 w;
    #pragma unroll
    for (int e = 0; e < 4; ++e) {
      float v0 = fmaxf(fmaf(va[e], st[ob0 + e], st[32 + ob0 + e]), 0.f);
      float v1 = fmaxf(fmaf(vb[e], st[ob1 + e], st[32 + ob1 + e]), 0.f);
      w[e] = (short)f2bf(v0); w[4 + e] = (short)f2bf(v1);
      sm[g] += v0 + v1;
      mx[g] = fmaxf(mx[g], fmaxf(v0, v1));
    }
    *(bh8*)(xp + oo * 8) = w;
  }
  bh8 am;
  #pragma unroll
  for (int g = 0; g < 4; ++g) {
    am[g] = (short)f2bf(sm[g] * (1.f / 32.f));
    am[4 + g] = (short)f2bf(mx[g]);
  }
  *(bh8*)(amap + (size_t)idx * 8) = am;
}

// layer-2 variant: BN+ReLU at 44x44 then 2x2 maxpool -> 22x22
__global__ void k_meanmax_bn_pool(const float* __restrict__ yr, const float* __restrict__ partl,
                                  const float* __restrict__ gamma, const float* __restrict__ beta,
                                  unsigned short* __restrict__ xn, unsigned short* __restrict__ amap,
                                  int npix) {
  const int HI = 44, HOq = 22, HWO = HOq * HOq;
  __shared__ float st[64];
  bn_finalize2(partl, gamma, beta, st, npix, threadIdx.x);
  int idx = blockIdx.x * 256 + threadIdx.x;
  if (idx >= 32 * HWO) return;
  int p22 = idx % HWO; int b = idx / HWO;
  int y0 = (p22 / HOq) * 2, x0 = (p22 % HOq) * 2;
  const float* p00 = yr + ((size_t)b * HI * HI + y0 * HI + x0) * 128;
  unsigned short* xp = xn + (size_t)idx * 128;
  float sm[4] = {0.f, 0.f, 0.f, 0.f};
  float mx[4] = {-1e30f, -1e30f, -1e30f, -1e30f};
  #pragma unroll 2
  for (int oo = 0; oo < 16; ++oo) {
    int g = oo >> 2;
    bh8 w;
    #pragma unroll
    for (int half = 0; half < 2; ++half) {
      int cc = 2 * oo + half;
      int ob = (cc & 7) * 4;
      f4v v0 = *(const f4v*)(p00 + cc * 4);
      f4v v1 = *(const f4v*)(p00 + 128 + cc * 4);
      f4v v2 = *(const f4v*)(p00 + (size_t)HI * 128 + cc * 4);
      f4v v3 = *(const f4v*)(p00 + (size_t)(HI + 1) * 128 + cc * 4);
      #pragma unroll
      for (int e = 0; e < 4; ++e) {
        float sc = st[ob + e], sh = st[32 + ob + e];
        float a0 = fmaxf(fmaf(v0[e], sc, sh), 0.f);
        float a1 = fmaxf(fmaf(v1[e], sc, sh), 0.f);
        float a2 = fmaxf(fmaf(v2[e], sc, sh), 0.f);
        float a3 = fmaxf(fmaf(v3[e], sc, sh), 0.f);
        float val = fmaxf(fmaxf(a0, a1), fmaxf(a2, a3));
        w[half * 4 + e] = (short)f2bf(val);
        sm[g] += val; mx[g] = fmaxf(mx[g], val);
      }
    }
    *(bh8*)(xp + oo * 8) = w;
  }
  bh8 am;
  #pragma unroll
  for (int g = 0; g < 4; ++g) {
    am[g] = (short)f2bf(sm[g] * (1.f / 32.f));
    am[4 + g] = (short)f2bf(mx[g]);
  }
  *(bh8*)(amap + (size_t)idx * 8) = am;
}

// ---------------- attention GG conv (bf16 channels-last amap) ----------------

__global__ void k_att_gg(const unsigned short* __restrict__ amap,
                         const float* __restrict__ aw,
                         float* __restrict__ att, int h) {
  int hw = h * h;
  int idx = blockIdx.x * blockDim.x + threadIdx.x;
  if (idx >= 32 * 4 * hw) return;
  int p = idx % hw; int t = idx / hw;
  int r = t & 3; int b = t >> 2;
  int yh = p / h, xw = p % h;
  float s = 0.f;
  for (int ky = 0; ky < 7; ++ky) {
    int y = yh + ky - 3;
    if ((unsigned)y >= (unsigned)h) continue;
    for (int kx = 0; kx < 7; ++kx) {
      int xx = xw + kx - 3;
      if ((unsigned)xx >= (unsigned)h) continue;
      int si, sj; rot_src(r, 7, ky, kx, si, sj);
      bh8 av = *(const bh8*)(amap + ((size_t)b * hw + y * h + xx) * 8);
      const float* awp = aw + si * 7 + sj;
      #pragma unroll
      for (int g = 0; g < 4; ++g) {
        int gs = (g - r) & 3;
        s += bf2f((unsigned short)av[g]) * awp[gs * 49]
           + bf2f((unsigned short)av[4 + g]) * awp[(4 + gs) * 49];
      }
    }
  }
  att[idx] = sigmoidf(s);
}

// ---------------- final: rotation max + spatial mean ----------------
// y7 [b][p(144)][40] with c' = r*10+o; out[b*10+o]
__global__ void k_final(const float* __restrict__ y7, float* __restrict__ out) {
  int idx = blockIdx.x * blockDim.x + threadIdx.x;
  if (idx >= 320) return;
  int o = idx % 10; int b = idx / 10;
  const float* p = y7 + (size_t)b * 144 * 40;
  float s = 0.f;
  for (int sp = 0; sp < 144; ++sp) {
    const float* q = p + sp * 40 + o;
    float m = fmaxf(fmaxf(q[0], q[10]), fmaxf(q[20], q[30]));
    s += m;
  }
  out[idx] = s * (1.f / 144.f);
}

// ---------------- host ----------------

extern "C" void kernel_launch(void* const* d_in, const int* in_sizes, int n_in,
                              void* d_out, int out_size, void* d_ws, size_t ws_size,
                              hipStream_t stream) {
  (void)in_sizes; (void)n_in; (void)out_size; (void)ws_size;
  const float* x   = (const float*)d_in[0];
  const float* w1  = (const float*)d_in[1];
  const float* b1  = (const float*)d_in[2];
  const float* aw1 = (const float*)d_in[3];
  const float* W[6];  const float* BI[6]; const float* AW[6];
  for (int i = 0; i < 6; ++i) {
    W[i]  = (const float*)d_in[4 + 3 * i];
    BI[i] = (const float*)d_in[5 + 3 * i];
    AW[i] = (const float*)d_in[6 + 3 * i];
  }
  const float* G[6]; const float* BE[6];
  for (int i = 0; i < 6; ++i) {
    G[i]  = (const float*)d_in[22 + 2 * i];
    BE[i] = (const float*)d_in[23 + 2 * i];
  }
  float* out = (float*)d_out;

  // workspace (floats): ~56 MB
  float* ws = (float*)d_ws;
  float* A  = ws;                                            // raw conv out fp32, 8,667,136
  unsigned short* XN   = (unsigned short*)(ws + 8667136);    // normalized xn bf16
  unsigned short* AMAP = (unsigned short*)(ws + 13000704);   // 541,696 ush
  float* ATT = ws + 13271552;                                // 294,912
  unsigned short* WROT = (unsigned short*)(ws + 13566464);   // 811,008 ush
  float* PART  = ws + 13971968;                              // 6 layers x 8192 = 49,152

  auto cdiv = [](int a, int b) { return (a + b - 1) / b; };
  float* PL[6];
  for (int i = 0; i < 6; ++i) PL[i] = PART + i * 8192;

  // zero the BN stat buckets (re-poisoned to 0xAA before every timed launch)
  hipMemsetAsync(PART, 0, 6 * 8192 * sizeof(float), stream);

  // weight prep (all 6 GG layers, one launch)
  k_prep_w<<<dim3(cdiv(811008, 256)), dim3(256), 0, stream>>>(
      W[0], W[1], W[2], W[3], W[4], W[5], WROT);
  const unsigned short* WL[6];
  for (int i = 0; i < 5; ++i) WL[i] = WROT + i * 147456;
  WL[5] = WROT + 737280;

  // ---- layer 1: fused att + lifting conv + stats ----
  {
    k_conv_lift<<<dim3(32 * 46 * 6), dim3(256), 0, stream>>>(x, aw1, w1, b1, A, PL[0]);
    int npix = 32 * 2116;
    k_meanmax_bn<<<dim3(cdiv(npix, 256)), dim3(256), 0, stream>>>(A, PL[0], G[0], BE[0], XN, AMAP, npix);
    k_att_gg<<<dim3(cdiv(npix * 4, 256)), dim3(256), 0, stream>>>(AMAP, AW[0], ATT, 46);
  }
  // ---- layer 2 (H=46 -> 44) + pool ----  NRT=6, NCT=3
  {
    k_conv_mfma<46, 2, 32, 128, true><<<dim3(128 * 6 * 3), dim3(256), 0, stream>>>(XN, ATT, WL[0], BI[0], A, PL[1]);
    int npix = 32 * 1936;
    int np22 = 32 * 484;
    k_meanmax_bn_pool<<<dim3(cdiv(np22, 256)), dim3(256), 0, stream>>>(A, PL[1], G[1], BE[1], XN, AMAP, npix);
    k_att_gg<<<dim3(cdiv(np22 * 4, 256)), dim3(256), 0, stream>>>(AMAP, AW[1], ATT, 22);
  }
  // ---- layer 3 (22 -> 20) ----  NRT=3, NCT=2
  {
    k_conv_mfma<22, 2, 32, 128, true><<<dim3(128 * 3 * 2), dim3(256), 0, stream>>>(XN, ATT, WL[1], BI[1], A, PL[2]);
    int npix = 32 * 400;
    k_meanmax_bn<<<dim3(cdiv(npix, 256)), dim3(256), 0, stream>>>(A, PL[2], G[2], BE[2], XN, AMAP, npix);
    k_att_gg<<<dim3(cdiv(npix * 4, 256)), dim3(256), 0, stream>>>(AMAP, AW[2], ATT, 20);
  }
  // ---- layer 4 (20 -> 18) ----  NRT=3, NCT=2
  {
    k_conv_mfma<20, 2, 32, 128, true><<<dim3(128 * 3 * 2), dim3(256), 0, stream>>>(XN, ATT, WL[2], BI[2], A, PL[3]);
    int npix = 32 * 324;
    k_meanmax_bn<<<dim3(cdiv(npix, 256)), dim3(256), 0, stream>>>(A, PL[3], G[3], BE[3], XN, AMAP, npix);
    k_att_gg<<<dim3(cdiv(npix * 4, 256)), dim3(256), 0, stream>>>(AMAP, AW[3], ATT, 18);
  }
  // ---- layer 5 (18 -> 16) ----  NRT=2, NCT=1
  {
    k_conv_mfma<18, 2, 32, 128, true><<<dim3(128 * 2 * 1), dim3(256), 0, stream>>>(XN, ATT, WL[3], BI[3], A, PL[4]);
    int npix = 32 * 256;
    k_meanmax_bn<<<dim3(cdiv(npix, 256)), dim3(256), 0, stream>>>(A, PL[4], G[4], BE[4], XN, AMAP, npix);
    k_att_gg<<<dim3(cdiv(npix * 4, 256)), dim3(256), 0, stream>>>(AMAP, AW[4], ATT, 16);
  }
  // ---- layer 6 (16 -> 14) ----  NRT=2, NCT=1
  {
    k_conv_mfma<16, 2, 32, 128, true><<<dim3(128 * 2 * 1), dim3(256), 0, stream>>>(XN, ATT, WL[4], BI[4], A, PL[5]);
    int npix = 32 * 196;
    k_meanmax_bn<<<dim3(cdiv(npix, 256)), dim3(256), 0, stream>>>(A, PL[5], G[5], BE[5], XN, AMAP, npix);
    k_att_gg<<<dim3(cdiv(npix * 4, 256)), dim3(256), 0, stream>>>(AMAP, AW[5], ATT, 14);
  }
  // ---- layer 7 (14 -> 12, O=10, no BN) ----  NRT=2, NCT=1
  k_conv_mfma<14, 1, 10, 40, false><<<dim3(128 * 2 * 1), dim3(256), 0, stream>>>(XN, ATT, WL[5], BI[5], A, nullptr);
  // ---- rotation max + spatial mean ----
  k_final<<<dim3(5), dim3(64), 0, stream>>>(A, out);
}

// Round 11
// 547.044 us; speedup vs baseline: 6.8289x; 1.0202x over previous
//
#include <hip/hip_runtime.h>
#include <cstddef>

#define DINL static __device__ __forceinline__

// collision-proof custom vector types (HIP headers own names like short8/float4)
typedef __attribute__((ext_vector_type(4))) float f4v;
typedef __attribute__((ext_vector_type(8))) short bh8;  // 8 bf16 bit patterns (4 VGPRs)

// rot90 applied r times (counter-clockwise, numpy convention): rotated_r[i][j] = w[si][sj]
DINL void rot_src(int r, int K, int i, int j, int& si, int& sj) {
  switch (r & 3) {
    case 0:  si = i;       sj = j;       break;
    case 1:  si = j;       sj = K-1-i;   break;
    case 2:  si = K-1-i;   sj = K-1-j;   break;
    default: si = K-1-j;   sj = i;       break;
  }
}

DINL float sigmoidf(float s) { return 1.f / (1.f + __expf(-s)); }

// float -> bf16 bits, round-to-nearest-even
DINL unsigned short f2bf(float f) {
  unsigned u = __builtin_bit_cast(unsigned, f);
  u += 0x7fffu + ((u >> 16) & 1u);
  return (unsigned short)(u >> 16);
}
DINL float bf2f(unsigned short h) {
  unsigned u = ((unsigned)h) << 16;
  return __builtin_bit_cast(float, u);
}

// ---------------- weight prep ----------------
// Activation channel layout: c' = g*32 + ci  (g = producing rotation, ci = channel).
// A-fragment coalesced layout: bh8 wrot[r][tap][ks][mi][lane(=16q+n)][j8]
//   lane(n,q) holds A[m = mi*16+n][k = q*8+j]; cg = ks*32 + q*8 + j => g=ks, ci=q*8+j.
// Sizes: L2..L6 at L*147456 ushorts (OM=2), L7 at 737280 (OM=1, O=10).
__global__ void k_prep_w(const float* __restrict__ w2, const float* __restrict__ w3,
                         const float* __restrict__ w4, const float* __restrict__ w5,
                         const float* __restrict__ w6, const float* __restrict__ w7,
                         unsigned short* __restrict__ wrot) {
  int idx = blockIdx.x * 256 + threadIdx.x;
  if (idx >= 811008) return;
  const float* w; int OM, O, base;
  if (idx < 737280) {
    int L = idx / 147456; base = L * 147456; OM = 2; O = 32;
    w = (L == 0) ? w2 : (L == 1) ? w3 : (L == 2) ? w4 : (L == 3) ? w5 : w6;
  } else { base = 737280; OM = 1; O = 10; w = w7; }
  int local = idx - base;
  int j = local & 7; int t = local >> 3;
  int lanei = t & 63; t >>= 6;
  int mi = t % OM; t /= OM;
  int ks = t & 3; t >>= 2;
  int tap = t % 9; int r = t / 9;
  int n = lanei & 15, q = lanei >> 4;
  int o = mi * 16 + n;
  int ci = q * 8 + j;
  int gs = (ks - r) & 3;
  int ky = tap / 3, kx = tap % 3;
  int si, sj; rot_src(r, 3, ky, kx, si, sj);
  float val = (o < O) ? w[((o * 32 + ci) * 4 + gs) * 9 + si * 3 + sj] : 0.f;
  wrot[idx] = f2bf(val);
}

// ---------------- layer 1 attention (standalone, parallel) ----------------
// att[b][r][48x48]; wsum[r] = rot_r(aw_mean + aw_max) staged in LDS.
__global__ void __launch_bounds__(256)
k_att_lift(const float* __restrict__ x, const float* __restrict__ aw,
           float* __restrict__ att) {
  const int H = 48, HW = H * H;
  __shared__ float wsum[4][49];
  for (int i = threadIdx.x; i < 196; i += 256) {
    int r = i / 49; int t = i % 49;
    int ky = t / 7, kx = t % 7;
    int si, sj; rot_src(r, 7, ky, kx, si, sj);
    wsum[r][t] = aw[si * 7 + sj] + aw[49 + si * 7 + sj];
  }
  __syncthreads();
  int idx = blockIdx.x * 256 + threadIdx.x;
  if (idx >= 32 * 4 * HW) return;
  int xw = idx % H; int t = idx / H;
  int yh = t % H;  t /= H;
  int r  = t & 3;  int b = t >> 2;
  const float* xb = x + b * HW;
  float s = 0.f;
  for (int ky = 0; ky < 7; ++ky) {
    int y = yh + ky - 3;
    if ((unsigned)y >= (unsigned)H) continue;
    for (int kx = 0; kx < 7; ++kx) {
      int xx = xw + kx - 3;
      if ((unsigned)xx >= (unsigned)H) continue;
      s += xb[y * H + xx] * wsum[r][ky * 7 + kx];
    }
  }
  att[idx] = sigmoidf(s);
}

// ---------------- layer 1: LDS-tiled lifting conv + BN partial stats ----------------
// block = (b, output row yo, 8-col group cg); 256 thr = 8 cols x 32 o.
// All rot indices compile-time (r unrolled). out: y[(b*2116+p)*128 + r*32 + o]
__global__ void __launch_bounds__(256)
k_conv_lift(const float* __restrict__ x, const float* __restrict__ att,
            const float* __restrict__ w, const float* __restrict__ bias,
            float* __restrict__ y, float* __restrict__ partl) {
  const int HO = 46;
  __shared__ float xs[3 * 48];
  __shared__ float as[4][3 * 48];
  __shared__ float wsm[288];
  __shared__ float bs[32];
  __shared__ float bnred[64];
  int id = blockIdx.x;
  int cg = id % 6; int t = id / 6;
  int yo = t % HO; int b = t / HO;

  for (int i = threadIdx.x; i < 144; i += 256)
    xs[i] = x[b * 2304 + (yo + i / 48) * 48 + (i % 48)];
  for (int i = threadIdx.x; i < 576; i += 256) {
    int r = i / 144; int rem = i % 144;
    as[r][rem] = att[(b * 4 + r) * 2304 + (yo + rem / 48) * 48 + (rem % 48)];
  }
  for (int i = threadIdx.x; i < 288; i += 256) wsm[i] = w[i];
  if (threadIdx.x < 32) bs[threadIdx.x] = bias[threadIdx.x];
  if (threadIdx.x < 64) bnred[threadIdx.x] = 0.f;
  __syncthreads();

  int o = threadIdx.x & 31;
  int cl = threadIdx.x >> 5;
  int col = cl + cg * 8;
  float sacc = 0.f, qacc = 0.f;
  if (col < HO) {
    float wreg[9];
    #pragma unroll
    for (int i = 0; i < 9; ++i) wreg[i] = wsm[o * 9 + i];
    float xv[9];
    #pragma unroll
    for (int ky = 0; ky < 3; ++ky)
      #pragma unroll
      for (int kx = 0; kx < 3; ++kx)
        xv[ky * 3 + kx] = xs[ky * 48 + col + kx];
    float bv = bs[o];
    float* yp = y + ((size_t)b * 2116 + yo * HO + col) * 128 + o;
    #pragma unroll
    for (int r = 0; r < 4; ++r) {
      float acc = bv;
      #pragma unroll
      for (int ky = 0; ky < 3; ++ky)
        #pragma unroll
        for (int kx = 0; kx < 3; ++kx) {
          int si, sj; rot_src(r, 3, ky, kx, si, sj);  // folds: r,ky,kx constant
          acc = fmaf(as[r][ky * 48 + col + kx] * xv[ky * 3 + kx], wreg[si * 3 + sj], acc);
        }
      yp[r * 32] = acc;
      sacc += acc; qacc += acc * acc;
    }
  }
  atomicAdd(&bnred[o], sacc);
  atomicAdd(&bnred[32 + o], qacc);
  __syncthreads();
  if (threadIdx.x < 64) {
    int bucket = blockIdx.x & 63;
    int c = threadIdx.x & 31;
    int off = (threadIdx.x < 32) ? c : (64 + c);
    atomicAdd(&partl[bucket * 128 + off], bnred[threadIdx.x]);
  }
}

// ---------------- MFMA attentive GG conv (split-K staging + fused BN stats) ----------------
// xn [b][p][128] bf16 (c' = g*32+ci), att [b][4][hw] fp32, weights coalesced (see prep).
// 256 threads = 4 waves; tile 8 rows x 16 cols per (b,r); wave wv does rows 2wv,2wv+1.
// Split-K: stage 64 channels (half) at a time -> LDS 25 KB -> 6 blocks/CU.
// A-loads wave-coalesced from global; B from LDS window (2-way bank alias = free).
// Out y [b][p'][OSTR] fp32 (c' = r*O+o). BNS: per-o sum/sumsq via shfl + bucketed atomics.
template<int H, int OM, int O, int OSTR, bool BNS>
__global__ void __launch_bounds__(256)
k_conv_mfma(const unsigned short* __restrict__ xn, const float* __restrict__ att,
            const unsigned short* __restrict__ wl, const float* __restrict__ bias,
            float* __restrict__ y, float* __restrict__ partl) {
  constexpr int HO = H - 2, HW = H * H;
  constexpr int TR = 8, TC = 16, WR = TR + 2, WC = TC + 2, CGH = 68;
  constexpr int NRT = (HO + TR - 1) / TR, NCT = (HO + TC - 1) / TC;
  __shared__ __align__(16) unsigned short xa[WR * WC * CGH];  // 24,480 B
  __shared__ float bnred[128];

  // XCD swizzle: blockIdx.x % 8 <-> b % 8
  int id = blockIdx.x;
  int slot = id & 7; int k = id >> 3;
  int tile = k % (NRT * NCT); k /= (NRT * NCT);
  int r = k & 3; int bhi = k >> 2;
  int b = bhi * 8 + slot;
  int rt = tile / NCT, ct = tile % NCT;
  int row0 = rt * TR, c0 = ct * TC;

  const unsigned short* xb = xn + (size_t)b * HW * 128;
  const float* ab = att + (size_t)(b * 4 + r) * HW;

  int lane = threadIdx.x & 63;
  int wv = threadIdx.x >> 6;
  int n = lane & 15, quad = lane >> 4;

  f4v acc[OM][2];
  #pragma unroll
  for (int mi = 0; mi < OM; ++mi)
    #pragma unroll
    for (int ri = 0; ri < 2; ++ri) {
      acc[mi][ri][0] = 0.f; acc[mi][ri][1] = 0.f;
      acc[mi][ri][2] = 0.f; acc[mi][ri][3] = 0.f;
    }

  const bh8* wa = (const bh8*)wl + (size_t)r * 9 * 4 * OM * 64 + lane;

  for (int half = 0; half < 2; ++half) {
    if (half) __syncthreads();  // all reads of previous half done
    // stage 64 channels: xa[pix][ch(8 chunks of 8 ushorts)]
    for (int u = threadIdx.x; u < WR * WC * 8; u += 256) {
      int ch = u & 7; int pix = u >> 3;
      int wr = pix / WC, wc = pix % WC;
      int row = row0 + wr; if (row > H - 1) row = H - 1;
      int col = c0 + wc;  if (col > H - 1) col = H - 1;
      int p = row * H + col;
      const unsigned short* xp = xb + (size_t)p * 128 + half * 64 + ch * 8;
      float av = ab[p];
      bh8 xv = *(const bh8*)xp;
      bh8 v;
      #pragma unroll
      for (int j2 = 0; j2 < 8; ++j2)
        v[j2] = (short)f2bf(bf2f((unsigned short)xv[j2]) * av);
      *(bh8*)&xa[pix * CGH + ch * 8] = v;
    }
    __syncthreads();

    #pragma unroll
    for (int tap = 0; tap < 9; ++tap) {
      int ky = tap / 3, kx = tap % 3;
      int pb0 = ((2 * wv + ky) * WC + n + kx) * CGH;
      int pb1 = pb0 + WC * CGH;
      #pragma unroll
      for (int kl = 0; kl < 2; ++kl) {
        int ks = half * 2 + kl;
        bh8 b0 = *(const bh8*)&xa[pb0 + kl * 32 + quad * 8];
        bh8 b1 = *(const bh8*)&xa[pb1 + kl * 32 + quad * 8];
        bh8 a0 = wa[(size_t)((tap * 4 + ks) * OM + 0) * 64];
        acc[0][0] = __builtin_amdgcn_mfma_f32_16x16x32_bf16(a0, b0, acc[0][0], 0, 0, 0);
        acc[0][1] = __builtin_amdgcn_mfma_f32_16x16x32_bf16(a0, b1, acc[0][1], 0, 0, 0);
        if constexpr (OM == 2) {
          bh8 a1 = wa[(size_t)((tap * 4 + ks) * OM + 1) * 64];
          acc[1][0] = __builtin_amdgcn_mfma_f32_16x16x32_bf16(a1, b0, acc[1][0], 0, 0, 0);
          acc[1][1] = __builtin_amdgcn_mfma_f32_16x16x32_bf16(a1, b1, acc[1][1], 0, 0, 0);
        }
      }
    }
  }

  // epilogue: C/D col=lane&15 (spatial), row=quad*4+reg (o); c' = r*O + o
  float sv[OM * 4], qv[OM * 4];
  #pragma unroll
  for (int e = 0; e < OM * 4; ++e) { sv[e] = 0.f; qv[e] = 0.f; }
  #pragma unroll
  for (int mi = 0; mi < OM; ++mi)
    #pragma unroll
    for (int ri = 0; ri < 2; ++ri) {
      int prow = row0 + 2 * wv + ri;
      int col = c0 + n;
      if (prow < HO && col < HO) {
        float* yp = y + ((size_t)b * HO * HO + prow * HO + col) * OSTR;
        int o0 = mi * 16 + quad * 4;
        f4v v = acc[mi][ri];
        if constexpr (O == 32) {
          f4v w4;
          #pragma unroll
          for (int reg = 0; reg < 4; ++reg) {
            float val = v[reg] + bias[o0 + reg];
            w4[reg] = val;
            if constexpr (BNS) { sv[mi * 4 + reg] += val; qv[mi * 4 + reg] += val * val; }
          }
          *(f4v*)(yp + r * 32 + o0) = w4;
        } else {
          #pragma unroll
          for (int reg = 0; reg < 4; ++reg) {
            int o = o0 + reg;
            if (o < O) yp[r * O + o] = v[reg] + bias[o];
          }
        }
      }
    }

  if constexpr (BNS) {
    #pragma unroll
    for (int e = 0; e < OM * 4; ++e) {
      #pragma unroll
      for (int off = 1; off < 16; off <<= 1) {
        sv[e] += __shfl_xor(sv[e], off);
        qv[e] += __shfl_xor(qv[e], off);
      }
    }
    if (threadIdx.x < 128) bnred[threadIdx.x] = 0.f;
    __syncthreads();
    if (n == 0) {
      #pragma unroll
      for (int e = 0; e < OM * 4; ++e) {
        int o = (e >> 2) * 16 + quad * 4 + (e & 3);
        atomicAdd(&bnred[o], sv[e]);
        atomicAdd(&bnred[64 + o], qv[e]);
      }
    }
    __syncthreads();
    if (threadIdx.x < 128)
      atomicAdd(&partl[(blockIdx.x & 63) * 128 + threadIdx.x], bnred[threadIdx.x]);
  }
}

// ---------------- BN finalize from bucketed partials (in-block) ----------------
DINL void bn_finalize2(const float* __restrict__ partl,
                       const float* __restrict__ gamma, const float* __restrict__ beta,
                       float* st, int npix, int tid) {
  if (tid < 32) {
    float s1 = 0.f, s2 = 0.f;
    for (int bk = 0; bk < 64; ++bk) {
      s1 += partl[bk * 128 + tid];
      s2 += partl[bk * 128 + 64 + tid];
    }
    float N = 4.f * (float)npix;
    float m = s1 / N;
    float v = s2 / N - m * m;
    float inv = rsqrtf(v + 2e-5f);
    float sc = gamma[tid] * inv;
    st[tid] = sc;
    st[32 + tid] = beta[tid] - m * sc;
  }
  __syncthreads();
}

// ---------------- fused BN-finalize+BN+ReLU+channel mean/max (bf16 out) ----------------
// c' = g*32 + o: chunk cc (4 floats) has g = cc>>3, o base = (cc&7)*4.
__global__ void k_meanmax_bn(const float* __restrict__ yr, const float* __restrict__ partl,
                             const float* __restrict__ gamma, const float* __restrict__ beta,
                             unsigned short* __restrict__ xn, unsigned short* __restrict__ amap,
                             int npix) {
  __shared__ float st[64];
  bn_finalize2(partl, gamma, beta, st, npix, threadIdx.x);
  int idx = blockIdx.x * 256 + threadIdx.x;
  if (idx >= npix) return;
  const float* yp = yr + (size_t)idx * 128;
  unsigned short* xp = xn + (size_t)idx * 128;
  float sm[4] = {0.f, 0.f, 0.f, 0.f};
  float mx[4] = {-1e30f, -1e30f, -1e30f, -1e30f};
  #pragma unroll 4
  for (int oo = 0; oo < 16; ++oo) {  // bh8 chunks; chunk cc pair (2oo, 2oo+1), g = oo>>2
    f4v va = *(const f4v*)(yp + oo * 8);
    f4v vb = *(const f4v*)(yp + oo * 8 + 4);
    int g = oo >> 2;
    int ob0 = ((2 * oo) & 7) * 4, ob1 = ((2 * oo + 1) & 7) * 4;
    bh8 w;
    #pragma unroll
    for (int e = 0; e < 4; ++e) {
      float v0 = fmaxf(fmaf(va[e], st[ob0 + e], st[32 + ob0 + e]), 0.f);
      float v1 = fmaxf(fmaf(vb[e], st[ob1 + e], st[32 + ob1 + e]), 0.f);
      w[e] = (short)f2bf(v0); w[4 + e] = (short)f2bf(v1);
      sm[g] += v0 + v1;
      mx[g] = fmaxf(mx[g], fmaxf(v0, v1));
    }
    *(bh8*)(xp + oo * 8) = w;
  }
  bh8 am;
  #pragma unroll
  for (int g = 0; g < 4; ++g) {
    am[g] = (short)f2bf(sm[g] * (1.f / 32.f));
    am[4 + g] = (short)f2bf(mx[g]);
  }
  *(bh8*)(amap + (size_t)idx * 8) = am;
}

// layer-2 variant: BN+ReLU at 44x44 then 2x2 maxpool -> 22x22
__global__ void k_meanmax_bn_pool(const float* __restrict__ yr, const float* __restrict__ partl,
                                  const float* __restrict__ gamma, const float* __restrict__ beta,
                                  unsigned short* __restrict__ xn, unsigned short* __restrict__ amap,
                                  int npix) {
  const int HI = 44, HOq = 22, HWO = HOq * HOq;
  __shared__ float st[64];
  bn_finalize2(partl, gamma, beta, st, npix, threadIdx.x);
  int idx = blockIdx.x * 256 + threadIdx.x;
  if (idx >= 32 * HWO) return;
  int p22 = idx % HWO; int b = idx / HWO;
  int y0 = (p22 / HOq) * 2, x0 = (p22 % HOq) * 2;
  const float* p00 = yr + ((size_t)b * HI * HI + y0 * HI + x0) * 128;
  unsigned short* xp = xn + (size_t)idx * 128;
  float sm[4] = {0.f, 0.f, 0.f, 0.f};
  float mx[4] = {-1e30f, -1e30f, -1e30f, -1e30f};
  #pragma unroll 2
  for (int oo = 0; oo < 16; ++oo) {
    int g = oo >> 2;
    bh8 w;
    #pragma unroll
    for (int half = 0; half < 2; ++half) {
      int cc = 2 * oo + half;
      int ob = (cc & 7) * 4;
      f4v v0 = *(const f4v*)(p00 + cc * 4);
      f4v v1 = *(const f4v*)(p00 + 128 + cc * 4);
      f4v v2 = *(const f4v*)(p00 + (size_t)HI * 128 + cc * 4);
      f4v v3 = *(const f4v*)(p00 + (size_t)(HI + 1) * 128 + cc * 4);
      #pragma unroll
      for (int e = 0; e < 4; ++e) {
        float sc = st[ob + e], sh = st[32 + ob + e];
        float a0 = fmaxf(fmaf(v0[e], sc, sh), 0.f);
        float a1 = fmaxf(fmaf(v1[e], sc, sh), 0.f);
        float a2 = fmaxf(fmaf(v2[e], sc, sh), 0.f);
        float a3 = fmaxf(fmaf(v3[e], sc, sh), 0.f);
        float val = fmaxf(fmaxf(a0, a1), fmaxf(a2, a3));
        w[half * 4 + e] = (short)f2bf(val);
        sm[g] += val; mx[g] = fmaxf(mx[g], val);
      }
    }
    *(bh8*)(xp + oo * 8) = w;
  }
  bh8 am;
  #pragma unroll
  for (int g = 0; g < 4; ++g) {
    am[g] = (short)f2bf(sm[g] * (1.f / 32.f));
    am[4 + g] = (short)f2bf(mx[g]);
  }
  *(bh8*)(amap + (size_t)idx * 8) = am;
}

// ---------------- attention GG conv (bf16 channels-last amap) ----------------

__global__ void k_att_gg(const unsigned short* __restrict__ amap,
                         const float* __restrict__ aw,
                         float* __restrict__ att, int h) {
  int hw = h * h;
  int idx = blockIdx.x * blockDim.x + threadIdx.x;
  if (idx >= 32 * 4 * hw) return;
  int p = idx % hw; int t = idx / hw;
  int r = t & 3; int b = t >> 2;
  int yh = p / h, xw = p % h;
  float s = 0.f;
  for (int ky = 0; ky < 7; ++ky) {
    int y = yh + ky - 3;
    if ((unsigned)y >= (unsigned)h) continue;
    for (int kx = 0; kx < 7; ++kx) {
      int xx = xw + kx - 3;
      if ((unsigned)xx >= (unsigned)h) continue;
      int si, sj; rot_src(r, 7, ky, kx, si, sj);
      bh8 av = *(const bh8*)(amap + ((size_t)b * hw + y * h + xx) * 8);
      const float* awp = aw + si * 7 + sj;
      #pragma unroll
      for (int g = 0; g < 4; ++g) {
        int gs = (g - r) & 3;
        s += bf2f((unsigned short)av[g]) * awp[gs * 49]
           + bf2f((unsigned short)av[4 + g]) * awp[(4 + gs) * 49];
      }
    }
  }
  att[idx] = sigmoidf(s);
}

// ---------------- final: rotation max + spatial mean ----------------
// y7 [b][p(144)][40] with c' = r*10+o; out[b*10+o]
__global__ void k_final(const float* __restrict__ y7, float* __restrict__ out) {
  int idx = blockIdx.x * blockDim.x + threadIdx.x;
  if (idx >= 320) return;
  int o = idx % 10; int b = idx / 10;
  const float* p = y7 + (size_t)b * 144 * 40;
  float s = 0.f;
  for (int sp = 0; sp < 144; ++sp) {
    const float* q = p + sp * 40 + o;
    float m = fmaxf(fmaxf(q[0], q[10]), fmaxf(q[20], q[30]));
    s += m;
  }
  out[idx] = s * (1.f / 144.f);
}

// ---------------- host ----------------

extern "C" void kernel_launch(void* const* d_in, const int* in_sizes, int n_in,
                              void* d_out, int out_size, void* d_ws, size_t ws_size,
                              hipStream_t stream) {
  (void)in_sizes; (void)n_in; (void)out_size; (void)ws_size;
  const float* x   = (const float*)d_in[0];
  const float* w1  = (const float*)d_in[1];
  const float* b1  = (const float*)d_in[2];
  const float* aw1 = (const float*)d_in[3];
  const float* W[6];  const float* BI[6]; const float* AW[6];
  for (int i = 0; i < 6; ++i) {
    W[i]  = (const float*)d_in[4 + 3 * i];
    BI[i] = (const float*)d_in[5 + 3 * i];
    AW[i] = (const float*)d_in[6 + 3 * i];
  }
  const float* G[6]; const float* BE[6];
  for (int i = 0; i < 6; ++i) {
    G[i]  = (const float*)d_in[22 + 2 * i];
    BE[i] = (const float*)d_in[23 + 2 * i];
  }
  float* out = (float*)d_out;

  // workspace (floats): ~56 MB
  float* ws = (float*)d_ws;
  float* A  = ws;                                            // raw conv out fp32, 8,667,136
  unsigned short* XN   = (unsigned short*)(ws + 8667136);    // normalized xn bf16
  unsigned short* AMAP = (unsigned short*)(ws + 13000704);   // 541,696 ush
  float* ATT = ws + 13271552;                                // 294,912
  unsigned short* WROT = (unsigned short*)(ws + 13566464);   // 811,008 ush
  float* PART  = ws + 13971968;                              // 6 layers x 8192 = 49,152

  auto cdiv = [](int a, int b) { return (a + b - 1) / b; };
  float* PL[6];
  for (int i = 0; i < 6; ++i) PL[i] = PART + i * 8192;

  // zero the BN stat buckets (re-poisoned to 0xAA before every timed launch)
  hipMemsetAsync(PART, 0, 6 * 8192 * sizeof(float), stream);

  // weight prep (all 6 GG layers, one launch)
  k_prep_w<<<dim3(cdiv(811008, 256)), dim3(256), 0, stream>>>(
      W[0], W[1], W[2], W[3], W[4], W[5], WROT);
  const unsigned short* WL[6];
  for (int i = 0; i < 5; ++i) WL[i] = WROT + i * 147456;
  WL[5] = WROT + 737280;

  // ---- layer 1: attention + lifting conv (stats fused) ----
  {
    int natt = 32 * 4 * 48 * 48;
    k_att_lift<<<dim3(cdiv(natt, 256)), dim3(256), 0, stream>>>(x, aw1, ATT);
    k_conv_lift<<<dim3(32 * 46 * 6), dim3(256), 0, stream>>>(x, ATT, w1, b1, A, PL[0]);
    int npix = 32 * 2116;
    k_meanmax_bn<<<dim3(cdiv(npix, 256)), dim3(256), 0, stream>>>(A, PL[0], G[0], BE[0], XN, AMAP, npix);
    k_att_gg<<<dim3(cdiv(npix * 4, 256)), dim3(256), 0, stream>>>(AMAP, AW[0], ATT, 46);
  }
  // ---- layer 2 (H=46 -> 44) + pool ----  NRT=6, NCT=3
  {
    k_conv_mfma<46, 2, 32, 128, true><<<dim3(128 * 6 * 3), dim3(256), 0, stream>>>(XN, ATT, WL[0], BI[0], A, PL[1]);
    int npix = 32 * 1936;
    int np22 = 32 * 484;
    k_meanmax_bn_pool<<<dim3(cdiv(np22, 256)), dim3(256), 0, stream>>>(A, PL[1], G[1], BE[1], XN, AMAP, npix);
    k_att_gg<<<dim3(cdiv(np22 * 4, 256)), dim3(256), 0, stream>>>(AMAP, AW[1], ATT, 22);
  }
  // ---- layer 3 (22 -> 20) ----  NRT=3, NCT=2
  {
    k_conv_mfma<22, 2, 32, 128, true><<<dim3(128 * 3 * 2), dim3(256), 0, stream>>>(XN, ATT, WL[1], BI[1], A, PL[2]);
    int npix = 32 * 400;
    k_meanmax_bn<<<dim3(cdiv(npix, 256)), dim3(256), 0, stream>>>(A, PL[2], G[2], BE[2], XN, AMAP, npix);
    k_att_gg<<<dim3(cdiv(npix * 4, 256)), dim3(256), 0, stream>>>(AMAP, AW[2], ATT, 20);
  }
  // ---- layer 4 (20 -> 18) ----  NRT=3, NCT=2
  {
    k_conv_mfma<20, 2, 32, 128, true><<<dim3(128 * 3 * 2), dim3(256), 0, stream>>>(XN, ATT, WL[2], BI[2], A, PL[3]);
    int npix = 32 * 324;
    k_meanmax_bn<<<dim3(cdiv(npix, 256)), dim3(256), 0, stream>>>(A, PL[3], G[3], BE[3], XN, AMAP, npix);
    k_att_gg<<<dim3(cdiv(npix * 4, 256)), dim3(256), 0, stream>>>(AMAP, AW[3], ATT, 18);
  }
  // ---- layer 5 (18 -> 16) ----  NRT=2, NCT=1
  {
    k_conv_mfma<18, 2, 32, 128, true><<<dim3(128 * 2 * 1), dim3(256), 0, stream>>>(XN, ATT, WL[3], BI[3], A, PL[4]);
    int npix = 32 * 256;
    k_meanmax_bn<<<dim3(cdiv(npix, 256)), dim3(256), 0, stream>>>(A, PL[4], G[4], BE[4], XN, AMAP, npix);
    k_att_gg<<<dim3(cdiv(npix * 4, 256)), dim3(256), 0, stream>>>(AMAP, AW[4], ATT, 16);
  }
  // ---- layer 6 (16 -> 14) ----  NRT=2, NCT=1
  {
    k_conv_mfma<16, 2, 32, 128, true><<<dim3(128 * 2 * 1), dim3(256), 0, stream>>>(XN, ATT, WL[4], BI[4], A, PL[5]);
    int npix = 32 * 196;
    k_meanmax_bn<<<dim3(cdiv(npix, 256)), dim3(256), 0, stream>>>(A, PL[5], G[5], BE[5], XN, AMAP, npix);
    k_att_gg<<<dim3(cdiv(npix * 4, 256)), dim3(256), 0, stream>>>(AMAP, AW[5], ATT, 14);
  }
  // ---- layer 7 (14 -> 12, O=10, no BN) ----  NRT=2, NCT=1
  k_conv_mfma<14, 1, 10, 40, false><<<dim3(128 * 2 * 1), dim3(256), 0, stream>>>(XN, ATT, WL[5], BI[5], A, nullptr);
  // ---- rotation max + spatial mean ----
  k_final<<<dim3(5), dim3(64), 0, stream>>>(A, out);
}

// Round 12
// 498.065 us; speedup vs baseline: 7.5005x; 1.0983x over previous
//
#include <hip/hip_runtime.h>
#include <cstddef>

#define DINL static __device__ __forceinline__

// collision-proof custom vector types (HIP headers own names like short8/float4)
typedef __attribute__((ext_vector_type(4))) float f4v;
typedef __attribute__((ext_vector_type(8))) short bh8;   // 8 bf16 bit patterns (4 VGPRs)
typedef __attribute__((ext_vector_type(4))) unsigned short us4;  // 4 bf16 (8 B)

// rot90 applied r times (counter-clockwise, numpy convention): rotated_r[i][j] = w[si][sj]
DINL void rot_src(int r, int K, int i, int j, int& si, int& sj) {
  switch (r & 3) {
    case 0:  si = i;       sj = j;       break;
    case 1:  si = j;       sj = K-1-i;   break;
    case 2:  si = K-1-i;   sj = K-1-j;   break;
    default: si = K-1-j;   sj = i;       break;
  }
}

DINL float sigmoidf(float s) { return 1.f / (1.f + __expf(-s)); }

// float -> bf16 bits, round-to-nearest-even
DINL unsigned short f2bf(float f) {
  unsigned u = __builtin_bit_cast(unsigned, f);
  u += 0x7fffu + ((u >> 16) & 1u);
  return (unsigned short)(u >> 16);
}
DINL float bf2f(unsigned short h) {
  unsigned u = ((unsigned)h) << 16;
  return __builtin_bit_cast(float, u);
}

// ---------------- weight prep ----------------
// Activation channel layout: c' = g*32 + ci  (g = producing rotation, ci = channel).
// A-fragment coalesced layout: bh8 wrot[r][tap][ks][mi][lane(=16q+n)][j8]
//   lane(n,q) holds A[m = mi*16+n][k = q*8+j]; cg = ks*32 + q*8 + j => g=ks, ci=q*8+j.
// Sizes: L2..L6 at L*147456 ushorts (OM=2), L7 at 737280 (OM=1, O=10).
__global__ void k_prep_w(const float* __restrict__ w2, const float* __restrict__ w3,
                         const float* __restrict__ w4, const float* __restrict__ w5,
                         const float* __restrict__ w6, const float* __restrict__ w7,
                         unsigned short* __restrict__ wrot) {
  int idx = blockIdx.x * 256 + threadIdx.x;
  if (idx >= 811008) return;
  const float* w; int OM, O, base;
  if (idx < 737280) {
    int L = idx / 147456; base = L * 147456; OM = 2; O = 32;
    w = (L == 0) ? w2 : (L == 1) ? w3 : (L == 2) ? w4 : (L == 3) ? w5 : w6;
  } else { base = 737280; OM = 1; O = 10; w = w7; }
  int local = idx - base;
  int j = local & 7; int t = local >> 3;
  int lanei = t & 63; t >>= 6;
  int mi = t % OM; t /= OM;
  int ks = t & 3; t >>= 2;
  int tap = t % 9; int r = t / 9;
  int n = lanei & 15, q = lanei >> 4;
  int o = mi * 16 + n;
  int ci = q * 8 + j;
  int gs = (ks - r) & 3;
  int ky = tap / 3, kx = tap % 3;
  int si, sj; rot_src(r, 3, ky, kx, si, sj);
  float val = (o < O) ? w[((o * 32 + ci) * 4 + gs) * 9 + si * 3 + sj] : 0.f;
  wrot[idx] = f2bf(val);
}

// ---------------- layer 1 attention (standalone, parallel) ----------------
__global__ void __launch_bounds__(256)
k_att_lift(const float* __restrict__ x, const float* __restrict__ aw,
           float* __restrict__ att) {
  const int H = 48, HW = H * H;
  __shared__ float wsum[4][49];
  for (int i = threadIdx.x; i < 196; i += 256) {
    int r = i / 49; int t = i % 49;
    int ky = t / 7, kx = t % 7;
    int si, sj; rot_src(r, 7, ky, kx, si, sj);
    wsum[r][t] = aw[si * 7 + sj] + aw[49 + si * 7 + sj];
  }
  __syncthreads();
  int idx = blockIdx.x * 256 + threadIdx.x;
  if (idx >= 32 * 4 * HW) return;
  int xw = idx % H; int t = idx / H;
  int yh = t % H;  t /= H;
  int r  = t & 3;  int b = t >> 2;
  const float* xb = x + b * HW;
  float s = 0.f;
  for (int ky = 0; ky < 7; ++ky) {
    int y = yh + ky - 3;
    if ((unsigned)y >= (unsigned)H) continue;
    for (int kx = 0; kx < 7; ++kx) {
      int xx = xw + kx - 3;
      if ((unsigned)xx >= (unsigned)H) continue;
      s += xb[y * H + xx] * wsum[r][ky * 7 + kx];
    }
  }
  att[idx] = sigmoidf(s);
}

// ---------------- layer 1: LDS-tiled lifting conv + BN partial stats ----------------
// block = (b, output row yo); 256 thr = 8-col strider x 32 o; 6 col-groups reuse the
// staged row strip. Raw output bf16: y[(b*2116+p)*128 + r*32 + o]. Stats fp32-exact.
__global__ void __launch_bounds__(256)
k_conv_lift(const float* __restrict__ x, const float* __restrict__ att,
            const float* __restrict__ w, const float* __restrict__ bias,
            unsigned short* __restrict__ y, float* __restrict__ partl) {
  const int HO = 46;
  __shared__ float xs[3 * 48];
  __shared__ float as[4][3 * 48];
  __shared__ float wsm[288];
  __shared__ float bs[32];
  __shared__ float bnred[64];
  int id = blockIdx.x;
  int yo = id % HO; int b = id / HO;

  for (int i = threadIdx.x; i < 144; i += 256)
    xs[i] = x[b * 2304 + (yo + i / 48) * 48 + (i % 48)];
  for (int i = threadIdx.x; i < 576; i += 256) {
    int r = i / 144; int rem = i % 144;
    as[r][rem] = att[(b * 4 + r) * 2304 + (yo + rem / 48) * 48 + (rem % 48)];
  }
  for (int i = threadIdx.x; i < 288; i += 256) wsm[i] = w[i];
  if (threadIdx.x < 32) bs[threadIdx.x] = bias[threadIdx.x];
  if (threadIdx.x < 64) bnred[threadIdx.x] = 0.f;
  __syncthreads();

  int o = threadIdx.x & 31;
  int cl = threadIdx.x >> 5;
  float wreg[9];
  #pragma unroll
  for (int i = 0; i < 9; ++i) wreg[i] = wsm[o * 9 + i];
  float bv = bs[o];
  float sacc = 0.f, qacc = 0.f;

  for (int c8 = 0; c8 < 6; ++c8) {
    int col = c8 * 8 + cl;
    if (col < HO) {
      float xv[9];
      #pragma unroll
      for (int ky = 0; ky < 3; ++ky)
        #pragma unroll
        for (int kx = 0; kx < 3; ++kx)
          xv[ky * 3 + kx] = xs[ky * 48 + col + kx];
      unsigned short* yp = y + ((size_t)b * 2116 + yo * HO + col) * 128 + o;
      #pragma unroll
      for (int r = 0; r < 4; ++r) {
        float acc = bv;
        #pragma unroll
        for (int ky = 0; ky < 3; ++ky)
          #pragma unroll
          for (int kx = 0; kx < 3; ++kx) {
            int si, sj; rot_src(r, 3, ky, kx, si, sj);  // folds: r,ky,kx constant
            acc = fmaf(as[r][ky * 48 + col + kx] * xv[ky * 3 + kx], wreg[si * 3 + sj], acc);
          }
        yp[r * 32] = f2bf(acc);
        sacc += acc; qacc += acc * acc;
      }
    }
  }
  atomicAdd(&bnred[o], sacc);
  atomicAdd(&bnred[32 + o], qacc);
  __syncthreads();
  if (threadIdx.x < 64) {
    int bucket = blockIdx.x & 63;
    int c = threadIdx.x & 31;
    int off = (threadIdx.x < 32) ? c : (64 + c);
    atomicAdd(&partl[bucket * 128 + off], bnred[threadIdx.x]);
  }
}

// ---------------- MFMA attentive GG conv (split-K staging + fused BN stats) ----------------
// xn [b][p][128] bf16 (c' = g*32+ci), att [b][4][hw] fp32, weights coalesced (see prep).
// Raw out y bf16 [b][p'][OSTR] (c' = r*O+o). Stats fp32-exact via shfl + bucketed atomics.
template<int H, int OM, int O, int OSTR, bool BNS>
__global__ void __launch_bounds__(256)
k_conv_mfma(const unsigned short* __restrict__ xn, const float* __restrict__ att,
            const unsigned short* __restrict__ wl, const float* __restrict__ bias,
            unsigned short* __restrict__ y, float* __restrict__ partl) {
  constexpr int HO = H - 2, HW = H * H;
  constexpr int TR = 8, TC = 16, WR = TR + 2, WC = TC + 2, CGH = 68;
  constexpr int NRT = (HO + TR - 1) / TR, NCT = (HO + TC - 1) / TC;
  __shared__ __align__(16) unsigned short xa[WR * WC * CGH];  // 24,480 B
  __shared__ float bnred[128];

  // XCD swizzle: blockIdx.x % 8 <-> b % 8
  int id = blockIdx.x;
  int slot = id & 7; int k = id >> 3;
  int tile = k % (NRT * NCT); k /= (NRT * NCT);
  int r = k & 3; int bhi = k >> 2;
  int b = bhi * 8 + slot;
  int rt = tile / NCT, ct = tile % NCT;
  int row0 = rt * TR, c0 = ct * TC;

  const unsigned short* xb = xn + (size_t)b * HW * 128;
  const float* ab = att + (size_t)(b * 4 + r) * HW;

  int lane = threadIdx.x & 63;
  int wv = threadIdx.x >> 6;
  int n = lane & 15, quad = lane >> 4;

  f4v acc[OM][2];
  #pragma unroll
  for (int mi = 0; mi < OM; ++mi)
    #pragma unroll
    for (int ri = 0; ri < 2; ++ri) {
      acc[mi][ri][0] = 0.f; acc[mi][ri][1] = 0.f;
      acc[mi][ri][2] = 0.f; acc[mi][ri][3] = 0.f;
    }

  const bh8* wa = (const bh8*)wl + (size_t)r * 9 * 4 * OM * 64 + lane;

  for (int half = 0; half < 2; ++half) {
    if (half) __syncthreads();  // all reads of previous half done
    // stage 64 channels: xa[pix][ch(8 chunks of 8 ushorts)]
    for (int u = threadIdx.x; u < WR * WC * 8; u += 256) {
      int ch = u & 7; int pix = u >> 3;
      int wr = pix / WC, wc = pix % WC;
      int row = row0 + wr; if (row > H - 1) row = H - 1;
      int col = c0 + wc;  if (col > H - 1) col = H - 1;
      int p = row * H + col;
      const unsigned short* xp = xb + (size_t)p * 128 + half * 64 + ch * 8;
      float av = ab[p];
      bh8 xv = *(const bh8*)xp;
      bh8 v;
      #pragma unroll
      for (int j2 = 0; j2 < 8; ++j2)
        v[j2] = (short)f2bf(bf2f((unsigned short)xv[j2]) * av);
      *(bh8*)&xa[pix * CGH + ch * 8] = v;
    }
    __syncthreads();

    #pragma unroll
    for (int tap = 0; tap < 9; ++tap) {
      int ky = tap / 3, kx = tap % 3;
      int pb0 = ((2 * wv + ky) * WC + n + kx) * CGH;
      int pb1 = pb0 + WC * CGH;
      #pragma unroll
      for (int kl = 0; kl < 2; ++kl) {
        int ks = half * 2 + kl;
        bh8 b0 = *(const bh8*)&xa[pb0 + kl * 32 + quad * 8];
        bh8 b1 = *(const bh8*)&xa[pb1 + kl * 32 + quad * 8];
        bh8 a0 = wa[(size_t)((tap * 4 + ks) * OM + 0) * 64];
        acc[0][0] = __builtin_amdgcn_mfma_f32_16x16x32_bf16(a0, b0, acc[0][0], 0, 0, 0);
        acc[0][1] = __builtin_amdgcn_mfma_f32_16x16x32_bf16(a0, b1, acc[0][1], 0, 0, 0);
        if constexpr (OM == 2) {
          bh8 a1 = wa[(size_t)((tap * 4 + ks) * OM + 1) * 64];
          acc[1][0] = __builtin_amdgcn_mfma_f32_16x16x32_bf16(a1, b0, acc[1][0], 0, 0, 0);
          acc[1][1] = __builtin_amdgcn_mfma_f32_16x16x32_bf16(a1, b1, acc[1][1], 0, 0, 0);
        }
      }
    }
  }

  // epilogue: C/D col=lane&15 (spatial), row=quad*4+reg (o); c' = r*O + o
  float sv[OM * 4], qv[OM * 4];
  #pragma unroll
  for (int e = 0; e < OM * 4; ++e) { sv[e] = 0.f; qv[e] = 0.f; }
  #pragma unroll
  for (int mi = 0; mi < OM; ++mi)
    #pragma unroll
    for (int ri = 0; ri < 2; ++ri) {
      int prow = row0 + 2 * wv + ri;
      int col = c0 + n;
      if (prow < HO && col < HO) {
        unsigned short* yp = y + ((size_t)b * HO * HO + prow * HO + col) * OSTR;
        int o0 = mi * 16 + quad * 4;
        f4v v = acc[mi][ri];
        if constexpr (O == 32) {
          us4 w4;
          #pragma unroll
          for (int reg = 0; reg < 4; ++reg) {
            float val = v[reg] + bias[o0 + reg];
            w4[reg] = f2bf(val);
            if constexpr (BNS) { sv[mi * 4 + reg] += val; qv[mi * 4 + reg] += val * val; }
          }
          *(us4*)(yp + r * 32 + o0) = w4;
        } else {
          #pragma unroll
          for (int reg = 0; reg < 4; ++reg) {
            int o = o0 + reg;
            if (o < O) yp[r * O + o] = f2bf(v[reg] + bias[o]);
          }
        }
      }
    }

  if constexpr (BNS) {
    #pragma unroll
    for (int e = 0; e < OM * 4; ++e) {
      #pragma unroll
      for (int off = 1; off < 16; off <<= 1) {
        sv[e] += __shfl_xor(sv[e], off);
        qv[e] += __shfl_xor(qv[e], off);
      }
    }
    if (threadIdx.x < 128) bnred[threadIdx.x] = 0.f;
    __syncthreads();
    if (n == 0) {
      #pragma unroll
      for (int e = 0; e < OM * 4; ++e) {
        int o = (e >> 2) * 16 + quad * 4 + (e & 3);
        atomicAdd(&bnred[o], sv[e]);
        atomicAdd(&bnred[64 + o], qv[e]);
      }
    }
    __syncthreads();
    if (threadIdx.x < 128)
      atomicAdd(&partl[(blockIdx.x & 63) * 128 + threadIdx.x], bnred[threadIdx.x]);
  }
}

// ---------------- BN finalize from bucketed partials (in-block) ----------------
DINL void bn_finalize2(const float* __restrict__ partl,
                       const float* __restrict__ gamma, const float* __restrict__ beta,
                       float* st, int npix, int tid) {
  if (tid < 32) {
    float s1 = 0.f, s2 = 0.f;
    for (int bk = 0; bk < 64; ++bk) {
      s1 += partl[bk * 128 + tid];
      s2 += partl[bk * 128 + 64 + tid];
    }
    float N = 4.f * (float)npix;
    float m = s1 / N;
    float v = s2 / N - m * m;
    float inv = rsqrtf(v + 2e-5f);
    float sc = gamma[tid] * inv;
    st[tid] = sc;
    st[32 + tid] = beta[tid] - m * sc;
  }
  __syncthreads();
}

// ---------------- fused BN-finalize+BN+ReLU+channel mean/max (bf16 raw in, bf16 out) ----
// c' = g*32 + o: bh8 chunk oo covers channels 8oo..8oo+7 -> g = oo>>2, o = (oo&3)*8+e.
__global__ void k_meanmax_bn(const unsigned short* __restrict__ yr, const float* __restrict__ partl,
                             const float* __restrict__ gamma, const float* __restrict__ beta,
                             unsigned short* __restrict__ xn, unsigned short* __restrict__ amap,
                             int npix) {
  __shared__ float st[64];
  bn_finalize2(partl, gamma, beta, st, npix, threadIdx.x);
  int idx = blockIdx.x * 256 + threadIdx.x;
  if (idx >= npix) return;
  const unsigned short* yp = yr + (size_t)idx * 128;
  unsigned short* xp = xn + (size_t)idx * 128;
  float sm[4] = {0.f, 0.f, 0.f, 0.f};
  float mx[4] = {-1e30f, -1e30f, -1e30f, -1e30f};
  #pragma unroll 4
  for (int oo = 0; oo < 16; ++oo) {
    int g = oo >> 2, ob = (oo & 3) * 8;
    bh8 raw = *(const bh8*)(yp + oo * 8);
    bh8 w;
    #pragma unroll
    for (int e = 0; e < 8; ++e) {
      float v = fmaxf(fmaf(bf2f((unsigned short)raw[e]), st[ob + e], st[32 + ob + e]), 0.f);
      w[e] = (short)f2bf(v);
      sm[g] += v;
      mx[g] = fmaxf(mx[g], v);
    }
    *(bh8*)(xp + oo * 8) = w;
  }
  bh8 am;
  #pragma unroll
  for (int g = 0; g < 4; ++g) {
    am[g] = (short)f2bf(sm[g] * (1.f / 32.f));
    am[4 + g] = (short)f2bf(mx[g]);
  }
  *(bh8*)(amap + (size_t)idx * 8) = am;
}

// layer-2 variant: BN+ReLU at 44x44 then 2x2 maxpool -> 22x22
__global__ void k_meanmax_bn_pool(const unsigned short* __restrict__ yr, const float* __restrict__ partl,
                                  const float* __restrict__ gamma, const float* __restrict__ beta,
                                  unsigned short* __restrict__ xn, unsigned short* __restrict__ amap,
                                  int npix) {
  const int HI = 44, HOq = 22, HWO = HOq * HOq;
  __shared__ float st[64];
  bn_finalize2(partl, gamma, beta, st, npix, threadIdx.x);
  int idx = blockIdx.x * 256 + threadIdx.x;
  if (idx >= 32 * HWO) return;
  int p22 = idx % HWO; int b = idx / HWO;
  int y0 = (p22 / HOq) * 2, x0 = (p22 % HOq) * 2;
  const unsigned short* p00 = yr + ((size_t)b * HI * HI + y0 * HI + x0) * 128;
  unsigned short* xp = xn + (size_t)idx * 128;
  float sm[4] = {0.f, 0.f, 0.f, 0.f};
  float mx[4] = {-1e30f, -1e30f, -1e30f, -1e30f};
  #pragma unroll 2
  for (int oo = 0; oo < 16; ++oo) {
    int g = oo >> 2, ob = (oo & 3) * 8;
    bh8 r0 = *(const bh8*)(p00 + oo * 8);
    bh8 r1 = *(const bh8*)(p00 + 128 + oo * 8);
    bh8 r2 = *(const bh8*)(p00 + (size_t)HI * 128 + oo * 8);
    bh8 r3 = *(const bh8*)(p00 + (size_t)(HI + 1) * 128 + oo * 8);
    bh8 w;
    #pragma unroll
    for (int e = 0; e < 8; ++e) {
      float sc = st[ob + e], sh = st[32 + ob + e];
      float a0 = fmaxf(fmaf(bf2f((unsigned short)r0[e]), sc, sh), 0.f);
      float a1 = fmaxf(fmaf(bf2f((unsigned short)r1[e]), sc, sh), 0.f);
      float a2 = fmaxf(fmaf(bf2f((unsigned short)r2[e]), sc, sh), 0.f);
      float a3 = fmaxf(fmaf(bf2f((unsigned short)r3[e]), sc, sh), 0.f);
      float val = fmaxf(fmaxf(a0, a1), fmaxf(a2, a3));
      w[e] = (short)f2bf(val);
      sm[g] += val; mx[g] = fmaxf(mx[g], val);
    }
    *(bh8*)(xp + oo * 8) = w;
  }
  bh8 am;
  #pragma unroll
  for (int g = 0; g < 4; ++g) {
    am[g] = (short)f2bf(sm[g] * (1.f / 32.f));
    am[4 + g] = (short)f2bf(mx[g]);
  }
  *(bh8*)(amap + (size_t)idx * 8) = am;
}

// ---------------- attention GG conv (LDS-staged rotated weights) ----------------

__global__ void __launch_bounds__(256)
k_att_gg(const unsigned short* __restrict__ amap, const float* __restrict__ aw,
         float* __restrict__ att, int h) {
  __shared__ float wsa[4][4][49], wsx[4][4][49];
  for (int i = threadIdx.x; i < 784; i += 256) {
    int r = i / 196; int rem = i % 196;
    int g = rem / 49; int t = rem % 49;
    int ky = t / 7, kx = t % 7;
    int si, sj; rot_src(r, 7, ky, kx, si, sj);
    int gs = (g - r) & 3;
    wsa[r][g][t] = aw[gs * 49 + si * 7 + sj];
    wsx[r][g][t] = aw[(4 + gs) * 49 + si * 7 + sj];
  }
  __syncthreads();
  int hw = h * h;
  int idx = blockIdx.x * 256 + threadIdx.x;
  if (idx >= 32 * 4 * hw) return;
  int p = idx % hw; int t = idx / hw;
  int r = t & 3; int b = t >> 2;
  int yh = p / h, xw = p % h;
  float s = 0.f;
  for (int ky = 0; ky < 7; ++ky) {
    int y = yh + ky - 3;
    if ((unsigned)y >= (unsigned)h) continue;
    for (int kx = 0; kx < 7; ++kx) {
      int xx = xw + kx - 3;
      if ((unsigned)xx >= (unsigned)h) continue;
      int tp = ky * 7 + kx;
      bh8 av = *(const bh8*)(amap + ((size_t)b * hw + y * h + xx) * 8);
      #pragma unroll
      for (int g = 0; g < 4; ++g)
        s += bf2f((unsigned short)av[g]) * wsa[r][g][tp]
           + bf2f((unsigned short)av[4 + g]) * wsx[r][g][tp];
    }
  }
  att[idx] = sigmoidf(s);
}

// ---------------- final: rotation max + spatial mean ----------------
// y7 bf16 [b][p(144)][40] with c' = r*10+o; out[b*10+o]
__global__ void k_final(const unsigned short* __restrict__ y7, float* __restrict__ out) {
  int idx = blockIdx.x * blockDim.x + threadIdx.x;
  if (idx >= 320) return;
  int o = idx % 10; int b = idx / 10;
  const unsigned short* p = y7 + (size_t)b * 144 * 40;
  float s = 0.f;
  for (int sp = 0; sp < 144; ++sp) {
    const unsigned short* q = p + sp * 40 + o;
    float m = fmaxf(fmaxf(bf2f(q[0]), bf2f(q[10])), fmaxf(bf2f(q[20]), bf2f(q[30])));
    s += m;
  }
  out[idx] = s * (1.f / 144.f);
}

// ---------------- host ----------------

extern "C" void kernel_launch(void* const* d_in, const int* in_sizes, int n_in,
                              void* d_out, int out_size, void* d_ws, size_t ws_size,
                              hipStream_t stream) {
  (void)in_sizes; (void)n_in; (void)out_size; (void)ws_size;
  const float* x   = (const float*)d_in[0];
  const float* w1  = (const float*)d_in[1];
  const float* b1  = (const float*)d_in[2];
  const float* aw1 = (const float*)d_in[3];
  const float* W[6];  const float* BI[6]; const float* AW[6];
  for (int i = 0; i < 6; ++i) {
    W[i]  = (const float*)d_in[4 + 3 * i];
    BI[i] = (const float*)d_in[5 + 3 * i];
    AW[i] = (const float*)d_in[6 + 3 * i];
  }
  const float* G[6]; const float* BE[6];
  for (int i = 0; i < 6; ++i) {
    G[i]  = (const float*)d_in[22 + 2 * i];
    BE[i] = (const float*)d_in[23 + 2 * i];
  }
  float* out = (float*)d_out;

  // workspace (floats): ~38.8 MB
  float* ws = (float*)d_ws;
  unsigned short* YR = (unsigned short*)ws;                  // raw conv out bf16, 8,667,136 ush
  unsigned short* XN = (unsigned short*)(ws + 4333568);      // normalized xn bf16, 8,667,136 ush
  unsigned short* AMAP = (unsigned short*)(ws + 8667136);    // 541,696 ush
  float* ATT = ws + 8937984;                                 // 294,912
  unsigned short* WROT = (unsigned short*)(ws + 9232896);    // 811,008 ush
  float* PART  = ws + 9638400;                               // 6 layers x 8192 = 49,152

  auto cdiv = [](int a, int b) { return (a + b - 1) / b; };
  float* PL[6];
  for (int i = 0; i < 6; ++i) PL[i] = PART + i * 8192;

  // zero the BN stat buckets (re-poisoned to 0xAA before every timed launch)
  hipMemsetAsync(PART, 0, 6 * 8192 * sizeof(float), stream);

  // weight prep (all 6 GG layers, one launch)
  k_prep_w<<<dim3(cdiv(811008, 256)), dim3(256), 0, stream>>>(
      W[0], W[1], W[2], W[3], W[4], W[5], WROT);
  const unsigned short* WL[6];
  for (int i = 0; i < 5; ++i) WL[i] = WROT + i * 147456;
  WL[5] = WROT + 737280;

  // ---- layer 1: attention + lifting conv (stats fused) ----
  {
    int natt = 32 * 4 * 48 * 48;
    k_att_lift<<<dim3(cdiv(natt, 256)), dim3(256), 0, stream>>>(x, aw1, ATT);
    k_conv_lift<<<dim3(32 * 46), dim3(256), 0, stream>>>(x, ATT, w1, b1, YR, PL[0]);
    int npix = 32 * 2116;
    k_meanmax_bn<<<dim3(cdiv(npix, 256)), dim3(256), 0, stream>>>(YR, PL[0], G[0], BE[0], XN, AMAP, npix);
    k_att_gg<<<dim3(cdiv(npix * 4, 256)), dim3(256), 0, stream>>>(AMAP, AW[0], ATT, 46);
  }
  // ---- layer 2 (H=46 -> 44) + pool ----  NRT=6, NCT=3
  {
    k_conv_mfma<46, 2, 32, 128, true><<<dim3(128 * 6 * 3), dim3(256), 0, stream>>>(XN, ATT, WL[0], BI[0], YR, PL[1]);
    int npix = 32 * 1936;
    int np22 = 32 * 484;
    k_meanmax_bn_pool<<<dim3(cdiv(np22, 256)), dim3(256), 0, stream>>>(YR, PL[1], G[1], BE[1], XN, AMAP, npix);
    k_att_gg<<<dim3(cdiv(np22 * 4, 256)), dim3(256), 0, stream>>>(AMAP, AW[1], ATT, 22);
  }
  // ---- layer 3 (22 -> 20) ----  NRT=3, NCT=2
  {
    k_conv_mfma<22, 2, 32, 128, true><<<dim3(128 * 3 * 2), dim3(256), 0, stream>>>(XN, ATT, WL[1], BI[1], YR, PL[2]);
    int npix = 32 * 400;
    k_meanmax_bn<<<dim3(cdiv(npix, 256)), dim3(256), 0, stream>>>(YR, PL[2], G[2], BE[2], XN, AMAP, npix);
    k_att_gg<<<dim3(cdiv(npix * 4, 256)), dim3(256), 0, stream>>>(AMAP, AW[2], ATT, 20);
  }
  // ---- layer 4 (20 -> 18) ----  NRT=3, NCT=2
  {
    k_conv_mfma<20, 2, 32, 128, true><<<dim3(128 * 3 * 2), dim3(256), 0, stream>>>(XN, ATT, WL[2], BI[2], YR, PL[3]);
    int npix = 32 * 324;
    k_meanmax_bn<<<dim3(cdiv(npix, 256)), dim3(256), 0, stream>>>(YR, PL[3], G[3], BE[3], XN, AMAP, npix);
    k_att_gg<<<dim3(cdiv(npix * 4, 256)), dim3(256), 0, stream>>>(AMAP, AW[3], ATT, 18);
  }
  // ---- layer 5 (18 -> 16) ----  NRT=2, NCT=1
  {
    k_conv_mfma<18, 2, 32, 128, true><<<dim3(128 * 2 * 1), dim3(256), 0, stream>>>(XN, ATT, WL[3], BI[3], YR, PL[4]);
    int npix = 32 * 256;
    k_meanmax_bn<<<dim3(cdiv(npix, 256)), dim3(256), 0, stream>>>(YR, PL[4], G[4], BE[4], XN, AMAP, npix);
    k_att_gg<<<dim3(cdiv(npix * 4, 256)), dim3(256), 0, stream>>>(AMAP, AW[4], ATT, 16);
  }
  // ---- layer 6 (16 -> 14) ----  NRT=2, NCT=1
  {
    k_conv_mfma<16, 2, 32, 128, true><<<dim3(128 * 2 * 1), dim3(256), 0, stream>>>(XN, ATT, WL[4], BI[4], YR, PL[5]);
    int npix = 32 * 196;
    k_meanmax_bn<<<dim3(cdiv(npix, 256)), dim3(256), 0, stream>>>(YR, PL[5], G[5], BE[5], XN, AMAP, npix);
    k_att_gg<<<dim3(cdiv(npix * 4, 256)), dim3(256), 0, stream>>>(AMAP, AW[5], ATT, 14);
  }
  // ---- layer 7 (14 -> 12, O=10, no BN) ----  NRT=2, NCT=1
  k_conv_mfma<14, 1, 10, 40, false><<<dim3(128 * 2 * 1), dim3(256), 0, stream>>>(XN, ATT, WL[5], BI[5], YR, nullptr);
  // ---- rotation max + spatial mean ----
  k_final<<<dim3(5), dim3(64), 0, stream>>>(YR, out);
}